// Round 2
// baseline (5040.348 us; speedup 1.0000x reference)
//
#include <hip/hip_runtime.h>
#include <math.h>

// Static problem dims
#define NG 64          // graphs
#define EE 64000       // edges
#define HC3 3072       // H*C
#define CC 1024        // C (and input feature dim)

static inline int cdiv(int a, int b) { return (a + b - 1) / b; }

__device__ __forceinline__ float lrelu(float x) { return x > 0.f ? x : 0.2f * x; }
// order-preserving float<->uint encoding for atomicMax on floats
__device__ __forceinline__ unsigned fenc(float f) {
    unsigned u = __float_as_uint(f);
    return (u & 0x80000000u) ? ~u : (u | 0x80000000u);
}
__device__ __forceinline__ float fdec(unsigned e) {
    return (e & 0x80000000u) ? __uint_as_float(e ^ 0x80000000u) : __uint_as_float(~e);
}

// ---- fp32 tiled GEMM: C[M,N] = A[M,K](lda) @ B[K,N](ldb) (+bias/accum/relu) ----
// M%64==0, N%64==0, K%16==0
__global__ __launch_bounds__(256) void gemm64(const float* __restrict__ A, int lda,
    const float* __restrict__ B, int ldb, const float* __restrict__ bias,
    float* __restrict__ C, int ldc, int M, int N, int K, int accum, int relu)
{
    __shared__ float As[16][64];   // As[k][m]
    __shared__ float Bs[16][64];   // Bs[k][n]
    const int t = threadIdx.x;
    const int row0 = blockIdx.y * 64, col0 = blockIdx.x * 64;
    const int ar = t >> 2, ac = (t & 3) << 2;     // A tile: 64 rows x 16 k
    const int br = t >> 4, bc = (t & 15) << 2;    // B tile: 16 k x 64 cols
    const int ty = t >> 4, tx = t & 15;
    float acc[4][4] = {{0.f}};
    const float* Ap = A + (long long)(row0 + ar) * lda + ac;
    const float* Bp = B + (long long)br * ldb + col0 + bc;
    for (int k0 = 0; k0 < K; k0 += 16) {
        float4 av = *(const float4*)(Ap + k0);
        float4 bv = *(const float4*)(Bp + (long long)k0 * ldb);
        As[ac + 0][ar] = av.x; As[ac + 1][ar] = av.y;
        As[ac + 2][ar] = av.z; As[ac + 3][ar] = av.w;
        *(float4*)&Bs[br][bc] = bv;
        __syncthreads();
#pragma unroll
        for (int kk = 0; kk < 16; ++kk) {
            float4 a4 = *(const float4*)&As[kk][ty << 2];
            float4 b4 = *(const float4*)&Bs[kk][tx << 2];
            acc[0][0] += a4.x * b4.x; acc[0][1] += a4.x * b4.y; acc[0][2] += a4.x * b4.z; acc[0][3] += a4.x * b4.w;
            acc[1][0] += a4.y * b4.x; acc[1][1] += a4.y * b4.y; acc[1][2] += a4.y * b4.z; acc[1][3] += a4.y * b4.w;
            acc[2][0] += a4.z * b4.x; acc[2][1] += a4.z * b4.y; acc[2][2] += a4.z * b4.z; acc[2][3] += a4.z * b4.w;
            acc[3][0] += a4.w * b4.x; acc[3][1] += a4.w * b4.y; acc[3][2] += a4.w * b4.z; acc[3][3] += a4.w * b4.w;
        }
        __syncthreads();
    }
#pragma unroll
    for (int i = 0; i < 4; ++i) {
        int row = row0 + (ty << 2) + i;
        int c0 = col0 + (tx << 2);
        float4 o = make_float4(acc[i][0], acc[i][1], acc[i][2], acc[i][3]);
        if (bias) { o.x += bias[c0]; o.y += bias[c0 + 1]; o.z += bias[c0 + 2]; o.w += bias[c0 + 3]; }
        float* cp = C + (long long)row * ldc + c0;
        if (accum) { float4 p = *(float4*)cp; o.x += p.x; o.y += p.y; o.z += p.z; o.w += p.w; }
        if (relu) { o.x = fmaxf(o.x, 0.f); o.y = fmaxf(o.y, 0.f); o.z = fmaxf(o.z, 0.f); o.w = fmaxf(o.w, 0.f); }
        *(float4*)cp = o;
    }
}

// ---- attention helper vectors: asv[h,k] = sum_c W[k, h*C+c]*atts[h,c] ----
__global__ __launch_bounds__(256) void attvec(const float* __restrict__ W,
    const float* __restrict__ atts, const float* __restrict__ attd,
    float* __restrict__ asv, float* __restrict__ adv)
{
    int wid = blockIdx.x * 4 + (threadIdx.x >> 6);   // 0..3071
    int lane = threadIdx.x & 63;
    int h = wid >> 10, kk = wid & 1023;
    const float* wr = W + (long long)kk * HC3 + h * CC;
    const float* sa = atts + h * CC;
    const float* da = attd + h * CC;
    float ss = 0.f, dd = 0.f;
    for (int c = lane; c < CC; c += 64) { float w = wr[c]; ss += w * sa[c]; dd += w * da[c]; }
    for (int off = 32; off; off >>= 1) { ss += __shfl_xor(ss, off, 64); dd += __shfl_xor(dd, off, 64); }
    if (lane == 0) { asv[h * CC + kk] = ss; adv[h * CC + kk] = dd; }
}

// ---- a_s[i,h], a_d[i,h] = x[i] . asv[h], x[i] . adv[h] ----
__global__ __launch_bounds__(256) void attn_dots(const float* __restrict__ xin,
    const float* __restrict__ asv, const float* __restrict__ adv,
    float* __restrict__ AS, float* __restrict__ AD, int n)
{
    int node = blockIdx.x * 4 + (threadIdx.x >> 6);
    int lane = threadIdx.x & 63;
    if (node >= n) return;
    const float* xr = xin + (long long)node * CC;
    float s0 = 0, s1 = 0, s2 = 0, d0 = 0, d1 = 0, d2 = 0;
    for (int j = lane; j < CC; j += 64) {
        float v = xr[j];
        s0 += v * asv[j]; s1 += v * asv[CC + j]; s2 += v * asv[2 * CC + j];
        d0 += v * adv[j]; d1 += v * adv[CC + j]; d2 += v * adv[2 * CC + j];
    }
    for (int off = 32; off; off >>= 1) {
        s0 += __shfl_xor(s0, off, 64); s1 += __shfl_xor(s1, off, 64); s2 += __shfl_xor(s2, off, 64);
        d0 += __shfl_xor(d0, off, 64); d1 += __shfl_xor(d1, off, 64); d2 += __shfl_xor(d2, off, 64);
    }
    if (lane == 0) {
        AS[node * 3 + 0] = s0; AS[node * 3 + 1] = s1; AS[node * 3 + 2] = s2;
        AD[node * 3 + 0] = d0; AD[node * 3 + 1] = d1; AD[node * 3 + 2] = d2;
    }
}

// ---- BV[c] = bt[c] + sum_k b[k] * Wt[k,c] ----
__global__ void bvec_kernel(const float* __restrict__ b, const float* __restrict__ Wt,
    const float* __restrict__ bt, float* __restrict__ BV)
{
    int c = blockIdx.x * 256 + threadIdx.x;
    if (c >= CC) return;
    float acc = bt[c];
    for (int k = 0; k < HC3; ++k) acc += b[k] * Wt[(long long)k * CC + c];
    BV[c] = acc;
}

// ---- CSR build (mask-based, head-independent) ----
__global__ void zero_cc(int* __restrict__ cnt, int* __restrict__ cur, int n)
{
    int i = blockIdx.x * 256 + threadIdx.x;
    if (i < n) { cnt[i] = 0; cur[i] = 0; }
}

__global__ void count_edges(const int* __restrict__ dst, const int* __restrict__ msk,
    int* __restrict__ cnt)
{
    int e = blockIdx.x * 256 + threadIdx.x;
    if (e >= EE || !msk[e]) return;
    atomicAdd(&cnt[dst[e]], 1);
}

__global__ void scan_graph(const int* __restrict__ cnt, int* __restrict__ offs,
    int* __restrict__ gt, int npg)
{
    if (threadIdx.x != 0) return;
    int g = blockIdx.x, base = g * npg, run = 0;
    for (int i = 0; i < npg; ++i) { offs[base + i] = run; run += cnt[base + i]; }
    gt[g] = run;
}

__global__ void scan_base(const int* __restrict__ gt, int* __restrict__ gb)
{
    if (threadIdx.x != 0 || blockIdx.x != 0) return;
    int run = 0;
    for (int g = 0; g < NG; ++g) { gb[g] = run; run += gt[g]; }
}

__global__ void add_base(int* __restrict__ offs, const int* __restrict__ gb, int n, int npg)
{
    int i = blockIdx.x * 256 + threadIdx.x;
    if (i < n) offs[i] += gb[i / npg];
}

__global__ void fill_csr(const int* __restrict__ src, const int* __restrict__ dst,
    const int* __restrict__ msk, const int* __restrict__ offs, int* __restrict__ cur,
    int* __restrict__ csrs, int* __restrict__ pose)
{
    int e = blockIdx.x * 256 + threadIdx.x;
    if (e >= EE) return;
    if (!msk[e]) { pose[e] = -1; return; }
    int d = dst[e];
    int pos = offs[d] + atomicAdd(&cur[d], 1);
    csrs[pos] = src[e];
    pose[e] = pos;
}

// ---- softmax over incoming edges (+ self loop), all 3 heads ----
__global__ void node_init(const float* __restrict__ AS, const float* __restrict__ AD,
    float* __restrict__ sl, unsigned* __restrict__ mxe, int n)
{
    int i = blockIdx.x * 256 + threadIdx.x;
    if (i >= n) return;
#pragma unroll
    for (int h = 0; h < 3; ++h) {
        float l = lrelu(AS[i * 3 + h] + AD[i * 3 + h]);
        sl[i * 3 + h] = l;
        mxe[i * 3 + h] = fenc(l);
    }
}

__global__ void edge_max(const int* __restrict__ src, const int* __restrict__ dst,
    const int* __restrict__ msk, const float* __restrict__ AS,
    const float* __restrict__ AD, unsigned* __restrict__ mxe)
{
    int e = blockIdx.x * 256 + threadIdx.x;
    if (e >= EE || !msk[e]) return;
    int s = src[e], d = dst[e];
#pragma unroll
    for (int h = 0; h < 3; ++h) {
        float l = lrelu(AS[s * 3 + h] + AD[d * 3 + h]);
        atomicMax(&mxe[d * 3 + h], fenc(l));
    }
}

__global__ void decode_selfden(const unsigned* __restrict__ mxe, const float* __restrict__ sl,
    float* __restrict__ mxf, float* __restrict__ den, int n)
{
    int i = blockIdx.x * 256 + threadIdx.x;
    if (i >= n) return;
#pragma unroll
    for (int h = 0; h < 3; ++h) {
        float m = fdec(mxe[i * 3 + h]);
        mxf[i * 3 + h] = m;
        den[i * 3 + h] = expf(sl[i * 3 + h] - m);   // self-loop contribution
    }
}

__global__ void edge_den(const int* __restrict__ src, const int* __restrict__ dst,
    const int* __restrict__ msk, const float* __restrict__ AS, const float* __restrict__ AD,
    const float* __restrict__ mxf, float* __restrict__ den)
{
    int e = blockIdx.x * 256 + threadIdx.x;
    if (e >= EE || !msk[e]) return;
    int s = src[e], d = dst[e];
#pragma unroll
    for (int h = 0; h < 3; ++h) {
        float l = lrelu(AS[s * 3 + h] + AD[d * 3 + h]);
        atomicAdd(&den[d * 3 + h], expf(l - mxf[d * 3 + h]));
    }
}

__global__ void alpha_fill(const int* __restrict__ src, const int* __restrict__ dst,
    const int* __restrict__ pose, const float* __restrict__ AS, const float* __restrict__ AD,
    const float* __restrict__ mxf, const float* __restrict__ den, float* __restrict__ csra)
{
    int e = blockIdx.x * 256 + threadIdx.x;
    if (e >= EE) return;
    int pos = pose[e];
    if (pos < 0) return;
    int s = src[e], d = dst[e];
#pragma unroll
    for (int h = 0; h < 3; ++h) {
        float l = lrelu(AS[s * 3 + h] + AD[d * 3 + h]);
        float ex = expf(l - mxf[d * 3 + h]);
        csra[pos * 3 + h] = ex / (den[d * 3 + h] + 1e-16f);
    }
}

// ---- per-head alpha-aggregation of raw x: AggX[i,:] = a_self*x[i,:] + sum alpha*x[s,:] ----
__global__ __launch_bounds__(256) void aggregate_h(const float* __restrict__ xin,
    const float* __restrict__ sl, const float* __restrict__ mxf, const float* __restrict__ den,
    const int* __restrict__ offs, const int* __restrict__ cnt,
    const int* __restrict__ csrs, const float* __restrict__ csra,
    int h, float* __restrict__ aggx)
{
    int i = blockIdx.x, t = threadIdx.x;
    float aself = expf(sl[i * 3 + h] - mxf[i * 3 + h]) / (den[i * 3 + h] + 1e-16f);
    const float* xr = xin + (long long)i * CC;
    float acc[4];
#pragma unroll
    for (int j = 0; j < 4; ++j) acc[j] = aself * xr[t + (j << 8)];
    int beg = offs[i], num = cnt[i];
    for (int e = 0; e < num; ++e) {
        int s = csrs[beg + e];
        float a = csra[(beg + e) * 3 + h];
        const float* sr = xin + (long long)s * CC;
#pragma unroll
        for (int j = 0; j < 4; ++j) acc[j] += a * sr[t + (j << 8)];
    }
#pragma unroll
    for (int j = 0; j < 4; ++j) aggx[(long long)i * CC + t + (j << 8)] = acc[j];
}

// ---------------- TopK pooling ----------------
__global__ void pnorm_kernel(const float* __restrict__ p, float* __restrict__ pn)
{
    __shared__ float red[256];
    int t = threadIdx.x;
    float s = 0.f;
    for (int j = t; j < CC; j += 256) { float v = p[j]; s += v * v; }
    red[t] = s; __syncthreads();
    for (int off = 128; off; off >>= 1) { if (t < off) red[t] += red[t + off]; __syncthreads(); }
    if (t == 0) pn[0] = sqrtf(red[0]);
}

__global__ __launch_bounds__(256) void score_kernel(const float* __restrict__ h,
    const float* __restrict__ p, const float* __restrict__ pn, float* __restrict__ sc, int n)
{
    int wid = blockIdx.x * 4 + (threadIdx.x >> 6);
    int lane = threadIdx.x & 63;
    if (wid >= n) return;
    const float* hr = h + (long long)wid * CC;
    float s = 0.f;
    for (int j = lane; j < CC; j += 64) s += hr[j] * p[j];
    for (int off = 32; off; off >>= 1) s += __shfl_xor(s, off, 64);
    if (lane == 0) sc[wid] = tanhf(s / pn[0]);
}

__global__ void seti(int* __restrict__ a, int val, int n)
{
    int i = blockIdx.x * 256 + threadIdx.x;
    if (i < n) a[i] = val;
}

// one wave per graph; iterative argmax (stable: ties -> lowest index), matches lax.top_k
__global__ __launch_bounds__(64) void topk_kernel(const float* __restrict__ score,
    int npg, int k, int* __restrict__ perm, float* __restrict__ vals, int* __restrict__ newid)
{
    int g = blockIdx.x, lane = threadIdx.x;
    const float* sc = score + g * npg;
    float v[4];
    int nsl = (npg + 63) >> 6;
#pragma unroll
    for (int s2 = 0; s2 < 4; ++s2) {
        int idx = lane + (s2 << 6);
        v[s2] = (s2 < nsl && idx < npg) ? sc[idx] : -1e30f;
    }
    for (int j = 0; j < k; ++j) {
        float bv = -2e30f; int bi = 0x7fffffff;
#pragma unroll
        for (int s2 = 0; s2 < 4; ++s2) {
            int idx = lane + (s2 << 6);
            if (v[s2] > bv) { bv = v[s2]; bi = idx; }  // ascending idx: strict > keeps lowest
        }
        for (int off = 32; off; off >>= 1) {
            float ov = __shfl_xor(bv, off, 64);
            int   oi = __shfl_xor(bi, off, 64);
            if (ov > bv || (ov == bv && oi < bi)) { bv = ov; bi = oi; }
        }
        if (lane == 0) {
            perm[g * k + j] = g * npg + bi;
            vals[g * k + j] = bv;
            newid[g * npg + bi] = g * k + j;
        }
        if ((bi & 63) == lane) v[bi >> 6] = -1e30f;
    }
}

__global__ __launch_bounds__(256) void gather_scale(const float* __restrict__ h,
    const int* __restrict__ perm, const float* __restrict__ vals, float* __restrict__ xn)
{
    int r = blockIdx.x, t = threadIdx.x;
    int pr = perm[r]; float v = vals[r];
    const float* s = h + (long long)pr * CC;
    float* d = xn + (long long)r * CC;
#pragma unroll
    for (int j = 0; j < 4; ++j) { int c = t + (j << 8); d[c] = s[c] * v; }
}

// in-place edge remap (per-thread read-then-write, no cross-thread deps)
__global__ void remap_edges(int* __restrict__ s, int* __restrict__ d,
    int* __restrict__ m, const int* __restrict__ newid)
{
    int e = blockIdx.x * 256 + threadIdx.x;
    if (e >= EE) return;
    if (!m[e]) { s[e] = 0; d[e] = 0; return; }
    int ns = newid[s[e]], nd = newid[d[e]];
    int nm = (ns >= 0 && nd >= 0) ? 1 : 0;
    m[e] = nm; s[e] = nm ? ns : 0; d[e] = nm ? nd : 0;
}

__global__ __launch_bounds__(256) void readout_kernel(const float* __restrict__ xn,
    int k, float* __restrict__ R)
{
    int g = blockIdx.x, t = threadIdx.x;
#pragma unroll
    for (int j = 0; j < 4; ++j) {
        int c = t + (j << 8);
        float mx = -1e30f, sm = 0.f;
        for (int r = 0; r < k; ++r) {
            float vv = xn[((long long)(g * k + r)) * CC + c];
            mx = fmaxf(mx, vv); sm += vv;
        }
        R[g * 2048 + c] = mx;
        R[g * 2048 + 1024 + c] = sm / (float)k;
    }
}

__global__ void copy_edges(const int* __restrict__ ei, int* __restrict__ s,
    int* __restrict__ d, int* __restrict__ m)
{
    int e = blockIdx.x * 256 + threadIdx.x;
    if (e >= EE) return;
    s[e] = ei[e]; d[e] = ei[EE + e]; m[e] = 1;
}

// ---------------- final MLP ----------------
__global__ void zsum(const float* __restrict__ a, const float* __restrict__ b,
    const float* __restrict__ c, float* __restrict__ z)
{
    int i = blockIdx.x * 256 + threadIdx.x;
    if (i < NG * 2048) z[i] = a[i] + b[i] + c[i];
}

__global__ __launch_bounds__(64) void mlp2_kernel(const float* __restrict__ Z1,
    const float* __restrict__ Wl2, const float* __restrict__ bl2, float* __restrict__ out)
{
    int b = blockIdx.x; int g = b >> 1, o = b & 1;
    int lane = threadIdx.x;
    const float* zr = Z1 + g * 1024;
    float s = 0.f;
    for (int j = lane; j < 1024; j += 64) s += zr[j] * Wl2[j * 2 + o];
    for (int off = 32; off; off >>= 1) s += __shfl_xor(s, off, 64);
    if (lane == 0) out[g * 2 + o] = s + bl2[o];
}

// ---------------- host ----------------
extern "C" void kernel_launch(void* const* d_in, const int* in_sizes, int n_in,
                              void* d_out, int out_size, void* d_ws, size_t ws_size,
                              hipStream_t stream)
{
    const float* x   = (const float*)d_in[0];
    const int*   ei  = (const int*)d_in[2];
    const float* W[3]    = {(const float*)d_in[4],  (const float*)d_in[11], (const float*)d_in[18]};
    const float* atts[3] = {(const float*)d_in[5],  (const float*)d_in[12], (const float*)d_in[19]};
    const float* attd[3] = {(const float*)d_in[6],  (const float*)d_in[13], (const float*)d_in[20]};
    const float* bb[3]   = {(const float*)d_in[7],  (const float*)d_in[14], (const float*)d_in[21]};
    const float* Wt[3]   = {(const float*)d_in[8],  (const float*)d_in[15], (const float*)d_in[22]};
    const float* bt[3]   = {(const float*)d_in[9],  (const float*)d_in[16], (const float*)d_in[23]};
    const float* pv[3]   = {(const float*)d_in[10], (const float*)d_in[17], (const float*)d_in[24]};
    const float* Wl1 = (const float*)d_in[25];
    const float* bl1 = (const float*)d_in[26];
    const float* Wl2 = (const float*)d_in[27];
    const float* bl2 = (const float*)d_in[28];
    float* out = (float*)d_out;

    // ---- workspace carve (~157 MB total) ----
    char* wp = (char*)d_ws;
    auto carve = [&](size_t bytes) -> void* {
        void* p = (void*)wp;
        wp += (bytes + 255) & ~(size_t)255;
        return p;
    };
    const int NMAX = 12800;
    float* AGGX = (float*)carve((size_t)NMAX * CC * 4);    // 52.4 MB
    float* Hb   = (float*)carve((size_t)NMAX * CC * 4);    // 52.4 MB
    float* XN   = (float*)carve((size_t)10240 * CC * 4);   // 41.9 MB
    float* MH   = (float*)carve((size_t)CC * CC * 4);      // 4.2 MB
    float* ASV  = (float*)carve((size_t)3 * CC * 4);
    float* ADV  = (float*)carve((size_t)3 * CC * 4);
    float* BV   = (float*)carve((size_t)CC * 4);
    float* AS   = (float*)carve((size_t)NMAX * 3 * 4);
    float* AD   = (float*)carve((size_t)NMAX * 3 * 4);
    float* SL   = (float*)carve((size_t)NMAX * 3 * 4);
    unsigned* MXE = (unsigned*)carve((size_t)NMAX * 3 * 4);
    float* MXF  = (float*)carve((size_t)NMAX * 3 * 4);
    float* DEN  = (float*)carve((size_t)NMAX * 3 * 4);
    int* CNT    = (int*)carve((size_t)NMAX * 4);
    int* OFFS   = (int*)carve((size_t)NMAX * 4);
    int* CUR    = (int*)carve((size_t)NMAX * 4);
    int* NEWID  = (int*)carve((size_t)NMAX * 4);
    int* GT     = (int*)carve((size_t)NG * 4);
    int* GB     = (int*)carve((size_t)NG * 4);
    int* CSRS   = (int*)carve((size_t)EE * 4);
    int* POSE   = (int*)carve((size_t)EE * 4);
    float* CSRA = (float*)carve((size_t)EE * 3 * 4);
    int* SRC = (int*)carve((size_t)EE * 4);
    int* DST = (int*)carve((size_t)EE * 4);
    int* MK  = (int*)carve((size_t)EE * 4);
    int* PERM  = (int*)carve((size_t)10240 * 4);
    float* VALS = (float*)carve((size_t)10240 * 4);
    float* SCORE = (float*)carve((size_t)NMAX * 4);
    float* PN = (float*)carve(256);
    float* R0 = (float*)carve((size_t)NG * 2048 * 4);
    float* R1 = (float*)carve((size_t)NG * 2048 * 4);
    float* R2 = (float*)carve((size_t)NG * 2048 * 4);
    float* Z  = (float*)carve((size_t)NG * 2048 * 4);
    float* Z1 = (float*)carve((size_t)NG * 1024 * 4);
    float* Rarr[3] = {R0, R1, R2};
    (void)ws_size; (void)in_sizes; (void)n_in; (void)out_size;

    copy_edges<<<cdiv(EE, 256), 256, 0, stream>>>(ei, SRC, DST, MK);

    const int ns_[3]  = {12800, 10240, 5120};
    const int npg_[3] = {200, 160, 80};
    const int kk_[3]  = {160, 80, 16};
    const float* xin = x;

    for (int L = 0; L < 3; ++L) {
        int n = ns_[L], npg = npg_[L], k = kk_[L];
        // attention helper vectors + per-node coefficients
        attvec<<<768, 256, 0, stream>>>(W[L], atts[L], attd[L], ASV, ADV);
        attn_dots<<<n / 4, 256, 0, stream>>>(xin, ASV, ADV, AS, AD, n);
        // folded bias: BV = b @ Wt + bt
        bvec_kernel<<<4, 256, 0, stream>>>(bb[L], Wt[L], bt[L], BV);
        // CSR build
        zero_cc<<<cdiv(n, 256), 256, 0, stream>>>(CNT, CUR, n);
        count_edges<<<cdiv(EE, 256), 256, 0, stream>>>(DST, MK, CNT);
        scan_graph<<<NG, 64, 0, stream>>>(CNT, OFFS, GT, npg);
        scan_base<<<1, 64, 0, stream>>>(GT, GB);
        add_base<<<cdiv(n, 256), 256, 0, stream>>>(OFFS, GB, n, npg);
        fill_csr<<<cdiv(EE, 256), 256, 0, stream>>>(SRC, DST, MK, OFFS, CUR, CSRS, POSE);
        // segment softmax (3 heads)
        node_init<<<cdiv(n, 256), 256, 0, stream>>>(AS, AD, SL, MXE, n);
        edge_max<<<cdiv(EE, 256), 256, 0, stream>>>(SRC, DST, MK, AS, AD, MXE);
        decode_selfden<<<cdiv(n, 256), 256, 0, stream>>>(MXE, SL, MXF, DEN, n);
        edge_den<<<cdiv(EE, 256), 256, 0, stream>>>(SRC, DST, MK, AS, AD, MXF, DEN);
        alpha_fill<<<cdiv(EE, 256), 256, 0, stream>>>(SRC, DST, POSE, AS, AD, MXF, DEN, CSRA);
        // per head: aggregate x, M_h = W_h @ Wt_h, Hb (+)= AggX @ M_h
        for (int h = 0; h < 3; ++h) {
            aggregate_h<<<n, 256, 0, stream>>>(xin, SL, MXF, DEN, OFFS, CNT, CSRS, CSRA, h, AGGX);
            gemm64<<<dim3(16, 16), 256, 0, stream>>>(W[L] + h * CC, HC3,
                Wt[L] + (long long)h * CC * CC, CC, nullptr, MH, CC, CC, CC, CC, 0, 0);
            gemm64<<<dim3(16, n / 64), 256, 0, stream>>>(AGGX, CC, MH, CC,
                (h == 0) ? BV : nullptr, Hb, CC, n, CC, CC, (h > 0) ? 1 : 0, 0);
        }
        // TopK pooling + readout
        pnorm_kernel<<<1, 256, 0, stream>>>(pv[L], PN);
        score_kernel<<<n / 4, 256, 0, stream>>>(Hb, pv[L], PN, SCORE, n);
        seti<<<cdiv(n, 256), 256, 0, stream>>>(NEWID, -1, n);
        topk_kernel<<<NG, 64, 0, stream>>>(SCORE, npg, k, PERM, VALS, NEWID);
        gather_scale<<<NG * k, 256, 0, stream>>>(Hb, PERM, VALS, XN);
        readout_kernel<<<NG, 256, 0, stream>>>(XN, k, Rarr[L]);
        if (L < 2) remap_edges<<<cdiv(EE, 256), 256, 0, stream>>>(SRC, DST, MK, NEWID);
        xin = XN;
    }

    // final MLP
    zsum<<<cdiv(NG * 2048, 256), 256, 0, stream>>>(R0, R1, R2, Z);
    gemm64<<<dim3(16, 1), 256, 0, stream>>>(Z, 2048, Wl1, 1024, bl1, Z1, 1024, 64, 1024, 2048, 0, 1);
    mlp2_kernel<<<NG * 2, 64, 0, stream>>>(Z1, Wl2, bl2, out);
}

// Round 3
// 2737.632 us; speedup vs baseline: 1.8411x; 1.8411x over previous
//
#include <hip/hip_runtime.h>
#include <math.h>

// Static problem dims
#define NG 64          // graphs
#define EE 64000       // edges
#define HC3 3072       // H*C
#define CC 1024        // C (and input feature dim)

static inline int cdiv(int a, int b) { return (a + b - 1) / b; }

typedef float f4_t __attribute__((ext_vector_type(4)));
typedef short s8_t __attribute__((ext_vector_type(8)));

__device__ __forceinline__ float lrelu(float x) { return x > 0.f ? x : 0.2f * x; }
__device__ __forceinline__ unsigned fenc(float f) {
    unsigned u = __float_as_uint(f);
    return (u & 0x80000000u) ? ~u : (u | 0x80000000u);
}
__device__ __forceinline__ float fdec(unsigned e) {
    return (e & 0x80000000u) ? __uint_as_float(e ^ 0x80000000u) : __uint_as_float(~e);
}
// round-to-nearest-even fp32 -> bf16
__device__ __forceinline__ unsigned short f2bf(float f) {
    unsigned u = __float_as_uint(f);
    u += 0x7fffu + ((u >> 16) & 1u);
    return (unsigned short)(u >> 16);
}
__device__ __forceinline__ float bf2f(unsigned short h) {
    return __uint_as_float(((unsigned)h) << 16);
}
__device__ __forceinline__ void gll16(const unsigned short* g, unsigned short* l) {
    __builtin_amdgcn_global_load_lds(
        (const __attribute__((address_space(1))) void*)g,
        (__attribute__((address_space(3))) void*)l, 16, 0, 0);
}

// ======== MFMA split-bf16 GEMM: C[M,N] = (Ahi+Alo)[M,K] @ (Bhi+Blo)[N,K]^T ========
// (drops lo*lo). M%128==0, N%128==0, K%32==0. Optional bias[n] and accumulate.
__global__ __launch_bounds__(256) void gemm_split(
    const unsigned short* __restrict__ Ahi, const unsigned short* __restrict__ Alo, int lda,
    const unsigned short* __restrict__ Bhi, const unsigned short* __restrict__ Blo, int ldb,
    const float* __restrict__ bias, float* __restrict__ C, int ldc, int K,
    size_t zsA, size_t zsB, size_t zsC, int accum)
{
    __shared__ unsigned short sAH[128 * 32];
    __shared__ unsigned short sAL[128 * 32];
    __shared__ unsigned short sBH[128 * 32];
    __shared__ unsigned short sBL[128 * 32];

    Ahi += blockIdx.z * zsA; Alo += blockIdx.z * zsA;
    Bhi += blockIdx.z * zsB; Blo += blockIdx.z * zsB;
    C   += blockIdx.z * zsC;

    const int t = threadIdx.x;
    const int w = t >> 6, lane = t & 63;
    const int wr = w >> 1, wc = w & 1;
    const int row0 = blockIdx.y * 128, col0 = blockIdx.x * 128;

    // staging addresses: wave w, issue i covers rows i*64 + w*16 + lane/4, k-chunk (lane&3)*8
    const int srow = w * 16 + (lane >> 2);
    const int skg = (lane & 3) * 8;
    const size_t aoff0 = (size_t)(row0 + srow) * lda + skg;
    const size_t aoff1 = (size_t)(row0 + 64 + srow) * lda + skg;
    const size_t boff0 = (size_t)(col0 + srow) * ldb + skg;
    const size_t boff1 = (size_t)(col0 + 64 + srow) * ldb + skg;
    const int l0 = (w * 16) * 32;          // wave-uniform LDS elem offset, issue 0
    const int l1 = (64 + w * 16) * 32;     // issue 1

    f4_t acc[4][4];
    const f4_t z4 = {0.f, 0.f, 0.f, 0.f};
#pragma unroll
    for (int i = 0; i < 4; ++i)
#pragma unroll
        for (int j = 0; j < 4; ++j) acc[i][j] = z4;

    const int mrow0 = wr * 64 + (lane & 15);
    const int nrow0 = wc * 64 + (lane & 15);
    const int koff = (lane >> 4) * 8;

    for (int k0 = 0; k0 < K; k0 += 32) {
        gll16(Ahi + aoff0 + k0, &sAH[l0]);
        gll16(Ahi + aoff1 + k0, &sAH[l1]);
        gll16(Alo + aoff0 + k0, &sAL[l0]);
        gll16(Alo + aoff1 + k0, &sAL[l1]);
        gll16(Bhi + boff0 + k0, &sBH[l0]);
        gll16(Bhi + boff1 + k0, &sBH[l1]);
        gll16(Blo + boff0 + k0, &sBL[l0]);
        gll16(Blo + boff1 + k0, &sBL[l1]);
        __syncthreads();

        s8_t ah[4], al[4], bh[4], bl[4];
#pragma unroll
        for (int mt = 0; mt < 4; ++mt) {
            ah[mt] = *(const s8_t*)&sAH[(mrow0 + mt * 16) * 32 + koff];
            al[mt] = *(const s8_t*)&sAL[(mrow0 + mt * 16) * 32 + koff];
        }
#pragma unroll
        for (int nt = 0; nt < 4; ++nt) {
            bh[nt] = *(const s8_t*)&sBH[(nrow0 + nt * 16) * 32 + koff];
            bl[nt] = *(const s8_t*)&sBL[(nrow0 + nt * 16) * 32 + koff];
        }
#pragma unroll
        for (int mt = 0; mt < 4; ++mt)
#pragma unroll
            for (int nt = 0; nt < 4; ++nt) {
                acc[mt][nt] = __builtin_amdgcn_mfma_f32_16x16x32_bf16(ah[mt], bh[nt], acc[mt][nt], 0, 0, 0);
                acc[mt][nt] = __builtin_amdgcn_mfma_f32_16x16x32_bf16(ah[mt], bl[nt], acc[mt][nt], 0, 0, 0);
                acc[mt][nt] = __builtin_amdgcn_mfma_f32_16x16x32_bf16(al[mt], bh[nt], acc[mt][nt], 0, 0, 0);
            }
        __syncthreads();
    }

    // epilogue: D row = (lane>>4)*4 + r (m dim), col = lane&15 (n dim)
#pragma unroll
    for (int mt = 0; mt < 4; ++mt) {
        int row = row0 + wr * 64 + mt * 16 + (lane >> 4) * 4;
#pragma unroll
        for (int nt = 0; nt < 4; ++nt) {
            int col = col0 + wc * 64 + nt * 16 + (lane & 15);
            float b = bias ? bias[col] : 0.f;
#pragma unroll
            for (int r = 0; r < 4; ++r) {
                float v = acc[mt][nt][r] + b;
                float* cp = C + (size_t)(row + r) * ldc + col;
                if (accum) v += *cp;
                *cp = v;
            }
        }
    }
}

// ---- fp32 tiled GEMM (small cases only: MLP1) ----
__global__ __launch_bounds__(256) void gemm64(const float* __restrict__ A, int lda,
    const float* __restrict__ B, int ldb, const float* __restrict__ bias,
    float* __restrict__ C, int ldc, int M, int N, int K, int accum, int relu)
{
    __shared__ float As[16][64];
    __shared__ float Bs[16][64];
    const int t = threadIdx.x;
    const int row0 = blockIdx.y * 64, col0 = blockIdx.x * 64;
    const int ar = t >> 2, ac = (t & 3) << 2;
    const int br = t >> 4, bc = (t & 15) << 2;
    const int ty = t >> 4, tx = t & 15;
    float acc[4][4] = {{0.f}};
    const float* Ap = A + (long long)(row0 + ar) * lda + ac;
    const float* Bp = B + (long long)br * ldb + col0 + bc;
    for (int k0 = 0; k0 < K; k0 += 16) {
        float4 av = *(const float4*)(Ap + k0);
        float4 bv = *(const float4*)(Bp + (long long)k0 * ldb);
        As[ac + 0][ar] = av.x; As[ac + 1][ar] = av.y;
        As[ac + 2][ar] = av.z; As[ac + 3][ar] = av.w;
        *(float4*)&Bs[br][bc] = bv;
        __syncthreads();
#pragma unroll
        for (int kk = 0; kk < 16; ++kk) {
            float4 a4 = *(const float4*)&As[kk][ty << 2];
            float4 b4 = *(const float4*)&Bs[kk][tx << 2];
            acc[0][0] += a4.x * b4.x; acc[0][1] += a4.x * b4.y; acc[0][2] += a4.x * b4.z; acc[0][3] += a4.x * b4.w;
            acc[1][0] += a4.y * b4.x; acc[1][1] += a4.y * b4.y; acc[1][2] += a4.y * b4.z; acc[1][3] += a4.y * b4.w;
            acc[2][0] += a4.z * b4.x; acc[2][1] += a4.z * b4.y; acc[2][2] += a4.z * b4.z; acc[2][3] += a4.z * b4.w;
            acc[3][0] += a4.w * b4.x; acc[3][1] += a4.w * b4.y; acc[3][2] += a4.w * b4.z; acc[3][3] += a4.w * b4.w;
        }
        __syncthreads();
    }
#pragma unroll
    for (int i = 0; i < 4; ++i) {
        int row = row0 + (ty << 2) + i;
        int c0 = col0 + (tx << 2);
        float4 o = make_float4(acc[i][0], acc[i][1], acc[i][2], acc[i][3]);
        if (bias) { o.x += bias[c0]; o.y += bias[c0 + 1]; o.z += bias[c0 + 2]; o.w += bias[c0 + 3]; }
        float* cp = C + (long long)row * ldc + c0;
        if (accum) { float4 p = *(float4*)cp; o.x += p.x; o.y += p.y; o.z += p.z; o.w += p.w; }
        if (relu) { o.x = fmaxf(o.x, 0.f); o.y = fmaxf(o.y, 0.f); o.z = fmaxf(o.z, 0.f); o.w = fmaxf(o.w, 0.f); }
        *(float4*)cp = o;
    }
}

// ---- weight prep: split W head-slice [1024 k][1024 j] (k-major, contiguous j) ----
__global__ void split_w(const float* __restrict__ W, unsigned short* __restrict__ ohi,
    unsigned short* __restrict__ olo)
{
    int h = blockIdx.y;
    int idx = blockIdx.x * 256 + threadIdx.x;       // r*1024 + c over 1024x1024
    int r = idx >> 10, c = idx & 1023;
    float v = W[(size_t)r * HC3 + h * CC + c];
    unsigned short hh = f2bf(v);
    ohi[(size_t)h * 1048576 + idx] = hh;
    olo[(size_t)h * 1048576 + idx] = f2bf(v - bf2f(hh));
}

// ---- weight prep: transpose+split Wt head-slice: out[c][j] = Wt[h*1024+j][c] ----
__global__ void transpose_split_wt(const float* __restrict__ Wt,
    unsigned short* __restrict__ ohi, unsigned short* __restrict__ olo)
{
    int h = blockIdx.z;
    __shared__ float tile[32][33];
    int t = threadIdx.x, tr = t >> 5, tc = t & 31;
    int r0 = blockIdx.y * 32, c0 = blockIdx.x * 32;
    const float* in = Wt + (size_t)h * 1048576;
#pragma unroll
    for (int i = 0; i < 4; ++i)
        tile[tr + i * 8][tc] = in[(size_t)(r0 + tr + i * 8) * CC + c0 + tc];
    __syncthreads();
    unsigned short* oh = ohi + (size_t)h * 1048576;
    unsigned short* ol = olo + (size_t)h * 1048576;
#pragma unroll
    for (int i = 0; i < 4; ++i) {
        int oc = c0 + tr + i * 8;   // out row = original col
        int orr = r0 + tc;          // out col = original row
        float v = tile[tc][tr + i * 8];
        unsigned short hh = f2bf(v);
        oh[(size_t)oc * CC + orr] = hh;
        ol[(size_t)oc * CC + orr] = f2bf(v - bf2f(hh));
    }
}

// ---- split fp32 matrix (contiguous) -> bf16 hi/lo ----
__global__ void split_plain(const float* __restrict__ in, unsigned short* __restrict__ ohi,
    unsigned short* __restrict__ olo)
{
    int h = blockIdx.y;
    int idx = blockIdx.x * 256 + threadIdx.x;
    float v = in[(size_t)h * 1048576 + idx];
    unsigned short hh = f2bf(v);
    ohi[(size_t)h * 1048576 + idx] = hh;
    olo[(size_t)h * 1048576 + idx] = f2bf(v - bf2f(hh));
}

// ---- attention helper vectors: asv[h,k] = sum_c W[k, h*C+c]*atts[h,c] ----
__global__ __launch_bounds__(256) void attvec(const float* __restrict__ W,
    const float* __restrict__ atts, const float* __restrict__ attd,
    float* __restrict__ asv, float* __restrict__ adv)
{
    int wid = blockIdx.x * 4 + (threadIdx.x >> 6);
    int lane = threadIdx.x & 63;
    int h = wid >> 10, kk = wid & 1023;
    const float* wr = W + (long long)kk * HC3 + h * CC;
    const float* sa = atts + h * CC;
    const float* da = attd + h * CC;
    float ss = 0.f, dd = 0.f;
    for (int c = lane; c < CC; c += 64) { float w = wr[c]; ss += w * sa[c]; dd += w * da[c]; }
    for (int off = 32; off; off >>= 1) { ss += __shfl_xor(ss, off, 64); dd += __shfl_xor(dd, off, 64); }
    if (lane == 0) { asv[h * CC + kk] = ss; adv[h * CC + kk] = dd; }
}

__global__ __launch_bounds__(256) void attn_dots(const float* __restrict__ xin,
    const float* __restrict__ asv, const float* __restrict__ adv,
    float* __restrict__ AS, float* __restrict__ AD, int n)
{
    int node = blockIdx.x * 4 + (threadIdx.x >> 6);
    int lane = threadIdx.x & 63;
    if (node >= n) return;
    const float* xr = xin + (long long)node * CC;
    float s0 = 0, s1 = 0, s2 = 0, d0 = 0, d1 = 0, d2 = 0;
    for (int j = lane; j < CC; j += 64) {
        float v = xr[j];
        s0 += v * asv[j]; s1 += v * asv[CC + j]; s2 += v * asv[2 * CC + j];
        d0 += v * adv[j]; d1 += v * adv[CC + j]; d2 += v * adv[2 * CC + j];
    }
    for (int off = 32; off; off >>= 1) {
        s0 += __shfl_xor(s0, off, 64); s1 += __shfl_xor(s1, off, 64); s2 += __shfl_xor(s2, off, 64);
        d0 += __shfl_xor(d0, off, 64); d1 += __shfl_xor(d1, off, 64); d2 += __shfl_xor(d2, off, 64);
    }
    if (lane == 0) {
        AS[node * 3 + 0] = s0; AS[node * 3 + 1] = s1; AS[node * 3 + 2] = s2;
        AD[node * 3 + 0] = d0; AD[node * 3 + 1] = d1; AD[node * 3 + 2] = d2;
    }
}

__global__ void bvec_kernel(const float* __restrict__ b, const float* __restrict__ Wt,
    const float* __restrict__ bt, float* __restrict__ BV)
{
    int c = blockIdx.x * 256 + threadIdx.x;
    if (c >= CC) return;
    float acc = bt[c];
    for (int k = 0; k < HC3; ++k) acc += b[k] * Wt[(long long)k * CC + c];
    BV[c] = acc;
}

// ---- CSR build ----
__global__ void zero_cc(int* __restrict__ cnt, int* __restrict__ cur, int n)
{
    int i = blockIdx.x * 256 + threadIdx.x;
    if (i < n) { cnt[i] = 0; cur[i] = 0; }
}

__global__ void count_edges(const int* __restrict__ dst, const int* __restrict__ msk,
    int* __restrict__ cnt)
{
    int e = blockIdx.x * 256 + threadIdx.x;
    if (e >= EE || !msk[e]) return;
    atomicAdd(&cnt[dst[e]], 1);
}

__global__ void scan_graph(const int* __restrict__ cnt, int* __restrict__ offs,
    int* __restrict__ gt, int npg)
{
    if (threadIdx.x != 0) return;
    int g = blockIdx.x, base = g * npg, run = 0;
    for (int i = 0; i < npg; ++i) { offs[base + i] = run; run += cnt[base + i]; }
    gt[g] = run;
}

__global__ void scan_base(const int* __restrict__ gt, int* __restrict__ gb)
{
    if (threadIdx.x != 0 || blockIdx.x != 0) return;
    int run = 0;
    for (int g = 0; g < NG; ++g) { gb[g] = run; run += gt[g]; }
}

__global__ void add_base(int* __restrict__ offs, const int* __restrict__ gb, int n, int npg)
{
    int i = blockIdx.x * 256 + threadIdx.x;
    if (i < n) offs[i] += gb[i / npg];
}

__global__ void fill_csr(const int* __restrict__ src, const int* __restrict__ dst,
    const int* __restrict__ msk, const int* __restrict__ offs, int* __restrict__ cur,
    int* __restrict__ csrs, int* __restrict__ pose)
{
    int e = blockIdx.x * 256 + threadIdx.x;
    if (e >= EE) return;
    if (!msk[e]) { pose[e] = -1; return; }
    int d = dst[e];
    int pos = offs[d] + atomicAdd(&cur[d], 1);
    csrs[pos] = src[e];
    pose[e] = pos;
}

// ---- segment softmax ----
__global__ void node_init(const float* __restrict__ AS, const float* __restrict__ AD,
    float* __restrict__ sl, unsigned* __restrict__ mxe, int n)
{
    int i = blockIdx.x * 256 + threadIdx.x;
    if (i >= n) return;
#pragma unroll
    for (int h = 0; h < 3; ++h) {
        float l = lrelu(AS[i * 3 + h] + AD[i * 3 + h]);
        sl[i * 3 + h] = l;
        mxe[i * 3 + h] = fenc(l);
    }
}

__global__ void edge_max(const int* __restrict__ src, const int* __restrict__ dst,
    const int* __restrict__ msk, const float* __restrict__ AS,
    const float* __restrict__ AD, unsigned* __restrict__ mxe)
{
    int e = blockIdx.x * 256 + threadIdx.x;
    if (e >= EE || !msk[e]) return;
    int s = src[e], d = dst[e];
#pragma unroll
    for (int h = 0; h < 3; ++h) {
        float l = lrelu(AS[s * 3 + h] + AD[d * 3 + h]);
        atomicMax(&mxe[d * 3 + h], fenc(l));
    }
}

__global__ void decode_selfden(const unsigned* __restrict__ mxe, const float* __restrict__ sl,
    float* __restrict__ mxf, float* __restrict__ den, int n)
{
    int i = blockIdx.x * 256 + threadIdx.x;
    if (i >= n) return;
#pragma unroll
    for (int h = 0; h < 3; ++h) {
        float m = fdec(mxe[i * 3 + h]);
        mxf[i * 3 + h] = m;
        den[i * 3 + h] = expf(sl[i * 3 + h] - m);
    }
}

__global__ void edge_den(const int* __restrict__ src, const int* __restrict__ dst,
    const int* __restrict__ msk, const float* __restrict__ AS, const float* __restrict__ AD,
    const float* __restrict__ mxf, float* __restrict__ den)
{
    int e = blockIdx.x * 256 + threadIdx.x;
    if (e >= EE || !msk[e]) return;
    int s = src[e], d = dst[e];
#pragma unroll
    for (int h = 0; h < 3; ++h) {
        float l = lrelu(AS[s * 3 + h] + AD[d * 3 + h]);
        atomicAdd(&den[d * 3 + h], expf(l - mxf[d * 3 + h]));
    }
}

__global__ void alpha_fill(const int* __restrict__ src, const int* __restrict__ dst,
    const int* __restrict__ pose, const float* __restrict__ AS, const float* __restrict__ AD,
    const float* __restrict__ mxf, const float* __restrict__ den, float* __restrict__ csra)
{
    int e = blockIdx.x * 256 + threadIdx.x;
    if (e >= EE) return;
    int pos = pose[e];
    if (pos < 0) return;
    int s = src[e], d = dst[e];
#pragma unroll
    for (int h = 0; h < 3; ++h) {
        float l = lrelu(AS[s * 3 + h] + AD[d * 3 + h]);
        float ex = expf(l - mxf[d * 3 + h]);
        csra[pos * 3 + h] = ex / (den[d * 3 + h] + 1e-16f);
    }
}

// ---- per-head alpha-aggregation of raw x, emits split bf16 ----
__global__ __launch_bounds__(256) void aggregate_h(const float* __restrict__ xin,
    const float* __restrict__ sl, const float* __restrict__ mxf, const float* __restrict__ den,
    const int* __restrict__ offs, const int* __restrict__ cnt,
    const int* __restrict__ csrs, const float* __restrict__ csra,
    int h, unsigned short* __restrict__ ahi, unsigned short* __restrict__ alo)
{
    int i = blockIdx.x, t = threadIdx.x;
    float aself = expf(sl[i * 3 + h] - mxf[i * 3 + h]) / (den[i * 3 + h] + 1e-16f);
    const float* xr = xin + (long long)i * CC;
    float acc[4];
#pragma unroll
    for (int j = 0; j < 4; ++j) acc[j] = aself * xr[t + (j << 8)];
    int beg = offs[i], num = cnt[i];
    for (int e = 0; e < num; ++e) {
        int s = csrs[beg + e];
        float a = csra[(beg + e) * 3 + h];
        const float* sr = xin + (long long)s * CC;
#pragma unroll
        for (int j = 0; j < 4; ++j) acc[j] += a * sr[t + (j << 8)];
    }
#pragma unroll
    for (int j = 0; j < 4; ++j) {
        int c = t + (j << 8);
        float v = acc[j];
        unsigned short hh = f2bf(v);
        ahi[(size_t)i * CC + c] = hh;
        alo[(size_t)i * CC + c] = f2bf(v - bf2f(hh));
    }
}

// ---------------- TopK pooling ----------------
__global__ void pnorm_kernel(const float* __restrict__ p, float* __restrict__ pn)
{
    __shared__ float red[256];
    int t = threadIdx.x;
    float s = 0.f;
    for (int j = t; j < CC; j += 256) { float v = p[j]; s += v * v; }
    red[t] = s; __syncthreads();
    for (int off = 128; off; off >>= 1) { if (t < off) red[t] += red[t + off]; __syncthreads(); }
    if (t == 0) pn[0] = sqrtf(red[0]);
}

__global__ __launch_bounds__(256) void score_kernel(const float* __restrict__ h,
    const float* __restrict__ p, const float* __restrict__ pn, float* __restrict__ sc, int n)
{
    int wid = blockIdx.x * 4 + (threadIdx.x >> 6);
    int lane = threadIdx.x & 63;
    if (wid >= n) return;
    const float* hr = h + (long long)wid * CC;
    float s = 0.f;
    for (int j = lane; j < CC; j += 64) s += hr[j] * p[j];
    for (int off = 32; off; off >>= 1) s += __shfl_xor(s, off, 64);
    if (lane == 0) sc[wid] = tanhf(s / pn[0]);
}

__global__ void seti(int* __restrict__ a, int val, int n)
{
    int i = blockIdx.x * 256 + threadIdx.x;
    if (i < n) a[i] = val;
}

__global__ __launch_bounds__(64) void topk_kernel(const float* __restrict__ score,
    int npg, int k, int* __restrict__ perm, float* __restrict__ vals, int* __restrict__ newid)
{
    int g = blockIdx.x, lane = threadIdx.x;
    const float* sc = score + g * npg;
    float v[4];
    int nsl = (npg + 63) >> 6;
#pragma unroll
    for (int s2 = 0; s2 < 4; ++s2) {
        int idx = lane + (s2 << 6);
        v[s2] = (s2 < nsl && idx < npg) ? sc[idx] : -1e30f;
    }
    for (int j = 0; j < k; ++j) {
        float bv = -2e30f; int bi = 0x7fffffff;
#pragma unroll
        for (int s2 = 0; s2 < 4; ++s2) {
            int idx = lane + (s2 << 6);
            if (v[s2] > bv) { bv = v[s2]; bi = idx; }
        }
        for (int off = 32; off; off >>= 1) {
            float ov = __shfl_xor(bv, off, 64);
            int   oi = __shfl_xor(bi, off, 64);
            if (ov > bv || (ov == bv && oi < bi)) { bv = ov; bi = oi; }
        }
        if (lane == 0) {
            perm[g * k + j] = g * npg + bi;
            vals[g * k + j] = bv;
            newid[g * npg + bi] = g * k + j;
        }
        if ((bi & 63) == lane) v[bi >> 6] = -1e30f;
    }
}

__global__ __launch_bounds__(256) void gather_scale(const float* __restrict__ h,
    const int* __restrict__ perm, const float* __restrict__ vals, float* __restrict__ xn)
{
    int r = blockIdx.x, t = threadIdx.x;
    int pr = perm[r]; float v = vals[r];
    const float* s = h + (long long)pr * CC;
    float* d = xn + (long long)r * CC;
#pragma unroll
    for (int j = 0; j < 4; ++j) { int c = t + (j << 8); d[c] = s[c] * v; }
}

__global__ void remap_edges(int* __restrict__ s, int* __restrict__ d,
    int* __restrict__ m, const int* __restrict__ newid)
{
    int e = blockIdx.x * 256 + threadIdx.x;
    if (e >= EE) return;
    if (!m[e]) { s[e] = 0; d[e] = 0; return; }
    int ns = newid[s[e]], nd = newid[d[e]];
    int nm = (ns >= 0 && nd >= 0) ? 1 : 0;
    m[e] = nm; s[e] = nm ? ns : 0; d[e] = nm ? nd : 0;
}

__global__ __launch_bounds__(256) void readout_kernel(const float* __restrict__ xn,
    int k, float* __restrict__ R)
{
    int g = blockIdx.x, t = threadIdx.x;
#pragma unroll
    for (int j = 0; j < 4; ++j) {
        int c = t + (j << 8);
        float mx = -1e30f, sm = 0.f;
        for (int r = 0; r < k; ++r) {
            float vv = xn[((long long)(g * k + r)) * CC + c];
            mx = fmaxf(mx, vv); sm += vv;
        }
        R[g * 2048 + c] = mx;
        R[g * 2048 + 1024 + c] = sm / (float)k;
    }
}

__global__ void copy_edges(const int* __restrict__ ei, int* __restrict__ s,
    int* __restrict__ d, int* __restrict__ m)
{
    int e = blockIdx.x * 256 + threadIdx.x;
    if (e >= EE) return;
    s[e] = ei[e]; d[e] = ei[EE + e]; m[e] = 1;
}

// ---------------- final MLP ----------------
__global__ void zsum(const float* __restrict__ a, const float* __restrict__ b,
    const float* __restrict__ c, float* __restrict__ z)
{
    int i = blockIdx.x * 256 + threadIdx.x;
    if (i < NG * 2048) z[i] = a[i] + b[i] + c[i];
}

__global__ __launch_bounds__(64) void mlp2_kernel(const float* __restrict__ Z1,
    const float* __restrict__ Wl2, const float* __restrict__ bl2, float* __restrict__ out)
{
    int b = blockIdx.x; int g = b >> 1, o = b & 1;
    int lane = threadIdx.x;
    const float* zr = Z1 + g * 1024;
    float s = 0.f;
    for (int j = lane; j < 1024; j += 64) s += zr[j] * Wl2[j * 2 + o];
    for (int off = 32; off; off >>= 1) s += __shfl_xor(s, off, 64);
    if (lane == 0) out[g * 2 + o] = s + bl2[o];
}

// ---------------- host ----------------
extern "C" void kernel_launch(void* const* d_in, const int* in_sizes, int n_in,
                              void* d_out, int out_size, void* d_ws, size_t ws_size,
                              hipStream_t stream)
{
    const float* x   = (const float*)d_in[0];
    const int*   ei  = (const int*)d_in[2];
    const float* W[3]    = {(const float*)d_in[4],  (const float*)d_in[11], (const float*)d_in[18]};
    const float* atts[3] = {(const float*)d_in[5],  (const float*)d_in[12], (const float*)d_in[19]};
    const float* attd[3] = {(const float*)d_in[6],  (const float*)d_in[13], (const float*)d_in[20]};
    const float* bb[3]   = {(const float*)d_in[7],  (const float*)d_in[14], (const float*)d_in[21]};
    const float* Wt[3]   = {(const float*)d_in[8],  (const float*)d_in[15], (const float*)d_in[22]};
    const float* bt[3]   = {(const float*)d_in[9],  (const float*)d_in[16], (const float*)d_in[23]};
    const float* pv[3]   = {(const float*)d_in[10], (const float*)d_in[17], (const float*)d_in[24]};
    const float* Wl1 = (const float*)d_in[25];
    const float* bl1 = (const float*)d_in[26];
    const float* Wl2 = (const float*)d_in[27];
    const float* bl2 = (const float*)d_in[28];
    float* out = (float*)d_out;

    // ---- workspace carve (~170 MB) ----
    char* wp = (char*)d_ws;
    auto carve = [&](size_t bytes) -> void* {
        void* p = (void*)wp;
        wp += (bytes + 255) & ~(size_t)255;
        return p;
    };
    const int NMAX = 12800;
    unsigned short* A2H = (unsigned short*)carve((size_t)NMAX * CC * 2);   // 26.2 MB
    unsigned short* A2L = (unsigned short*)carve((size_t)NMAX * CC * 2);   // 26.2 MB
    float* Hb   = (float*)carve((size_t)NMAX * CC * 4);                    // 52.4 MB
    float* XN   = (float*)carve((size_t)10240 * CC * 4);                   // 41.9 MB
    unsigned short* B2H = (unsigned short*)carve((size_t)3 * CC * CC * 2); // 6.3 MB
    unsigned short* B2L = (unsigned short*)carve((size_t)3 * CC * CC * 2);
    unsigned short* WTH = (unsigned short*)carve((size_t)3 * CC * CC * 2);
    unsigned short* WTL = (unsigned short*)carve((size_t)3 * CC * CC * 2);
    unsigned short* WSH = (unsigned short*)carve((size_t)3 * CC * CC * 2);
    unsigned short* WSL = (unsigned short*)carve((size_t)3 * CC * CC * 2);
    float* MHT  = (float*)carve((size_t)3 * CC * CC * 4);                  // 12.6 MB
    float* ASV  = (float*)carve((size_t)3 * CC * 4);
    float* ADV  = (float*)carve((size_t)3 * CC * 4);
    float* BV   = (float*)carve((size_t)CC * 4);
    float* AS   = (float*)carve((size_t)NMAX * 3 * 4);
    float* AD   = (float*)carve((size_t)NMAX * 3 * 4);
    float* SL   = (float*)carve((size_t)NMAX * 3 * 4);
    unsigned* MXE = (unsigned*)carve((size_t)NMAX * 3 * 4);
    float* MXF  = (float*)carve((size_t)NMAX * 3 * 4);
    float* DEN  = (float*)carve((size_t)NMAX * 3 * 4);
    int* CNT    = (int*)carve((size_t)NMAX * 4);
    int* OFFS   = (int*)carve((size_t)NMAX * 4);
    int* CUR    = (int*)carve((size_t)NMAX * 4);
    int* NEWID  = (int*)carve((size_t)NMAX * 4);
    int* GT     = (int*)carve((size_t)NG * 4);
    int* GB     = (int*)carve((size_t)NG * 4);
    int* CSRS   = (int*)carve((size_t)EE * 4);
    int* POSE   = (int*)carve((size_t)EE * 4);
    float* CSRA = (float*)carve((size_t)EE * 3 * 4);
    int* SRC = (int*)carve((size_t)EE * 4);
    int* DST = (int*)carve((size_t)EE * 4);
    int* MK  = (int*)carve((size_t)EE * 4);
    int* PERM  = (int*)carve((size_t)10240 * 4);
    float* VALS = (float*)carve((size_t)10240 * 4);
    float* SCORE = (float*)carve((size_t)NMAX * 4);
    float* PN = (float*)carve(256);
    float* R0 = (float*)carve((size_t)NG * 2048 * 4);
    float* R1 = (float*)carve((size_t)NG * 2048 * 4);
    float* R2 = (float*)carve((size_t)NG * 2048 * 4);
    float* Z  = (float*)carve((size_t)NG * 2048 * 4);
    float* Z1 = (float*)carve((size_t)NG * 1024 * 4);
    float* Rarr[3] = {R0, R1, R2};
    (void)ws_size; (void)in_sizes; (void)n_in; (void)out_size;

    copy_edges<<<cdiv(EE, 256), 256, 0, stream>>>(ei, SRC, DST, MK);

    const int ns_[3]  = {12800, 10240, 5120};
    const int npg_[3] = {200, 160, 80};
    const int kk_[3]  = {160, 80, 16};
    const float* xin = x;
    const size_t MSZ = (size_t)CC * CC;   // 1048576

    for (int L = 0; L < 3; ++L) {
        int n = ns_[L], npg = npg_[L], k = kk_[L];
        // attention vectors + per-node coefficients + folded bias
        attvec<<<768, 256, 0, stream>>>(W[L], atts[L], attd[L], ASV, ADV);
        attn_dots<<<n / 4, 256, 0, stream>>>(xin, ASV, ADV, AS, AD, n);
        bvec_kernel<<<4, 256, 0, stream>>>(bb[L], Wt[L], bt[L], BV);
        // fused per-head weight M_h^T = Wt_h^T @ W_h^T (all heads batched via z)
        split_w<<<dim3(4096, 3), 256, 0, stream>>>(W[L], WSH, WSL);
        transpose_split_wt<<<dim3(32, 32, 3), 256, 0, stream>>>(Wt[L], WTH, WTL);
        gemm_split<<<dim3(8, 8, 3), 256, 0, stream>>>(WTH, WTL, CC, WSH, WSL, CC,
            nullptr, MHT, CC, CC, MSZ, MSZ, MSZ, 0);
        split_plain<<<dim3(4096, 3), 256, 0, stream>>>(MHT, B2H, B2L);
        // CSR build
        zero_cc<<<cdiv(n, 256), 256, 0, stream>>>(CNT, CUR, n);
        count_edges<<<cdiv(EE, 256), 256, 0, stream>>>(DST, MK, CNT);
        scan_graph<<<NG, 64, 0, stream>>>(CNT, OFFS, GT, npg);
        scan_base<<<1, 64, 0, stream>>>(GT, GB);
        add_base<<<cdiv(n, 256), 256, 0, stream>>>(OFFS, GB, n, npg);
        fill_csr<<<cdiv(EE, 256), 256, 0, stream>>>(SRC, DST, MK, OFFS, CUR, CSRS, POSE);
        // segment softmax
        node_init<<<cdiv(n, 256), 256, 0, stream>>>(AS, AD, SL, MXE, n);
        edge_max<<<cdiv(EE, 256), 256, 0, stream>>>(SRC, DST, MK, AS, AD, MXE);
        decode_selfden<<<cdiv(n, 256), 256, 0, stream>>>(MXE, SL, MXF, DEN, n);
        edge_den<<<cdiv(EE, 256), 256, 0, stream>>>(SRC, DST, MK, AS, AD, MXF, DEN);
        alpha_fill<<<cdiv(EE, 256), 256, 0, stream>>>(SRC, DST, POSE, AS, AD, MXF, DEN, CSRA);
        // per head: aggregate x (split-bf16 out), Hb (+)= AggX @ M_h^T^T
        for (int h = 0; h < 3; ++h) {
            aggregate_h<<<n, 256, 0, stream>>>(xin, SL, MXF, DEN, OFFS, CNT, CSRS, CSRA,
                                               h, A2H, A2L);
            gemm_split<<<dim3(8, n / 128, 1), 256, 0, stream>>>(A2H, A2L, CC,
                B2H + (size_t)h * MSZ, B2L + (size_t)h * MSZ, CC,
                (h == 0) ? BV : nullptr, Hb, CC, CC, 0, 0, 0, (h > 0) ? 1 : 0);
        }
        // TopK pooling + readout
        pnorm_kernel<<<1, 256, 0, stream>>>(pv[L], PN);
        score_kernel<<<n / 4, 256, 0, stream>>>(Hb, pv[L], PN, SCORE, n);
        seti<<<cdiv(n, 256), 256, 0, stream>>>(NEWID, -1, n);
        topk_kernel<<<NG, 64, 0, stream>>>(SCORE, npg, k, PERM, VALS, NEWID);
        gather_scale<<<NG * k, 256, 0, stream>>>(Hb, PERM, VALS, XN);
        readout_kernel<<<NG, 256, 0, stream>>>(XN, k, Rarr[L]);
        if (L < 2) remap_edges<<<cdiv(EE, 256), 256, 0, stream>>>(SRC, DST, MK, NEWID);
        xin = XN;
    }

    // final MLP
    zsum<<<cdiv(NG * 2048, 256), 256, 0, stream>>>(R0, R1, R2, Z);
    gemm64<<<dim3(16, 1), 256, 0, stream>>>(Z, 2048, Wl1, 1024, bl1, Z1, 1024, 64, 1024, 2048, 0, 1);
    mlp2_kernel<<<NG * 2, 64, 0, stream>>>(Z1, Wl2, bl2, out);
}

// Round 4
// 2505.467 us; speedup vs baseline: 2.0117x; 1.0927x over previous
//
#include <hip/hip_runtime.h>
#include <math.h>

// Static problem dims
#define NG 64          // graphs
#define EE 64000       // edges
#define HC3 3072       // H*C
#define CC 1024        // C (and input feature dim)

static inline int cdiv(int a, int b) { return (a + b - 1) / b; }

typedef float f4_t __attribute__((ext_vector_type(4)));
typedef short s8_t __attribute__((ext_vector_type(8)));

__device__ __forceinline__ float lrelu(float x) { return x > 0.f ? x : 0.2f * x; }
__device__ __forceinline__ unsigned fenc(float f) {
    unsigned u = __float_as_uint(f);
    return (u & 0x80000000u) ? ~u : (u | 0x80000000u);
}
__device__ __forceinline__ float fdec(unsigned e) {
    return (e & 0x80000000u) ? __uint_as_float(e ^ 0x80000000u) : __uint_as_float(~e);
}
__device__ __forceinline__ unsigned short f2bf(float f) {
    unsigned u = __float_as_uint(f);
    u += 0x7fffu + ((u >> 16) & 1u);
    return (unsigned short)(u >> 16);
}
__device__ __forceinline__ float bf2f(unsigned short h) {
    return __uint_as_float(((unsigned)h) << 16);
}
__device__ __forceinline__ void gll16(const unsigned short* g, unsigned short* l) {
    __builtin_amdgcn_global_load_lds(
        (const __attribute__((address_space(1))) void*)g,
        (__attribute__((address_space(3))) void*)l, 16, 0, 0);
}

// ======== MFMA split-bf16 GEMM: C[M,N] = (Ahi+Alo)[M,K] @ (Bhi+Blo)[N,K]^T ========
__global__ __launch_bounds__(256) void gemm_split(
    const unsigned short* __restrict__ Ahi, const unsigned short* __restrict__ Alo, int lda,
    const unsigned short* __restrict__ Bhi, const unsigned short* __restrict__ Blo, int ldb,
    const float* __restrict__ bias, float* __restrict__ C, int ldc, int K,
    size_t zsA, size_t zsB, size_t zsC, int accum)
{
    __shared__ unsigned short sAH[128 * 32];
    __shared__ unsigned short sAL[128 * 32];
    __shared__ unsigned short sBH[128 * 32];
    __shared__ unsigned short sBL[128 * 32];

    Ahi += blockIdx.z * zsA; Alo += blockIdx.z * zsA;
    Bhi += blockIdx.z * zsB; Blo += blockIdx.z * zsB;
    C   += blockIdx.z * zsC;

    const int t = threadIdx.x;
    const int w = t >> 6, lane = t & 63;
    const int wr = w >> 1, wc = w & 1;
    const int row0 = blockIdx.y * 128, col0 = blockIdx.x * 128;

    const int srow = w * 16 + (lane >> 2);
    const int skg = (lane & 3) * 8;
    const size_t aoff0 = (size_t)(row0 + srow) * lda + skg;
    const size_t aoff1 = (size_t)(row0 + 64 + srow) * lda + skg;
    const size_t boff0 = (size_t)(col0 + srow) * ldb + skg;
    const size_t boff1 = (size_t)(col0 + 64 + srow) * ldb + skg;
    const int l0 = (w * 16) * 32;
    const int l1 = (64 + w * 16) * 32;

    f4_t acc[4][4];
    const f4_t z4 = {0.f, 0.f, 0.f, 0.f};
#pragma unroll
    for (int i = 0; i < 4; ++i)
#pragma unroll
        for (int j = 0; j < 4; ++j) acc[i][j] = z4;

    const int mrow0 = wr * 64 + (lane & 15);
    const int nrow0 = wc * 64 + (lane & 15);
    const int koff = (lane >> 4) * 8;

    for (int k0 = 0; k0 < K; k0 += 32) {
        gll16(Ahi + aoff0 + k0, &sAH[l0]);
        gll16(Ahi + aoff1 + k0, &sAH[l1]);
        gll16(Alo + aoff0 + k0, &sAL[l0]);
        gll16(Alo + aoff1 + k0, &sAL[l1]);
        gll16(Bhi + boff0 + k0, &sBH[l0]);
        gll16(Bhi + boff1 + k0, &sBH[l1]);
        gll16(Blo + boff0 + k0, &sBL[l0]);
        gll16(Blo + boff1 + k0, &sBL[l1]);
        __syncthreads();

        s8_t ah[4], al[4], bh[4], bl[4];
#pragma unroll
        for (int mt = 0; mt < 4; ++mt) {
            ah[mt] = *(const s8_t*)&sAH[(mrow0 + mt * 16) * 32 + koff];
            al[mt] = *(const s8_t*)&sAL[(mrow0 + mt * 16) * 32 + koff];
        }
#pragma unroll
        for (int nt = 0; nt < 4; ++nt) {
            bh[nt] = *(const s8_t*)&sBH[(nrow0 + nt * 16) * 32 + koff];
            bl[nt] = *(const s8_t*)&sBL[(nrow0 + nt * 16) * 32 + koff];
        }
#pragma unroll
        for (int mt = 0; mt < 4; ++mt)
#pragma unroll
            for (int nt = 0; nt < 4; ++nt) {
                acc[mt][nt] = __builtin_amdgcn_mfma_f32_16x16x32_bf16(ah[mt], bh[nt], acc[mt][nt], 0, 0, 0);
                acc[mt][nt] = __builtin_amdgcn_mfma_f32_16x16x32_bf16(ah[mt], bl[nt], acc[mt][nt], 0, 0, 0);
                acc[mt][nt] = __builtin_amdgcn_mfma_f32_16x16x32_bf16(al[mt], bh[nt], acc[mt][nt], 0, 0, 0);
            }
        __syncthreads();
    }

#pragma unroll
    for (int mt = 0; mt < 4; ++mt) {
        int row = row0 + wr * 64 + mt * 16 + (lane >> 4) * 4;
#pragma unroll
        for (int nt = 0; nt < 4; ++nt) {
            int col = col0 + wc * 64 + nt * 16 + (lane & 15);
            float b = bias ? bias[col] : 0.f;
#pragma unroll
            for (int r = 0; r < 4; ++r) {
                float v = acc[mt][nt][r] + b;
                float* cp = C + (size_t)(row + r) * ldc + col;
                if (accum) v += *cp;
                *cp = v;
            }
        }
    }
}

// ---- fp32 tiled GEMM (MLP1 only) ----
__global__ __launch_bounds__(256) void gemm64(const float* __restrict__ A, int lda,
    const float* __restrict__ B, int ldb, const float* __restrict__ bias,
    float* __restrict__ C, int ldc, int M, int N, int K, int accum, int relu)
{
    __shared__ float As[16][64];
    __shared__ float Bs[16][64];
    const int t = threadIdx.x;
    const int row0 = blockIdx.y * 64, col0 = blockIdx.x * 64;
    const int ar = t >> 2, ac = (t & 3) << 2;
    const int br = t >> 4, bc = (t & 15) << 2;
    const int ty = t >> 4, tx = t & 15;
    float acc[4][4] = {{0.f}};
    const float* Ap = A + (long long)(row0 + ar) * lda + ac;
    const float* Bp = B + (long long)br * ldb + col0 + bc;
    for (int k0 = 0; k0 < K; k0 += 16) {
        float4 av = *(const float4*)(Ap + k0);
        float4 bv = *(const float4*)(Bp + (long long)k0 * ldb);
        As[ac + 0][ar] = av.x; As[ac + 1][ar] = av.y;
        As[ac + 2][ar] = av.z; As[ac + 3][ar] = av.w;
        *(float4*)&Bs[br][bc] = bv;
        __syncthreads();
#pragma unroll
        for (int kk = 0; kk < 16; ++kk) {
            float4 a4 = *(const float4*)&As[kk][ty << 2];
            float4 b4 = *(const float4*)&Bs[kk][tx << 2];
            acc[0][0] += a4.x * b4.x; acc[0][1] += a4.x * b4.y; acc[0][2] += a4.x * b4.z; acc[0][3] += a4.x * b4.w;
            acc[1][0] += a4.y * b4.x; acc[1][1] += a4.y * b4.y; acc[1][2] += a4.y * b4.z; acc[1][3] += a4.y * b4.w;
            acc[2][0] += a4.z * b4.x; acc[2][1] += a4.z * b4.y; acc[2][2] += a4.z * b4.z; acc[2][3] += a4.z * b4.w;
            acc[3][0] += a4.w * b4.x; acc[3][1] += a4.w * b4.y; acc[3][2] += a4.w * b4.z; acc[3][3] += a4.w * b4.w;
        }
        __syncthreads();
    }
#pragma unroll
    for (int i = 0; i < 4; ++i) {
        int row = row0 + (ty << 2) + i;
        int c0 = col0 + (tx << 2);
        float4 o = make_float4(acc[i][0], acc[i][1], acc[i][2], acc[i][3]);
        if (bias) { o.x += bias[c0]; o.y += bias[c0 + 1]; o.z += bias[c0 + 2]; o.w += bias[c0 + 3]; }
        float* cp = C + (long long)row * ldc + c0;
        if (accum) { float4 p = *(float4*)cp; o.x += p.x; o.y += p.y; o.z += p.z; o.w += p.w; }
        if (relu) { o.x = fmaxf(o.x, 0.f); o.y = fmaxf(o.y, 0.f); o.z = fmaxf(o.z, 0.f); o.w = fmaxf(o.w, 0.f); }
        *(float4*)cp = o;
    }
}

// ---- weight prep ----
__global__ void split_w(const float* __restrict__ W, unsigned short* __restrict__ ohi,
    unsigned short* __restrict__ olo)
{
    int h = blockIdx.y;
    int idx = blockIdx.x * 256 + threadIdx.x;
    int r = idx >> 10, c = idx & 1023;
    float v = W[(size_t)r * HC3 + h * CC + c];
    unsigned short hh = f2bf(v);
    ohi[(size_t)h * 1048576 + idx] = hh;
    olo[(size_t)h * 1048576 + idx] = f2bf(v - bf2f(hh));
}

__global__ void transpose_split_wt(const float* __restrict__ Wt,
    unsigned short* __restrict__ ohi, unsigned short* __restrict__ olo)
{
    int h = blockIdx.z;
    __shared__ float tile[32][33];
    int t = threadIdx.x, tr = t >> 5, tc = t & 31;
    int r0 = blockIdx.y * 32, c0 = blockIdx.x * 32;
    const float* in = Wt + (size_t)h * 1048576;
#pragma unroll
    for (int i = 0; i < 4; ++i)
        tile[tr + i * 8][tc] = in[(size_t)(r0 + tr + i * 8) * CC + c0 + tc];
    __syncthreads();
    unsigned short* oh = ohi + (size_t)h * 1048576;
    unsigned short* ol = olo + (size_t)h * 1048576;
#pragma unroll
    for (int i = 0; i < 4; ++i) {
        int oc = c0 + tr + i * 8;
        int orr = r0 + tc;
        float v = tile[tc][tr + i * 8];
        unsigned short hh = f2bf(v);
        oh[(size_t)oc * CC + orr] = hh;
        ol[(size_t)oc * CC + orr] = f2bf(v - bf2f(hh));
    }
}

// split MHT[h][c][d] -> out[h*headOff + c*ldb + d]
__global__ void split_interleave(const float* __restrict__ in, unsigned short* __restrict__ ohi,
    unsigned short* __restrict__ olo, size_t headOff, int ldb)
{
    int h = blockIdx.y;
    int idx = blockIdx.x * 256 + threadIdx.x;
    int c = idx >> 10, d = idx & 1023;
    float v = in[(size_t)h * 1048576 + idx];
    unsigned short hh = f2bf(v);
    size_t dst = (size_t)h * headOff + (size_t)c * ldb + d;
    ohi[dst] = hh;
    olo[dst] = f2bf(v - bf2f(hh));
}

// ---- attention helper vectors ----
__global__ __launch_bounds__(256) void attvec(const float* __restrict__ W,
    const float* __restrict__ atts, const float* __restrict__ attd,
    float* __restrict__ asv, float* __restrict__ adv)
{
    int wid = blockIdx.x * 4 + (threadIdx.x >> 6);
    int lane = threadIdx.x & 63;
    int h = wid >> 10, kk = wid & 1023;
    const float* wr = W + (long long)kk * HC3 + h * CC;
    const float* sa = atts + h * CC;
    const float* da = attd + h * CC;
    float ss = 0.f, dd = 0.f;
    for (int c = lane; c < CC; c += 64) { float w = wr[c]; ss += w * sa[c]; dd += w * da[c]; }
    for (int off = 32; off; off >>= 1) { ss += __shfl_xor(ss, off, 64); dd += __shfl_xor(dd, off, 64); }
    if (lane == 0) { asv[h * CC + kk] = ss; adv[h * CC + kk] = dd; }
}

__global__ __launch_bounds__(256) void attn_dots(const float* __restrict__ xin,
    const float* __restrict__ asv, const float* __restrict__ adv,
    float* __restrict__ AS, float* __restrict__ AD, int n)
{
    int node = blockIdx.x * 4 + (threadIdx.x >> 6);
    int lane = threadIdx.x & 63;
    if (node >= n) return;
    const float* xr = xin + (long long)node * CC;
    float s0 = 0, s1 = 0, s2 = 0, d0 = 0, d1 = 0, d2 = 0;
    for (int j = lane; j < CC; j += 64) {
        float v = xr[j];
        s0 += v * asv[j]; s1 += v * asv[CC + j]; s2 += v * asv[2 * CC + j];
        d0 += v * adv[j]; d1 += v * adv[CC + j]; d2 += v * adv[2 * CC + j];
    }
    for (int off = 32; off; off >>= 1) {
        s0 += __shfl_xor(s0, off, 64); s1 += __shfl_xor(s1, off, 64); s2 += __shfl_xor(s2, off, 64);
        d0 += __shfl_xor(d0, off, 64); d1 += __shfl_xor(d1, off, 64); d2 += __shfl_xor(d2, off, 64);
    }
    if (lane == 0) {
        AS[node * 3 + 0] = s0; AS[node * 3 + 1] = s1; AS[node * 3 + 2] = s2;
        AD[node * 3 + 0] = d0; AD[node * 3 + 1] = d1; AD[node * 3 + 2] = d2;
    }
}

// bvec (blocks 0-3) + pnorm (block 4)
__global__ void bvec_pnorm(const float* __restrict__ b, const float* __restrict__ Wt,
    const float* __restrict__ bt, float* __restrict__ BV,
    const float* __restrict__ p, float* __restrict__ pn)
{
    if (blockIdx.x < 4) {
        int c = blockIdx.x * 256 + threadIdx.x;
        float acc = bt[c];
        for (int k = 0; k < HC3; ++k) acc += b[k] * Wt[(long long)k * CC + c];
        BV[c] = acc;
    } else {
        __shared__ float red[256];
        int t = threadIdx.x;
        float s = 0.f;
        for (int j = t; j < CC; j += 256) { float v = p[j]; s += v * v; }
        red[t] = s; __syncthreads();
        for (int off = 128; off; off >>= 1) { if (t < off) red[t] += red[t + off]; __syncthreads(); }
        if (t == 0) pn[0] = sqrtf(red[0]);
    }
}

// ---- per-node init: self-loop logits, segment-max seed, counters ----
__global__ void node_init_zero(const float* __restrict__ AS, const float* __restrict__ AD,
    float* __restrict__ sl, unsigned* __restrict__ mxe, int* __restrict__ cnt,
    int* __restrict__ cur, int n)
{
    int i = blockIdx.x * 256 + threadIdx.x;
    if (i >= n) return;
#pragma unroll
    for (int h = 0; h < 3; ++h) {
        float l = lrelu(AS[i * 3 + h] + AD[i * 3 + h]);
        sl[i * 3 + h] = l;
        mxe[i * 3 + h] = fenc(l);
    }
    cnt[i] = 0; cur[i] = 0;
}

// ---- fused edge pass 1: in-degree count + segment max ----
__global__ void edge_pass1(const int* __restrict__ src, const int* __restrict__ dst,
    const int* __restrict__ msk, const float* __restrict__ AS, const float* __restrict__ AD,
    unsigned* __restrict__ mxe, int* __restrict__ cnt)
{
    int e = blockIdx.x * 256 + threadIdx.x;
    if (e >= EE || !msk[e]) return;
    int s = src[e], d = dst[e];
    atomicAdd(&cnt[d], 1);
#pragma unroll
    for (int h = 0; h < 3; ++h) {
        float l = lrelu(AS[s * 3 + h] + AD[d * 3 + h]);
        atomicMax(&mxe[d * 3 + h], fenc(l));
    }
}

__global__ void scan_graph(const int* __restrict__ cnt, int* __restrict__ offs,
    int* __restrict__ gt, int npg)
{
    if (threadIdx.x != 0) return;
    int g = blockIdx.x, base = g * npg, run = 0;
    for (int i = 0; i < npg; ++i) { offs[base + i] = run; run += cnt[base + i]; }
    gt[g] = run;
}

__global__ void scan_base(const int* __restrict__ gt, int* __restrict__ gb)
{
    if (threadIdx.x != 0 || blockIdx.x != 0) return;
    int run = 0;
    for (int g = 0; g < NG; ++g) { gb[g] = run; run += gt[g]; }
}

__global__ void add_base(int* __restrict__ offs, const int* __restrict__ gb, int n, int npg)
{
    int i = blockIdx.x * 256 + threadIdx.x;
    if (i < n) offs[i] += gb[i / npg];
}

__global__ void decode_selfden(const unsigned* __restrict__ mxe, const float* __restrict__ sl,
    float* __restrict__ mxf, float* __restrict__ den, int n)
{
    int i = blockIdx.x * 256 + threadIdx.x;
    if (i >= n) return;
#pragma unroll
    for (int h = 0; h < 3; ++h) {
        float m = fdec(mxe[i * 3 + h]);
        mxf[i * 3 + h] = m;
        den[i * 3 + h] = expf(sl[i * 3 + h] - m);
    }
}

__global__ void edge_den(const int* __restrict__ src, const int* __restrict__ dst,
    const int* __restrict__ msk, const float* __restrict__ AS, const float* __restrict__ AD,
    const float* __restrict__ mxf, float* __restrict__ den)
{
    int e = blockIdx.x * 256 + threadIdx.x;
    if (e >= EE || !msk[e]) return;
    int s = src[e], d = dst[e];
#pragma unroll
    for (int h = 0; h < 3; ++h) {
        float l = lrelu(AS[s * 3 + h] + AD[d * 3 + h]);
        atomicAdd(&den[d * 3 + h], expf(l - mxf[d * 3 + h]));
    }
}

// ---- fused CSR fill + alpha (runs after den complete) ----
__global__ void fill_alpha(const int* __restrict__ src, const int* __restrict__ dst,
    const int* __restrict__ msk, const int* __restrict__ offs, int* __restrict__ cur,
    const float* __restrict__ AS, const float* __restrict__ AD,
    const float* __restrict__ mxf, const float* __restrict__ den,
    int* __restrict__ csrs, float* __restrict__ csra)
{
    int e = blockIdx.x * 256 + threadIdx.x;
    if (e >= EE || !msk[e]) return;
    int s = src[e], d = dst[e];
    int pos = offs[d] + atomicAdd(&cur[d], 1);
    csrs[pos] = s;
#pragma unroll
    for (int h = 0; h < 3; ++h) {
        float l = lrelu(AS[s * 3 + h] + AD[d * 3 + h]);
        float ex = expf(l - mxf[d * 3 + h]);
        csra[pos * 3 + h] = ex / (den[d * 3 + h] + 1e-16f);
    }
}

// ---- aggregation: all 3 heads in one pass, concat layout [n][3072] ----
__global__ __launch_bounds__(256) void aggregate3(const float* __restrict__ xin,
    const float* __restrict__ sl, const float* __restrict__ mxf, const float* __restrict__ den,
    const int* __restrict__ offs, const int* __restrict__ cnt,
    const int* __restrict__ csrs, const float* __restrict__ csra,
    unsigned short* __restrict__ ahi, unsigned short* __restrict__ alo)
{
    int i = blockIdx.x, t = threadIdx.x;
    float aself[3];
#pragma unroll
    for (int h = 0; h < 3; ++h)
        aself[h] = expf(sl[i * 3 + h] - mxf[i * 3 + h]) / (den[i * 3 + h] + 1e-16f);
    const float* xr = xin + (long long)i * CC;
    float acc[3][4];
#pragma unroll
    for (int j = 0; j < 4; ++j) {
        float v = xr[t + (j << 8)];
#pragma unroll
        for (int h = 0; h < 3; ++h) acc[h][j] = aself[h] * v;
    }
    int beg = offs[i], num = cnt[i];
    for (int e = 0; e < num; ++e) {
        int s = csrs[beg + e];
        float a0 = csra[(beg + e) * 3 + 0];
        float a1 = csra[(beg + e) * 3 + 1];
        float a2 = csra[(beg + e) * 3 + 2];
        const float* sr = xin + (long long)s * CC;
#pragma unroll
        for (int j = 0; j < 4; ++j) {
            float v = sr[t + (j << 8)];
            acc[0][j] += a0 * v; acc[1][j] += a1 * v; acc[2][j] += a2 * v;
        }
    }
#pragma unroll
    for (int h = 0; h < 3; ++h)
#pragma unroll
        for (int j = 0; j < 4; ++j) {
            int c = t + (j << 8);
            float v = acc[h][j];
            unsigned short hh = f2bf(v);
            size_t idx = (size_t)i * HC3 + h * CC + c;
            ahi[idx] = hh;
            alo[idx] = f2bf(v - bf2f(hh));
        }
}

// ---- per-head aggregation (fallback, [n][1024]) ----
__global__ __launch_bounds__(256) void aggregate_h(const float* __restrict__ xin,
    const float* __restrict__ sl, const float* __restrict__ mxf, const float* __restrict__ den,
    const int* __restrict__ offs, const int* __restrict__ cnt,
    const int* __restrict__ csrs, const float* __restrict__ csra,
    int h, unsigned short* __restrict__ ahi, unsigned short* __restrict__ alo)
{
    int i = blockIdx.x, t = threadIdx.x;
    float aself = expf(sl[i * 3 + h] - mxf[i * 3 + h]) / (den[i * 3 + h] + 1e-16f);
    const float* xr = xin + (long long)i * CC;
    float acc[4];
#pragma unroll
    for (int j = 0; j < 4; ++j) acc[j] = aself * xr[t + (j << 8)];
    int beg = offs[i], num = cnt[i];
    for (int e = 0; e < num; ++e) {
        int s = csrs[beg + e];
        float a = csra[(beg + e) * 3 + h];
        const float* sr = xin + (long long)s * CC;
#pragma unroll
        for (int j = 0; j < 4; ++j) acc[j] += a * sr[t + (j << 8)];
    }
#pragma unroll
    for (int j = 0; j < 4; ++j) {
        int c = t + (j << 8);
        float v = acc[j];
        unsigned short hh = f2bf(v);
        ahi[(size_t)i * CC + c] = hh;
        alo[(size_t)i * CC + c] = f2bf(v - bf2f(hh));
    }
}

// ---------------- TopK pooling ----------------
__global__ __launch_bounds__(256) void score_kernel(const float* __restrict__ h,
    const float* __restrict__ p, const float* __restrict__ pn, float* __restrict__ sc, int n)
{
    int wid = blockIdx.x * 4 + (threadIdx.x >> 6);
    int lane = threadIdx.x & 63;
    if (wid >= n) return;
    const float* hr = h + (long long)wid * CC;
    float s = 0.f;
    for (int j = lane; j < CC; j += 64) s += hr[j] * p[j];
    for (int off = 32; off; off >>= 1) s += __shfl_xor(s, off, 64);
    if (lane == 0) sc[wid] = tanhf(s / pn[0]);
}

// one wave per graph; newid init folded in; stable argmax matches lax.top_k
__global__ __launch_bounds__(64) void topk_kernel(const float* __restrict__ score,
    int npg, int k, int* __restrict__ perm, float* __restrict__ vals, int* __restrict__ newid)
{
    int g = blockIdx.x, lane = threadIdx.x;
    for (int idx = lane; idx < npg; idx += 64) newid[g * npg + idx] = -1;
    const float* sc = score + g * npg;
    float v[4];
    int nsl = (npg + 63) >> 6;
#pragma unroll
    for (int s2 = 0; s2 < 4; ++s2) {
        int idx = lane + (s2 << 6);
        v[s2] = (s2 < nsl && idx < npg) ? sc[idx] : -1e30f;
    }
    for (int j = 0; j < k; ++j) {
        float bv = -2e30f; int bi = 0x7fffffff;
#pragma unroll
        for (int s2 = 0; s2 < 4; ++s2) {
            int idx = lane + (s2 << 6);
            if (v[s2] > bv) { bv = v[s2]; bi = idx; }
        }
        for (int off = 32; off; off >>= 1) {
            float ov = __shfl_xor(bv, off, 64);
            int   oi = __shfl_xor(bi, off, 64);
            if (ov > bv || (ov == bv && oi < bi)) { bv = ov; bi = oi; }
        }
        if (lane == 0) {
            perm[g * k + j] = g * npg + bi;
            vals[g * k + j] = bv;
            newid[g * npg + bi] = g * k + j;
        }
        if ((bi & 63) == lane) v[bi >> 6] = -1e30f;
    }
}

__global__ __launch_bounds__(256) void gather_scale(const float* __restrict__ h,
    const int* __restrict__ perm, const float* __restrict__ vals, float* __restrict__ xn)
{
    int r = blockIdx.x, t = threadIdx.x;
    int pr = perm[r]; float v = vals[r];
    const float* s = h + (long long)pr * CC;
    float* d = xn + (long long)r * CC;
#pragma unroll
    for (int j = 0; j < 4; ++j) { int c = t + (j << 8); d[c] = s[c] * v; }
}

__global__ void remap_edges(int* __restrict__ s, int* __restrict__ d,
    int* __restrict__ m, const int* __restrict__ newid)
{
    int e = blockIdx.x * 256 + threadIdx.x;
    if (e >= EE) return;
    if (!m[e]) { s[e] = 0; d[e] = 0; return; }
    int ns = newid[s[e]], nd = newid[d[e]];
    int nm = (ns >= 0 && nd >= 0) ? 1 : 0;
    m[e] = nm; s[e] = nm ? ns : 0; d[e] = nm ? nd : 0;
}

// ---- two-pass readout ----
__global__ __launch_bounds__(256) void readout_part(const float* __restrict__ xn,
    int k, float* __restrict__ PM, float* __restrict__ PS)
{
    int g = blockIdx.x, ch = blockIdx.y, t = threadIdx.x;
    int rpc = k >> 3, r0 = ch * rpc;
#pragma unroll
    for (int j = 0; j < 4; ++j) {
        int c = t + (j << 8);
        float mx = -1e30f, sm = 0.f;
        for (int r = r0; r < r0 + rpc; ++r) {
            float vv = xn[((size_t)(g * k + r)) * CC + c];
            mx = fmaxf(mx, vv); sm += vv;
        }
        PM[(size_t)(g * 8 + ch) * CC + c] = mx;
        PS[(size_t)(g * 8 + ch) * CC + c] = sm;
    }
}

__global__ __launch_bounds__(256) void readout_fin(const float* __restrict__ PM,
    const float* __restrict__ PS, int k, float* __restrict__ R)
{
    int g = blockIdx.x, t = threadIdx.x;
#pragma unroll
    for (int j = 0; j < 4; ++j) {
        int c = t + (j << 8);
        float mx = -1e30f, sm = 0.f;
#pragma unroll
        for (int ch = 0; ch < 8; ++ch) {
            mx = fmaxf(mx, PM[(size_t)(g * 8 + ch) * CC + c]);
            sm += PS[(size_t)(g * 8 + ch) * CC + c];
        }
        R[g * 2048 + c] = mx;
        R[g * 2048 + 1024 + c] = sm / (float)k;
    }
}

__global__ void copy_edges(const int* __restrict__ ei, int* __restrict__ s,
    int* __restrict__ d, int* __restrict__ m)
{
    int e = blockIdx.x * 256 + threadIdx.x;
    if (e >= EE) return;
    s[e] = ei[e]; d[e] = ei[EE + e]; m[e] = 1;
}

// ---------------- final MLP ----------------
__global__ void zsum(const float* __restrict__ a, const float* __restrict__ b,
    const float* __restrict__ c, float* __restrict__ z)
{
    int i = blockIdx.x * 256 + threadIdx.x;
    if (i < NG * 2048) z[i] = a[i] + b[i] + c[i];
}

__global__ __launch_bounds__(64) void mlp2_kernel(const float* __restrict__ Z1,
    const float* __restrict__ Wl2, const float* __restrict__ bl2, float* __restrict__ out)
{
    int b = blockIdx.x; int g = b >> 1, o = b & 1;
    int lane = threadIdx.x;
    const float* zr = Z1 + g * 1024;
    float s = 0.f;
    for (int j = lane; j < 1024; j += 64) s += zr[j] * Wl2[j * 2 + o];
    for (int off = 32; off; off >>= 1) s += __shfl_xor(s, off, 64);
    if (lane == 0) out[g * 2 + o] = s + bl2[o];
}

// ---------------- host ----------------
extern "C" void kernel_launch(void* const* d_in, const int* in_sizes, int n_in,
                              void* d_out, int out_size, void* d_ws, size_t ws_size,
                              hipStream_t stream)
{
    const float* x   = (const float*)d_in[0];
    const int*   ei  = (const int*)d_in[2];
    const float* W[3]    = {(const float*)d_in[4],  (const float*)d_in[11], (const float*)d_in[18]};
    const float* atts[3] = {(const float*)d_in[5],  (const float*)d_in[12], (const float*)d_in[19]};
    const float* attd[3] = {(const float*)d_in[6],  (const float*)d_in[13], (const float*)d_in[20]};
    const float* bb[3]   = {(const float*)d_in[7],  (const float*)d_in[14], (const float*)d_in[21]};
    const float* Wt[3]   = {(const float*)d_in[8],  (const float*)d_in[15], (const float*)d_in[22]};
    const float* bt[3]   = {(const float*)d_in[9],  (const float*)d_in[16], (const float*)d_in[23]};
    const float* pv[3]   = {(const float*)d_in[10], (const float*)d_in[17], (const float*)d_in[24]};
    const float* Wl1 = (const float*)d_in[25];
    const float* bl1 = (const float*)d_in[26];
    const float* Wl2 = (const float*)d_in[27];
    const float* bl2 = (const float*)d_in[28];
    float* out = (float*)d_out;

    // concat path needs ~320 MB; fallback ~185 MB (round-3-proven)
    const bool concat = ws_size >= (size_t)340 * 1024 * 1024;

    char* wp = (char*)d_ws;
    auto carve = [&](size_t bytes) -> void* {
        void* p = (void*)wp;
        wp += (bytes + 255) & ~(size_t)255;
        return p;
    };
    const int NMAX = 12800;
    const size_t MSZ = (size_t)CC * CC;
    const size_t AW = concat ? HC3 : CC;   // A2 width
    unsigned short* A2H = (unsigned short*)carve((size_t)NMAX * AW * 2);
    unsigned short* A2L = (unsigned short*)carve((size_t)NMAX * AW * 2);
    float* Hb   = (float*)carve((size_t)NMAX * CC * 4);
    float* XN   = (float*)carve((size_t)10240 * CC * 4);
    unsigned short* B2H = (unsigned short*)carve((size_t)3 * MSZ * 2);
    unsigned short* B2L = (unsigned short*)carve((size_t)3 * MSZ * 2);
    unsigned short* WTH = (unsigned short*)carve((size_t)3 * MSZ * 2);
    unsigned short* WTL = (unsigned short*)carve((size_t)3 * MSZ * 2);
    unsigned short* WSH = (unsigned short*)carve((size_t)3 * MSZ * 2);
    unsigned short* WSL = (unsigned short*)carve((size_t)3 * MSZ * 2);
    float* MHT  = (float*)carve((size_t)3 * MSZ * 4);
    float* PM   = (float*)carve((size_t)NG * 8 * CC * 4);
    float* PS   = (float*)carve((size_t)NG * 8 * CC * 4);
    float* ASV  = (float*)carve((size_t)3 * CC * 4);
    float* ADV  = (float*)carve((size_t)3 * CC * 4);
    float* BV   = (float*)carve((size_t)CC * 4);
    float* AS   = (float*)carve((size_t)NMAX * 3 * 4);
    float* AD   = (float*)carve((size_t)NMAX * 3 * 4);
    float* SL   = (float*)carve((size_t)NMAX * 3 * 4);
    unsigned* MXE = (unsigned*)carve((size_t)NMAX * 3 * 4);
    float* MXF  = (float*)carve((size_t)NMAX * 3 * 4);
    float* DEN  = (float*)carve((size_t)NMAX * 3 * 4);
    int* CNT    = (int*)carve((size_t)NMAX * 4);
    int* OFFS   = (int*)carve((size_t)NMAX * 4);
    int* CUR    = (int*)carve((size_t)NMAX * 4);
    int* NEWID  = (int*)carve((size_t)NMAX * 4);
    int* GT     = (int*)carve((size_t)NG * 4);
    int* GB     = (int*)carve((size_t)NG * 4);
    int* CSRS   = (int*)carve((size_t)EE * 4);
    float* CSRA = (float*)carve((size_t)EE * 3 * 4);
    int* SRC = (int*)carve((size_t)EE * 4);
    int* DST = (int*)carve((size_t)EE * 4);
    int* MK  = (int*)carve((size_t)EE * 4);
    int* PERM  = (int*)carve((size_t)10240 * 4);
    float* VALS = (float*)carve((size_t)10240 * 4);
    float* SCORE = (float*)carve((size_t)NMAX * 4);
    float* PN = (float*)carve(256);
    float* R0 = (float*)carve((size_t)NG * 2048 * 4);
    float* R1 = (float*)carve((size_t)NG * 2048 * 4);
    float* R2 = (float*)carve((size_t)NG * 2048 * 4);
    float* Z  = (float*)carve((size_t)NG * 2048 * 4);
    float* Z1 = (float*)carve((size_t)NG * 1024 * 4);
    float* Rarr[3] = {R0, R1, R2};
    (void)in_sizes; (void)n_in; (void)out_size;

    copy_edges<<<cdiv(EE, 256), 256, 0, stream>>>(ei, SRC, DST, MK);

    const int ns_[3]  = {12800, 10240, 5120};
    const int npg_[3] = {200, 160, 80};
    const int kk_[3]  = {160, 80, 16};
    const float* xin = x;

    for (int L = 0; L < 3; ++L) {
        int n = ns_[L], npg = npg_[L], k = kk_[L];
        // attention vectors + per-node coefficients + folded bias + pnorm
        attvec<<<768, 256, 0, stream>>>(W[L], atts[L], attd[L], ASV, ADV);
        attn_dots<<<n / 4, 256, 0, stream>>>(xin, ASV, ADV, AS, AD, n);
        bvec_pnorm<<<5, 256, 0, stream>>>(bb[L], Wt[L], bt[L], BV, pv[L], PN);
        // fused per-head weight M_h^T (batched over heads)
        split_w<<<dim3(4096, 3), 256, 0, stream>>>(W[L], WSH, WSL);
        transpose_split_wt<<<dim3(32, 32, 3), 256, 0, stream>>>(Wt[L], WTH, WTL);
        gemm_split<<<dim3(8, 8, 3), 256, 0, stream>>>(WTH, WTL, CC, WSH, WSL, CC,
            nullptr, MHT, CC, CC, MSZ, MSZ, MSZ, 0);
        if (concat)
            split_interleave<<<dim3(4096, 3), 256, 0, stream>>>(MHT, B2H, B2L, CC, HC3);
        else
            split_interleave<<<dim3(4096, 3), 256, 0, stream>>>(MHT, B2H, B2L, MSZ, CC);
        // CSR + segment softmax
        node_init_zero<<<cdiv(n, 256), 256, 0, stream>>>(AS, AD, SL, MXE, CNT, CUR, n);
        edge_pass1<<<cdiv(EE, 256), 256, 0, stream>>>(SRC, DST, MK, AS, AD, MXE, CNT);
        scan_graph<<<NG, 64, 0, stream>>>(CNT, OFFS, GT, npg);
        scan_base<<<1, 64, 0, stream>>>(GT, GB);
        add_base<<<cdiv(n, 256), 256, 0, stream>>>(OFFS, GB, n, npg);
        decode_selfden<<<cdiv(n, 256), 256, 0, stream>>>(MXE, SL, MXF, DEN, n);
        edge_den<<<cdiv(EE, 256), 256, 0, stream>>>(SRC, DST, MK, AS, AD, MXF, DEN);
        fill_alpha<<<cdiv(EE, 256), 256, 0, stream>>>(SRC, DST, MK, OFFS, CUR,
                                                      AS, AD, MXF, DEN, CSRS, CSRA);
        // aggregate + linear
        if (concat) {
            aggregate3<<<n, 256, 0, stream>>>(xin, SL, MXF, DEN, OFFS, CNT, CSRS, CSRA,
                                              A2H, A2L);
            gemm_split<<<dim3(8, n / 128, 1), 256, 0, stream>>>(A2H, A2L, HC3,
                B2H, B2L, HC3, BV, Hb, CC, HC3, 0, 0, 0, 0);
        } else {
            for (int h = 0; h < 3; ++h) {
                aggregate_h<<<n, 256, 0, stream>>>(xin, SL, MXF, DEN, OFFS, CNT, CSRS, CSRA,
                                                   h, A2H, A2L);
                gemm_split<<<dim3(8, n / 128, 1), 256, 0, stream>>>(A2H, A2L, CC,
                    B2H + (size_t)h * MSZ, B2L + (size_t)h * MSZ, CC,
                    (h == 0) ? BV : nullptr, Hb, CC, CC, 0, 0, 0, (h > 0) ? 1 : 0);
            }
        }
        // TopK pooling + readout
        score_kernel<<<n / 4, 256, 0, stream>>>(Hb, pv[L], PN, SCORE, n);
        topk_kernel<<<NG, 64, 0, stream>>>(SCORE, npg, k, PERM, VALS, NEWID);
        gather_scale<<<NG * k, 256, 0, stream>>>(Hb, PERM, VALS, XN);
        readout_part<<<dim3(NG, 8), 256, 0, stream>>>(XN, k, PM, PS);
        readout_fin<<<NG, 256, 0, stream>>>(PM, PS, k, Rarr[L]);
        if (L < 2) remap_edges<<<cdiv(EE, 256), 256, 0, stream>>>(SRC, DST, MK, NEWID);
        xin = XN;
    }

    // final MLP
    zsum<<<cdiv(NG * 2048, 256), 256, 0, stream>>>(R0, R1, R2, Z);
    gemm64<<<dim3(16, 1), 256, 0, stream>>>(Z, 2048, Wl1, 1024, bl1, Z1, 1024, 64, 1024, 2048, 0, 1);
    mlp2_kernel<<<NG * 2, 64, 0, stream>>>(Z1, Wl2, bl2, out);
}

// Round 5
// 1936.797 us; speedup vs baseline: 2.6024x; 1.2936x over previous
//
#include <hip/hip_runtime.h>
#include <math.h>

// Static problem dims
#define NG 64          // graphs
#define EE 64000       // edges
#define HC3 3072       // H*C
#define CC 1024        // C (and input feature dim)

static inline int cdiv(int a, int b) { return (a + b - 1) / b; }

typedef float f4_t __attribute__((ext_vector_type(4)));
typedef short s8_t __attribute__((ext_vector_type(8)));

__device__ __forceinline__ float lrelu(float x) { return x > 0.f ? x : 0.2f * x; }
__device__ __forceinline__ unsigned fenc(float f) {
    unsigned u = __float_as_uint(f);
    return (u & 0x80000000u) ? ~u : (u | 0x80000000u);
}
__device__ __forceinline__ float fdec(unsigned e) {
    return (e & 0x80000000u) ? __uint_as_float(e ^ 0x80000000u) : __uint_as_float(~e);
}
__device__ __forceinline__ unsigned short f2bf(float f) {
    unsigned u = __float_as_uint(f);
    u += 0x7fffu + ((u >> 16) & 1u);
    return (unsigned short)(u >> 16);
}
__device__ __forceinline__ float bf2f(unsigned short h) {
    return __uint_as_float(((unsigned)h) << 16);
}
__device__ __forceinline__ void gll16(const unsigned short* g, unsigned short* l) {
    __builtin_amdgcn_global_load_lds(
        (const __attribute__((address_space(1))) void*)g,
        (__attribute__((address_space(3))) void*)l, 16, 0, 0);
}

// ======== MFMA split-bf16 GEMM: C[M,N] = (Ahi+Alo)[M,K] @ (Bhi+Blo)[N,K]^T ========
// optional bias[col], optional per-row scale (applied after bias)
__global__ __launch_bounds__(256) void gemm_split(
    const unsigned short* __restrict__ Ahi, const unsigned short* __restrict__ Alo, int lda,
    const unsigned short* __restrict__ Bhi, const unsigned short* __restrict__ Blo, int ldb,
    const float* __restrict__ bias, const float* __restrict__ rowscale,
    float* __restrict__ C, int ldc, int K,
    size_t zsA, size_t zsB, size_t zsC)
{
    __shared__ unsigned short sAH[128 * 32];
    __shared__ unsigned short sAL[128 * 32];
    __shared__ unsigned short sBH[128 * 32];
    __shared__ unsigned short sBL[128 * 32];

    Ahi += blockIdx.z * zsA; Alo += blockIdx.z * zsA;
    Bhi += blockIdx.z * zsB; Blo += blockIdx.z * zsB;
    C   += blockIdx.z * zsC;

    const int t = threadIdx.x;
    const int w = t >> 6, lane = t & 63;
    const int wr = w >> 1, wc = w & 1;
    const int row0 = blockIdx.y * 128, col0 = blockIdx.x * 128;

    const int srow = w * 16 + (lane >> 2);
    const int skg = (lane & 3) * 8;
    const size_t aoff0 = (size_t)(row0 + srow) * lda + skg;
    const size_t aoff1 = (size_t)(row0 + 64 + srow) * lda + skg;
    const size_t boff0 = (size_t)(col0 + srow) * ldb + skg;
    const size_t boff1 = (size_t)(col0 + 64 + srow) * ldb + skg;
    const int l0 = (w * 16) * 32;
    const int l1 = (64 + w * 16) * 32;

    f4_t acc[4][4];
    const f4_t z4 = {0.f, 0.f, 0.f, 0.f};
#pragma unroll
    for (int i = 0; i < 4; ++i)
#pragma unroll
        for (int j = 0; j < 4; ++j) acc[i][j] = z4;

    const int mrow0 = wr * 64 + (lane & 15);
    const int nrow0 = wc * 64 + (lane & 15);
    const int koff = (lane >> 4) * 8;

    for (int k0 = 0; k0 < K; k0 += 32) {
        gll16(Ahi + aoff0 + k0, &sAH[l0]);
        gll16(Ahi + aoff1 + k0, &sAH[l1]);
        gll16(Alo + aoff0 + k0, &sAL[l0]);
        gll16(Alo + aoff1 + k0, &sAL[l1]);
        gll16(Bhi + boff0 + k0, &sBH[l0]);
        gll16(Bhi + boff1 + k0, &sBH[l1]);
        gll16(Blo + boff0 + k0, &sBL[l0]);
        gll16(Blo + boff1 + k0, &sBL[l1]);
        __syncthreads();

        s8_t ah[4], al[4], bh[4], bl[4];
#pragma unroll
        for (int mt = 0; mt < 4; ++mt) {
            ah[mt] = *(const s8_t*)&sAH[(mrow0 + mt * 16) * 32 + koff];
            al[mt] = *(const s8_t*)&sAL[(mrow0 + mt * 16) * 32 + koff];
        }
#pragma unroll
        for (int nt = 0; nt < 4; ++nt) {
            bh[nt] = *(const s8_t*)&sBH[(nrow0 + nt * 16) * 32 + koff];
            bl[nt] = *(const s8_t*)&sBL[(nrow0 + nt * 16) * 32 + koff];
        }
#pragma unroll
        for (int mt = 0; mt < 4; ++mt)
#pragma unroll
            for (int nt = 0; nt < 4; ++nt) {
                acc[mt][nt] = __builtin_amdgcn_mfma_f32_16x16x32_bf16(ah[mt], bh[nt], acc[mt][nt], 0, 0, 0);
                acc[mt][nt] = __builtin_amdgcn_mfma_f32_16x16x32_bf16(ah[mt], bl[nt], acc[mt][nt], 0, 0, 0);
                acc[mt][nt] = __builtin_amdgcn_mfma_f32_16x16x32_bf16(al[mt], bh[nt], acc[mt][nt], 0, 0, 0);
            }
        __syncthreads();
    }

#pragma unroll
    for (int mt = 0; mt < 4; ++mt) {
        int row = row0 + wr * 64 + mt * 16 + (lane >> 4) * 4;
#pragma unroll
        for (int nt = 0; nt < 4; ++nt) {
            int col = col0 + wc * 64 + nt * 16 + (lane & 15);
            float b = bias ? bias[col] : 0.f;
#pragma unroll
            for (int r = 0; r < 4; ++r) {
                float v = acc[mt][nt][r] + b;
                if (rowscale) v *= rowscale[row + r];
                C[(size_t)(row + r) * ldc + col] = v;
            }
        }
    }
}

// ---- weight prep ----
__global__ void split_w(const float* __restrict__ W, unsigned short* __restrict__ ohi,
    unsigned short* __restrict__ olo)
{
    int h = blockIdx.y;
    int idx = blockIdx.x * 256 + threadIdx.x;
    int r = idx >> 10, c = idx & 1023;
    float v = W[(size_t)r * HC3 + h * CC + c];
    unsigned short hh = f2bf(v);
    ohi[(size_t)h * 1048576 + idx] = hh;
    olo[(size_t)h * 1048576 + idx] = f2bf(v - bf2f(hh));
}

__global__ void transpose_split_wt(const float* __restrict__ Wt,
    unsigned short* __restrict__ ohi, unsigned short* __restrict__ olo)
{
    int h = blockIdx.z;
    __shared__ float tile[32][33];
    int t = threadIdx.x, tr = t >> 5, tc = t & 31;
    int r0 = blockIdx.y * 32, c0 = blockIdx.x * 32;
    const float* in = Wt + (size_t)h * 1048576;
#pragma unroll
    for (int i = 0; i < 4; ++i)
        tile[tr + i * 8][tc] = in[(size_t)(r0 + tr + i * 8) * CC + c0 + tc];
    __syncthreads();
    unsigned short* oh = ohi + (size_t)h * 1048576;
    unsigned short* ol = olo + (size_t)h * 1048576;
#pragma unroll
    for (int i = 0; i < 4; ++i) {
        int oc = c0 + tr + i * 8;
        int orr = r0 + tc;
        float v = tile[tc][tr + i * 8];
        unsigned short hh = f2bf(v);
        oh[(size_t)oc * CC + orr] = hh;
        ol[(size_t)oc * CC + orr] = f2bf(v - bf2f(hh));
    }
}

// split MHT[h][c][d] -> B2[h*headOff + c*ldb + d] (concat: headOff=CC, ldb=HC3)
__global__ void split_interleave(const float* __restrict__ in, unsigned short* __restrict__ ohi,
    unsigned short* __restrict__ olo, size_t headOff, int ldb)
{
    int h = blockIdx.y;
    int idx = blockIdx.x * 256 + threadIdx.x;
    int c = idx >> 10, d = idx & 1023;
    float v = in[(size_t)h * 1048576 + idx];
    unsigned short hh = f2bf(v);
    size_t dst = (size_t)h * headOff + (size_t)c * ldb + d;
    ohi[dst] = hh;
    olo[dst] = f2bf(v - bf2f(hh));
}

// ---- q[h*CC+d] = sum_c MHT[h][c][d] * p[c]  (partials via atomicAdd) ----
__global__ void qzero(float* __restrict__ q) {
    int i = blockIdx.x * 256 + threadIdx.x;
    if (i < HC3) q[i] = 0.f;
}
__global__ void qvec(const float* __restrict__ MHT, const float* __restrict__ p,
    float* __restrict__ q)
{
    int h = blockIdx.z;
    int d = blockIdx.x * 256 + threadIdx.x;    // 0..1023
    int c0 = blockIdx.y * 128;
    const float* m = MHT + (size_t)h * 1048576 + (size_t)c0 * CC + d;
    float s = 0.f;
#pragma unroll 8
    for (int c = 0; c < 128; ++c) s += m[(size_t)c * CC] * p[c0 + c];
    atomicAdd(&q[h * CC + d], s);
}

// ---- attention helper vectors ----
__global__ __launch_bounds__(256) void attvec(const float* __restrict__ W,
    const float* __restrict__ atts, const float* __restrict__ attd,
    float* __restrict__ asv, float* __restrict__ adv)
{
    int wid = blockIdx.x * 4 + (threadIdx.x >> 6);
    int lane = threadIdx.x & 63;
    int h = wid >> 10, kk = wid & 1023;
    const float* wr = W + (long long)kk * HC3 + h * CC;
    const float* sa = atts + h * CC;
    const float* da = attd + h * CC;
    float ss = 0.f, dd = 0.f;
    for (int c = lane; c < CC; c += 64) { float w = wr[c]; ss += w * sa[c]; dd += w * da[c]; }
    for (int off = 32; off; off >>= 1) { ss += __shfl_xor(ss, off, 64); dd += __shfl_xor(dd, off, 64); }
    if (lane == 0) { asv[h * CC + kk] = ss; adv[h * CC + kk] = dd; }
}

// ---- per-node: a_s, a_d (att) and t (score dots), 9 reductions in one pass ----
__global__ __launch_bounds__(256) void attn_dots_t(const float* __restrict__ xin,
    const float* __restrict__ asv, const float* __restrict__ adv, const float* __restrict__ q,
    float* __restrict__ AS, float* __restrict__ AD, float* __restrict__ T3, int n)
{
    int node = blockIdx.x * 4 + (threadIdx.x >> 6);
    int lane = threadIdx.x & 63;
    if (node >= n) return;
    const float* xr = xin + (long long)node * CC;
    float s0 = 0, s1 = 0, s2 = 0, d0 = 0, d1 = 0, d2 = 0, t0 = 0, t1 = 0, t2 = 0;
    for (int j = lane; j < CC; j += 64) {
        float v = xr[j];
        s0 += v * asv[j]; s1 += v * asv[CC + j]; s2 += v * asv[2 * CC + j];
        d0 += v * adv[j]; d1 += v * adv[CC + j]; d2 += v * adv[2 * CC + j];
        t0 += v * q[j];   t1 += v * q[CC + j];   t2 += v * q[2 * CC + j];
    }
    for (int off = 32; off; off >>= 1) {
        s0 += __shfl_xor(s0, off, 64); s1 += __shfl_xor(s1, off, 64); s2 += __shfl_xor(s2, off, 64);
        d0 += __shfl_xor(d0, off, 64); d1 += __shfl_xor(d1, off, 64); d2 += __shfl_xor(d2, off, 64);
        t0 += __shfl_xor(t0, off, 64); t1 += __shfl_xor(t1, off, 64); t2 += __shfl_xor(t2, off, 64);
    }
    if (lane == 0) {
        AS[node * 3 + 0] = s0; AS[node * 3 + 1] = s1; AS[node * 3 + 2] = s2;
        AD[node * 3 + 0] = d0; AD[node * 3 + 1] = d1; AD[node * 3 + 2] = d2;
        T3[node * 3 + 0] = t0; T3[node * 3 + 1] = t1; T3[node * 3 + 2] = t2;
    }
}

// bvec (blocks 0-3) + pnorm (block 4)
__global__ void bvec_pnorm(const float* __restrict__ b, const float* __restrict__ Wt,
    const float* __restrict__ bt, float* __restrict__ BV,
    const float* __restrict__ p, float* __restrict__ pn)
{
    if (blockIdx.x < 4) {
        int c = blockIdx.x * 256 + threadIdx.x;
        float acc = bt[c];
        for (int k = 0; k < HC3; ++k) acc += b[k] * Wt[(long long)k * CC + c];
        BV[c] = acc;
    } else {
        __shared__ float red[256];
        int t = threadIdx.x;
        float s = 0.f;
        for (int j = t; j < CC; j += 256) { float v = p[j]; s += v * v; }
        red[t] = s; __syncthreads();
        for (int off = 128; off; off >>= 1) { if (t < off) red[t] += red[t + off]; __syncthreads(); }
        if (t == 0) pn[0] = sqrtf(red[0]);
    }
}

// bvp = BV . p
__global__ void bvp_kernel(const float* __restrict__ BV, const float* __restrict__ p,
    float* __restrict__ bvp)
{
    __shared__ float red[256];
    int t = threadIdx.x;
    float s = 0.f;
    for (int j = t; j < CC; j += 256) s += BV[j] * p[j];
    red[t] = s; __syncthreads();
    for (int off = 128; off; off >>= 1) { if (t < off) red[t] += red[t + off]; __syncthreads(); }
    if (t == 0) bvp[0] = red[0];
}

// ---- per-node init ----
__global__ void node_init_zero(const float* __restrict__ AS, const float* __restrict__ AD,
    float* __restrict__ sl, unsigned* __restrict__ mxe, int* __restrict__ cnt,
    int* __restrict__ cur, int n)
{
    int i = blockIdx.x * 256 + threadIdx.x;
    if (i >= n) return;
#pragma unroll
    for (int h = 0; h < 3; ++h) {
        float l = lrelu(AS[i * 3 + h] + AD[i * 3 + h]);
        sl[i * 3 + h] = l;
        mxe[i * 3 + h] = fenc(l);
    }
    cnt[i] = 0; cur[i] = 0;
}

// ---- fused edge pass 1: in-degree count + segment max ----
__global__ void edge_pass1(const int* __restrict__ src, const int* __restrict__ dst,
    const int* __restrict__ msk, const float* __restrict__ AS, const float* __restrict__ AD,
    unsigned* __restrict__ mxe, int* __restrict__ cnt)
{
    int e = blockIdx.x * 256 + threadIdx.x;
    if (e >= EE || !msk[e]) return;
    int s = src[e], d = dst[e];
    atomicAdd(&cnt[d], 1);
#pragma unroll
    for (int h = 0; h < 3; ++h) {
        float l = lrelu(AS[s * 3 + h] + AD[d * 3 + h]);
        atomicMax(&mxe[d * 3 + h], fenc(l));
    }
}

__global__ void scan_graph(const int* __restrict__ cnt, int* __restrict__ offs,
    int* __restrict__ gt, int npg)
{
    if (threadIdx.x != 0) return;
    int g = blockIdx.x, base = g * npg, run = 0;
    for (int i = 0; i < npg; ++i) { offs[base + i] = run; run += cnt[base + i]; }
    gt[g] = run;
}

__global__ void scan_base(const int* __restrict__ gt, int* __restrict__ gb)
{
    if (threadIdx.x != 0 || blockIdx.x != 0) return;
    int run = 0;
    for (int g = 0; g < NG; ++g) { gb[g] = run; run += gt[g]; }
}

__global__ void add_base(int* __restrict__ offs, const int* __restrict__ gb, int n, int npg)
{
    int i = blockIdx.x * 256 + threadIdx.x;
    if (i < n) offs[i] += gb[i / npg];
}

__global__ void decode_selfden(const unsigned* __restrict__ mxe, const float* __restrict__ sl,
    float* __restrict__ mxf, float* __restrict__ den, int n)
{
    int i = blockIdx.x * 256 + threadIdx.x;
    if (i >= n) return;
#pragma unroll
    for (int h = 0; h < 3; ++h) {
        float m = fdec(mxe[i * 3 + h]);
        mxf[i * 3 + h] = m;
        den[i * 3 + h] = expf(sl[i * 3 + h] - m);
    }
}

__global__ void edge_den(const int* __restrict__ src, const int* __restrict__ dst,
    const int* __restrict__ msk, const float* __restrict__ AS, const float* __restrict__ AD,
    const float* __restrict__ mxf, float* __restrict__ den)
{
    int e = blockIdx.x * 256 + threadIdx.x;
    if (e >= EE || !msk[e]) return;
    int s = src[e], d = dst[e];
#pragma unroll
    for (int h = 0; h < 3; ++h) {
        float l = lrelu(AS[s * 3 + h] + AD[d * 3 + h]);
        atomicAdd(&den[d * 3 + h], expf(l - mxf[d * 3 + h]));
    }
}

__global__ void fill_alpha(const int* __restrict__ src, const int* __restrict__ dst,
    const int* __restrict__ msk, const int* __restrict__ offs, int* __restrict__ cur,
    const float* __restrict__ AS, const float* __restrict__ AD,
    const float* __restrict__ mxf, const float* __restrict__ den,
    int* __restrict__ csrs, float* __restrict__ csra)
{
    int e = blockIdx.x * 256 + threadIdx.x;
    if (e >= EE || !msk[e]) return;
    int s = src[e], d = dst[e];
    int pos = offs[d] + atomicAdd(&cur[d], 1);
    csrs[pos] = s;
#pragma unroll
    for (int h = 0; h < 3; ++h) {
        float l = lrelu(AS[s * 3 + h] + AD[d * 3 + h]);
        float ex = expf(l - mxf[d * 3 + h]);
        csra[pos * 3 + h] = ex / (den[d * 3 + h] + 1e-16f);
    }
}

// ---- score via scalar CSR pass: score_i = tanh((sum alpha*t + bvp)/||p||) ----
__global__ void score_csr(const float* __restrict__ T3,
    const float* __restrict__ sl, const float* __restrict__ mxf, const float* __restrict__ den,
    const int* __restrict__ offs, const int* __restrict__ cnt, const int* __restrict__ csrs,
    const float* __restrict__ csra, const float* __restrict__ bvp, const float* __restrict__ pn,
    float* __restrict__ score, int n)
{
    int i = blockIdx.x * 256 + threadIdx.x;
    if (i >= n) return;
    float s = 0.f;
#pragma unroll
    for (int h = 0; h < 3; ++h) {
        float aself = expf(sl[i * 3 + h] - mxf[i * 3 + h]) / (den[i * 3 + h] + 1e-16f);
        s += aself * T3[i * 3 + h];
    }
    int beg = offs[i], num = cnt[i];
    for (int e = 0; e < num; ++e) {
        int sn = csrs[beg + e];
#pragma unroll
        for (int h = 0; h < 3; ++h) s += csra[(beg + e) * 3 + h] * T3[sn * 3 + h];
    }
    score[i] = tanhf((s + bvp[0]) / pn[0]);
}

// one wave per graph; newid init folded; stable argmax matches lax.top_k
__global__ __launch_bounds__(64) void topk_kernel(const float* __restrict__ score,
    int npg, int k, int* __restrict__ perm, float* __restrict__ vals, int* __restrict__ newid)
{
    int g = blockIdx.x, lane = threadIdx.x;
    for (int idx = lane; idx < npg; idx += 64) newid[g * npg + idx] = -1;
    const float* sc = score + g * npg;
    float v[4];
    int nsl = (npg + 63) >> 6;
#pragma unroll
    for (int s2 = 0; s2 < 4; ++s2) {
        int idx = lane + (s2 << 6);
        v[s2] = (s2 < nsl && idx < npg) ? sc[idx] : -1e30f;
    }
    for (int j = 0; j < k; ++j) {
        float bv = -2e30f; int bi = 0x7fffffff;
#pragma unroll
        for (int s2 = 0; s2 < 4; ++s2) {
            int idx = lane + (s2 << 6);
            if (v[s2] > bv) { bv = v[s2]; bi = idx; }
        }
        for (int off = 32; off; off >>= 1) {
            float ov = __shfl_xor(bv, off, 64);
            int   oi = __shfl_xor(bi, off, 64);
            if (ov > bv || (ov == bv && oi < bi)) { bv = ov; bi = oi; }
        }
        if (lane == 0) {
            perm[g * k + j] = g * npg + bi;
            vals[g * k + j] = bv;
            newid[g * npg + bi] = g * k + j;
        }
        if ((bi & 63) == lane) v[bi >> 6] = -1e30f;
    }
}

// ---- aggregation of SELECTED rows only, all 3 heads, concat split-bf16 [Gk][3072] ----
__global__ __launch_bounds__(256) void aggregate_sel(const float* __restrict__ xin,
    const float* __restrict__ sl, const float* __restrict__ mxf, const float* __restrict__ den,
    const int* __restrict__ offs, const int* __restrict__ cnt,
    const int* __restrict__ csrs, const float* __restrict__ csra,
    const int* __restrict__ perm,
    unsigned short* __restrict__ ahi, unsigned short* __restrict__ alo)
{
    int r = blockIdx.x, t = threadIdx.x;
    int i = perm[r];
    float aself[3];
#pragma unroll
    for (int h = 0; h < 3; ++h)
        aself[h] = expf(sl[i * 3 + h] - mxf[i * 3 + h]) / (den[i * 3 + h] + 1e-16f);
    const float* xr = xin + (long long)i * CC;
    float acc[3][4];
#pragma unroll
    for (int j = 0; j < 4; ++j) {
        float v = xr[t + (j << 8)];
#pragma unroll
        for (int h = 0; h < 3; ++h) acc[h][j] = aself[h] * v;
    }
    int beg = offs[i], num = cnt[i];
    for (int e = 0; e < num; ++e) {
        int s = csrs[beg + e];
        float a0 = csra[(beg + e) * 3 + 0];
        float a1 = csra[(beg + e) * 3 + 1];
        float a2 = csra[(beg + e) * 3 + 2];
        const float* sr = xin + (long long)s * CC;
#pragma unroll
        for (int j = 0; j < 4; ++j) {
            float v = sr[t + (j << 8)];
            acc[0][j] += a0 * v; acc[1][j] += a1 * v; acc[2][j] += a2 * v;
        }
    }
#pragma unroll
    for (int h = 0; h < 3; ++h)
#pragma unroll
        for (int j = 0; j < 4; ++j) {
            int c = t + (j << 8);
            float v = acc[h][j];
            unsigned short hh = f2bf(v);
            size_t idx = (size_t)r * HC3 + h * CC + c;
            ahi[idx] = hh;
            alo[idx] = f2bf(v - bf2f(hh));
        }
}

__global__ void remap_edges(int* __restrict__ s, int* __restrict__ d,
    int* __restrict__ m, const int* __restrict__ newid)
{
    int e = blockIdx.x * 256 + threadIdx.x;
    if (e >= EE) return;
    if (!m[e]) { s[e] = 0; d[e] = 0; return; }
    int ns = newid[s[e]], nd = newid[d[e]];
    int nm = (ns >= 0 && nd >= 0) ? 1 : 0;
    m[e] = nm; s[e] = nm ? ns : 0; d[e] = nm ? nd : 0;
}

// ---- two-pass readout ----
__global__ __launch_bounds__(256) void readout_part(const float* __restrict__ xn,
    int k, float* __restrict__ PM, float* __restrict__ PS)
{
    int g = blockIdx.x, ch = blockIdx.y, t = threadIdx.x;
    int rpc = k >> 3, r0 = ch * rpc;
#pragma unroll
    for (int j = 0; j < 4; ++j) {
        int c = t + (j << 8);
        float mx = -1e30f, sm = 0.f;
        for (int r = r0; r < r0 + rpc; ++r) {
            float vv = xn[((size_t)(g * k + r)) * CC + c];
            mx = fmaxf(mx, vv); sm += vv;
        }
        PM[(size_t)(g * 8 + ch) * CC + c] = mx;
        PS[(size_t)(g * 8 + ch) * CC + c] = sm;
    }
}

__global__ __launch_bounds__(256) void readout_fin(const float* __restrict__ PM,
    const float* __restrict__ PS, int k, float* __restrict__ R)
{
    int g = blockIdx.x, t = threadIdx.x;
#pragma unroll
    for (int j = 0; j < 4; ++j) {
        int c = t + (j << 8);
        float mx = -1e30f, sm = 0.f;
#pragma unroll
        for (int ch = 0; ch < 8; ++ch) {
            mx = fmaxf(mx, PM[(size_t)(g * 8 + ch) * CC + c]);
            sm += PS[(size_t)(g * 8 + ch) * CC + c];
        }
        R[g * 2048 + c] = mx;
        R[g * 2048 + 1024 + c] = sm / (float)k;
    }
}

__global__ void copy_edges(const int* __restrict__ ei, int* __restrict__ s,
    int* __restrict__ d, int* __restrict__ m)
{
    int e = blockIdx.x * 256 + threadIdx.x;
    if (e >= EE) return;
    s[e] = ei[e]; d[e] = ei[EE + e]; m[e] = 1;
}

// ---------------- final MLP ----------------
__global__ void zsum(const float* __restrict__ a, const float* __restrict__ b,
    const float* __restrict__ c, float* __restrict__ z)
{
    int i = blockIdx.x * 256 + threadIdx.x;
    if (i < NG * 2048) z[i] = a[i] + b[i] + c[i];
}

__global__ __launch_bounds__(256) void mlp1_kernel(const float* __restrict__ Z,
    const float* __restrict__ Wl1, const float* __restrict__ bl1, float* __restrict__ Z1)
{
    int c = blockIdx.x * 256 + threadIdx.x;   // 0..1023
    int g = blockIdx.y;
    float acc = bl1[c];
    const float* zr = Z + g * 2048;
    for (int kk = 0; kk < 2048; ++kk) acc += zr[kk] * Wl1[kk * 1024 + c];
    Z1[g * 1024 + c] = acc > 0.f ? acc : 0.f;
}

__global__ __launch_bounds__(64) void mlp2_kernel(const float* __restrict__ Z1,
    const float* __restrict__ Wl2, const float* __restrict__ bl2, float* __restrict__ out)
{
    int b = blockIdx.x; int g = b >> 1, o = b & 1;
    int lane = threadIdx.x;
    const float* zr = Z1 + g * 1024;
    float s = 0.f;
    for (int j = lane; j < 1024; j += 64) s += zr[j] * Wl2[j * 2 + o];
    for (int off = 32; off; off >>= 1) s += __shfl_xor(s, off, 64);
    if (lane == 0) out[g * 2 + o] = s + bl2[o];
}

// ---------------- host ----------------
extern "C" void kernel_launch(void* const* d_in, const int* in_sizes, int n_in,
                              void* d_out, int out_size, void* d_ws, size_t ws_size,
                              hipStream_t stream)
{
    const float* x   = (const float*)d_in[0];
    const int*   ei  = (const int*)d_in[2];
    const float* W[3]    = {(const float*)d_in[4],  (const float*)d_in[11], (const float*)d_in[18]};
    const float* atts[3] = {(const float*)d_in[5],  (const float*)d_in[12], (const float*)d_in[19]};
    const float* attd[3] = {(const float*)d_in[6],  (const float*)d_in[13], (const float*)d_in[20]};
    const float* bb[3]   = {(const float*)d_in[7],  (const float*)d_in[14], (const float*)d_in[21]};
    const float* Wt[3]   = {(const float*)d_in[8],  (const float*)d_in[15], (const float*)d_in[22]};
    const float* bt[3]   = {(const float*)d_in[9],  (const float*)d_in[16], (const float*)d_in[23]};
    const float* pv[3]   = {(const float*)d_in[10], (const float*)d_in[17], (const float*)d_in[24]};
    const float* Wl1 = (const float*)d_in[25];
    const float* bl1 = (const float*)d_in[26];
    const float* Wl2 = (const float*)d_in[27];
    const float* bl2 = (const float*)d_in[28];
    float* out = (float*)d_out;

    // ---- workspace carve (~185 MB; weight temps aliased into A2 region) ----
    char* wp = (char*)d_ws;
    auto carve = [&](size_t bytes) -> void* {
        void* p = (void*)wp;
        wp += (bytes + 255) & ~(size_t)255;
        return p;
    };
    const int NMAX = 12800;
    const int GKMAX = 10240;
    const size_t MSZ = (size_t)CC * CC;
    // A2: selected-row concat split-bf16 [GKMAX][3072]
    unsigned short* A2H = (unsigned short*)carve((size_t)GKMAX * HC3 * 2);  // 62.9 MB
    unsigned short* A2L = (unsigned short*)carve((size_t)GKMAX * HC3 * 2);  // 62.9 MB
    // weight temps alias into A2 (weight prep finishes before aggregate_sel writes A2)
    unsigned short* WTH = (unsigned short*)A2H;            // 3*MSZ elems
    unsigned short* WTL = WTH + 3 * MSZ;
    unsigned short* WSH = WTL + 3 * MSZ;
    unsigned short* WSL = WSH + 3 * MSZ;                   // 4*3*MSZ*2B = 25.2 MB < 62.9
    float* MHT = (float*)A2L;                              // 3*MSZ*4B = 12.6 MB < 62.9
    float* XN   = (float*)carve((size_t)GKMAX * CC * 4);   // 41.9 MB
    unsigned short* B2H = (unsigned short*)carve((size_t)3 * MSZ * 2);  // 6.3 MB
    unsigned short* B2L = (unsigned short*)carve((size_t)3 * MSZ * 2);  // 6.3 MB
    float* PM   = (float*)carve((size_t)NG * 8 * CC * 4);
    float* PS   = (float*)carve((size_t)NG * 8 * CC * 4);
    float* ASV  = (float*)carve((size_t)3 * CC * 4);
    float* ADV  = (float*)carve((size_t)3 * CC * 4);
    float* QV   = (float*)carve((size_t)3 * CC * 4);
    float* BV   = (float*)carve((size_t)CC * 4);
    float* AS   = (float*)carve((size_t)NMAX * 3 * 4);
    float* AD   = (float*)carve((size_t)NMAX * 3 * 4);
    float* T3   = (float*)carve((size_t)NMAX * 3 * 4);
    float* SL   = (float*)carve((size_t)NMAX * 3 * 4);
    unsigned* MXE = (unsigned*)carve((size_t)NMAX * 3 * 4);
    float* MXF  = (float*)carve((size_t)NMAX * 3 * 4);
    float* DEN  = (float*)carve((size_t)NMAX * 3 * 4);
    int* CNT    = (int*)carve((size_t)NMAX * 4);
    int* OFFS   = (int*)carve((size_t)NMAX * 4);
    int* CUR    = (int*)carve((size_t)NMAX * 4);
    int* NEWID  = (int*)carve((size_t)NMAX * 4);
    int* GT     = (int*)carve((size_t)NG * 4);
    int* GB     = (int*)carve((size_t)NG * 4);
    int* CSRS   = (int*)carve((size_t)EE * 4);
    float* CSRA = (float*)carve((size_t)EE * 3 * 4);
    int* SRC = (int*)carve((size_t)EE * 4);
    int* DST = (int*)carve((size_t)EE * 4);
    int* MK  = (int*)carve((size_t)EE * 4);
    int* PERM  = (int*)carve((size_t)GKMAX * 4);
    float* VALS = (float*)carve((size_t)GKMAX * 4);
    float* SCORE = (float*)carve((size_t)NMAX * 4);
    float* PN  = (float*)carve(256);
    float* BVP = (float*)carve(256);
    float* R0 = (float*)carve((size_t)NG * 2048 * 4);
    float* R1 = (float*)carve((size_t)NG * 2048 * 4);
    float* R2 = (float*)carve((size_t)NG * 2048 * 4);
    float* Z  = (float*)carve((size_t)NG * 2048 * 4);
    float* Z1 = (float*)carve((size_t)NG * 1024 * 4);
    float* Rarr[3] = {R0, R1, R2};
    (void)ws_size; (void)in_sizes; (void)n_in; (void)out_size;

    copy_edges<<<cdiv(EE, 256), 256, 0, stream>>>(ei, SRC, DST, MK);

    const int ns_[3]  = {12800, 10240, 5120};
    const int npg_[3] = {200, 160, 80};
    const int kk_[3]  = {160, 80, 16};
    const float* xin = x;

    for (int L = 0; L < 3; ++L) {
        int n = ns_[L], npg = npg_[L], k = kk_[L];
        int gk = NG * k;
        // weight prep: M_h^T = Wt_h^T @ W_h^T (batched over heads), B2 concat, q = M_h p
        split_w<<<dim3(4096, 3), 256, 0, stream>>>(W[L], WSH, WSL);
        transpose_split_wt<<<dim3(32, 32, 3), 256, 0, stream>>>(Wt[L], WTH, WTL);
        gemm_split<<<dim3(8, 8, 3), 256, 0, stream>>>(WTH, WTL, CC, WSH, WSL, CC,
            nullptr, nullptr, MHT, CC, CC, MSZ, MSZ, MSZ);
        split_interleave<<<dim3(4096, 3), 256, 0, stream>>>(MHT, B2H, B2L, CC, HC3);
        qzero<<<12, 256, 0, stream>>>(QV);
        qvec<<<dim3(4, 8, 3), 256, 0, stream>>>(MHT, pv[L], QV);
        bvec_pnorm<<<5, 256, 0, stream>>>(bb[L], Wt[L], bt[L], BV, pv[L], PN);
        bvp_kernel<<<1, 256, 0, stream>>>(BV, pv[L], BVP);
        // attention coefficients + score dots
        attvec<<<768, 256, 0, stream>>>(W[L], atts[L], attd[L], ASV, ADV);
        attn_dots_t<<<n / 4, 256, 0, stream>>>(xin, ASV, ADV, QV, AS, AD, T3, n);
        // CSR + segment softmax
        node_init_zero<<<cdiv(n, 256), 256, 0, stream>>>(AS, AD, SL, MXE, CNT, CUR, n);
        edge_pass1<<<cdiv(EE, 256), 256, 0, stream>>>(SRC, DST, MK, AS, AD, MXE, CNT);
        scan_graph<<<NG, 64, 0, stream>>>(CNT, OFFS, GT, npg);
        scan_base<<<1, 64, 0, stream>>>(GT, GB);
        add_base<<<cdiv(n, 256), 256, 0, stream>>>(OFFS, GB, n, npg);
        decode_selfden<<<cdiv(n, 256), 256, 0, stream>>>(MXE, SL, MXF, DEN, n);
        edge_den<<<cdiv(EE, 256), 256, 0, stream>>>(SRC, DST, MK, AS, AD, MXF, DEN);
        fill_alpha<<<cdiv(EE, 256), 256, 0, stream>>>(SRC, DST, MK, OFFS, CUR,
                                                      AS, AD, MXF, DEN, CSRS, CSRA);
        // scores (cheap scalar pass) -> topk BEFORE any big GEMM
        score_csr<<<cdiv(n, 256), 256, 0, stream>>>(T3, SL, MXF, DEN, OFFS, CNT, CSRS, CSRA,
                                                    BVP, PN, SCORE, n);
        topk_kernel<<<NG, 64, 0, stream>>>(SCORE, npg, k, PERM, VALS, NEWID);
        // aggregate only selected rows; GEMM with bias+rowscale writes XN directly
        aggregate_sel<<<gk, 256, 0, stream>>>(xin, SL, MXF, DEN, OFFS, CNT, CSRS, CSRA,
                                              PERM, A2H, A2L);
        gemm_split<<<dim3(8, gk / 128, 1), 256, 0, stream>>>(A2H, A2L, HC3,
            B2H, B2L, HC3, BV, VALS, XN, CC, HC3, 0, 0, 0);
        // readout + edge remap
        readout_part<<<dim3(NG, 8), 256, 0, stream>>>(XN, k, PM, PS);
        readout_fin<<<NG, 256, 0, stream>>>(PM, PS, k, Rarr[L]);
        if (L < 2) remap_edges<<<cdiv(EE, 256), 256, 0, stream>>>(SRC, DST, MK, NEWID);
        xin = XN;
    }

    // final MLP
    zsum<<<cdiv(NG * 2048, 256), 256, 0, stream>>>(R0, R1, R2, Z);
    mlp1_kernel<<<dim3(4, NG), 256, 0, stream>>>(Z, Wl1, bl1, Z1);
    mlp2_kernel<<<NG * 2, 64, 0, stream>>>(Z1, Wl2, bl2, out);
}

// Round 6
// 1594.500 us; speedup vs baseline: 3.1611x; 1.2147x over previous
//
#include <hip/hip_runtime.h>
#include <math.h>

// Static problem dims
#define NG 64          // graphs
#define EE 64000       // edges
#define HC3 3072       // H*C
#define CC 1024        // C (and input feature dim)

static inline int cdiv(int a, int b) { return (a + b - 1) / b; }

typedef float f4_t __attribute__((ext_vector_type(4)));
typedef short s8_t __attribute__((ext_vector_type(8)));

__device__ __forceinline__ float lrelu(float x) { return x > 0.f ? x : 0.2f * x; }
__device__ __forceinline__ unsigned fenc(float f) {
    unsigned u = __float_as_uint(f);
    return (u & 0x80000000u) ? ~u : (u | 0x80000000u);
}
__device__ __forceinline__ float fdec(unsigned e) {
    return (e & 0x80000000u) ? __uint_as_float(e ^ 0x80000000u) : __uint_as_float(~e);
}
__device__ __forceinline__ unsigned short f2bf(float f) {
    unsigned u = __float_as_uint(f);
    u += 0x7fffu + ((u >> 16) & 1u);
    return (unsigned short)(u >> 16);
}
__device__ __forceinline__ float bf2f(unsigned short h) {
    return __uint_as_float(((unsigned)h) << 16);
}
__device__ __forceinline__ void gll16(const unsigned short* g, unsigned short* l) {
    __builtin_amdgcn_global_load_lds(
        (const __attribute__((address_space(1))) void*)g,
        (__attribute__((address_space(3))) void*)l, 16, 0, 0);
}

// ======== MFMA split-bf16 GEMM: C[M,N] = (Ahi+Alo)[M,K] @ (Bhi+Blo)[N,K]^T ========
// XOR-swizzled LDS layout: lane i stages global k-chunk (i&3)^((i>>3)&3); slot for
// (row,chunk q) is q ^ ((row>>1)&3). Breaks the 8-way bank conflict of the 64B-row
// layout down to 2-way (free). optional bias[col], per-row scale.
__global__ __launch_bounds__(256) void gemm_split(
    const unsigned short* __restrict__ Ahi, const unsigned short* __restrict__ Alo, int lda,
    const unsigned short* __restrict__ Bhi, const unsigned short* __restrict__ Blo, int ldb,
    const float* __restrict__ bias, const float* __restrict__ rowscale,
    float* __restrict__ C, int ldc, int K,
    size_t zsA, size_t zsB, size_t zsC)
{
    __shared__ unsigned short sAH[128 * 32];
    __shared__ unsigned short sAL[128 * 32];
    __shared__ unsigned short sBH[128 * 32];
    __shared__ unsigned short sBL[128 * 32];

    Ahi += blockIdx.z * zsA; Alo += blockIdx.z * zsA;
    Bhi += blockIdx.z * zsB; Blo += blockIdx.z * zsB;
    C   += blockIdx.z * zsC;

    const int t = threadIdx.x;
    const int w = t >> 6, lane = t & 63;
    const int wr = w >> 1, wc = w & 1;
    const int row0 = blockIdx.y * 128, col0 = blockIdx.x * 128;

    const int srow = w * 16 + (lane >> 2);
    // swizzled global k-chunk for staging (lands at LDS slot lane&3)
    const int skg = (((lane & 3) ^ ((lane >> 3) & 3)) << 3);
    const size_t aoff0 = (size_t)(row0 + srow) * lda + skg;
    const size_t aoff1 = (size_t)(row0 + 64 + srow) * lda + skg;
    const size_t boff0 = (size_t)(col0 + srow) * ldb + skg;
    const size_t boff1 = (size_t)(col0 + 64 + srow) * ldb + skg;
    const int l0 = (w * 16) * 32;
    const int l1 = (64 + w * 16) * 32;

    f4_t acc[4][4];
    const f4_t z4 = {0.f, 0.f, 0.f, 0.f};
#pragma unroll
    for (int i = 0; i < 4; ++i)
#pragma unroll
        for (int j = 0; j < 4; ++j) acc[i][j] = z4;

    const int mrow0 = wr * 64 + (lane & 15);
    const int nrow0 = wc * 64 + (lane & 15);
    // swizzled LDS slot for fragment reads (global chunk lane>>4)
    const int kslot = (((lane >> 4) ^ ((lane >> 1) & 3)) << 3);

    for (int k0 = 0; k0 < K; k0 += 32) {
        gll16(Ahi + aoff0 + k0, &sAH[l0]);
        gll16(Ahi + aoff1 + k0, &sAH[l1]);
        gll16(Alo + aoff0 + k0, &sAL[l0]);
        gll16(Alo + aoff1 + k0, &sAL[l1]);
        gll16(Bhi + boff0 + k0, &sBH[l0]);
        gll16(Bhi + boff1 + k0, &sBH[l1]);
        gll16(Blo + boff0 + k0, &sBL[l0]);
        gll16(Blo + boff1 + k0, &sBL[l1]);
        __syncthreads();

        s8_t ah[4], al[4], bh[4], bl[4];
#pragma unroll
        for (int mt = 0; mt < 4; ++mt) {
            ah[mt] = *(const s8_t*)&sAH[(mrow0 + mt * 16) * 32 + kslot];
            al[mt] = *(const s8_t*)&sAL[(mrow0 + mt * 16) * 32 + kslot];
        }
#pragma unroll
        for (int nt = 0; nt < 4; ++nt) {
            bh[nt] = *(const s8_t*)&sBH[(nrow0 + nt * 16) * 32 + kslot];
            bl[nt] = *(const s8_t*)&sBL[(nrow0 + nt * 16) * 32 + kslot];
        }
#pragma unroll
        for (int mt = 0; mt < 4; ++mt)
#pragma unroll
            for (int nt = 0; nt < 4; ++nt) {
                acc[mt][nt] = __builtin_amdgcn_mfma_f32_16x16x32_bf16(ah[mt], bh[nt], acc[mt][nt], 0, 0, 0);
                acc[mt][nt] = __builtin_amdgcn_mfma_f32_16x16x32_bf16(ah[mt], bl[nt], acc[mt][nt], 0, 0, 0);
                acc[mt][nt] = __builtin_amdgcn_mfma_f32_16x16x32_bf16(al[mt], bh[nt], acc[mt][nt], 0, 0, 0);
            }
        __syncthreads();
    }

#pragma unroll
    for (int mt = 0; mt < 4; ++mt) {
        int row = row0 + wr * 64 + mt * 16 + (lane >> 4) * 4;
#pragma unroll
        for (int nt = 0; nt < 4; ++nt) {
            int col = col0 + wc * 64 + nt * 16 + (lane & 15);
            float b = bias ? bias[col] : 0.f;
#pragma unroll
            for (int r = 0; r < 4; ++r) {
                float v = acc[mt][nt][r] + b;
                if (rowscale) v *= rowscale[row + r];
                C[(size_t)(row + r) * ldc + col] = v;
            }
        }
    }
}

// ---- weight prep (slot = blockIdx-based; L = lbase + slot/3, h = slot%3) ----
__global__ void split_w_all(const float* __restrict__ w0, const float* __restrict__ w1,
    const float* __restrict__ w2, int lbase,
    unsigned short* __restrict__ ohi, unsigned short* __restrict__ olo)
{
    const float* Wp[3] = {w0, w1, w2};
    int slot = blockIdx.y;
    int L = lbase + slot / 3, h = slot % 3;
    int idx = blockIdx.x * 256 + threadIdx.x;
    int r = idx >> 10, c = idx & 1023;
    float v = Wp[L][(size_t)r * HC3 + h * CC + c];
    unsigned short hh = f2bf(v);
    ohi[(size_t)slot * 1048576 + idx] = hh;
    olo[(size_t)slot * 1048576 + idx] = f2bf(v - bf2f(hh));
}

__global__ void transpose_split_wt_all(const float* __restrict__ w0,
    const float* __restrict__ w1, const float* __restrict__ w2, int lbase,
    unsigned short* __restrict__ ohi, unsigned short* __restrict__ olo)
{
    const float* Wp[3] = {w0, w1, w2};
    int slot = blockIdx.z;
    int L = lbase + slot / 3, h = slot % 3;
    __shared__ float tile[32][33];
    int t = threadIdx.x, tr = t >> 5, tc = t & 31;
    int r0 = blockIdx.y * 32, c0 = blockIdx.x * 32;
    const float* in = Wp[L] + (size_t)h * 1048576;
#pragma unroll
    for (int i = 0; i < 4; ++i)
        tile[tr + i * 8][tc] = in[(size_t)(r0 + tr + i * 8) * CC + c0 + tc];
    __syncthreads();
    unsigned short* oh = ohi + (size_t)slot * 1048576;
    unsigned short* ol = olo + (size_t)slot * 1048576;
#pragma unroll
    for (int i = 0; i < 4; ++i) {
        int oc = c0 + tr + i * 8;
        int orr = r0 + tc;
        float v = tile[tc][tr + i * 8];
        unsigned short hh = f2bf(v);
        oh[(size_t)oc * CC + orr] = hh;
        ol[(size_t)oc * CC + orr] = f2bf(v - bf2f(hh));
    }
}

// MHT[slot][c][d] -> B2[(slot/3)*3MSZ + c*HC3 + (slot%3)*CC + d]
__global__ void split_interleave_all(const float* __restrict__ in,
    unsigned short* __restrict__ ohi, unsigned short* __restrict__ olo)
{
    int slot = blockIdx.y;
    int lrel = slot / 3, h = slot % 3;
    int idx = blockIdx.x * 256 + threadIdx.x;
    int c = idx >> 10, d = idx & 1023;
    float v = in[(size_t)slot * 1048576 + idx];
    unsigned short hh = f2bf(v);
    size_t dst = (size_t)lrel * 3145728 + (size_t)c * HC3 + h * CC + d;
    ohi[dst] = hh;
    olo[dst] = f2bf(v - bf2f(hh));
}

__global__ void qzero(float* __restrict__ q, int n) {
    int i = blockIdx.x * 256 + threadIdx.x;
    if (i < n) q[i] = 0.f;
}

// q[L][h*CC+d] += sum_c MHT[slot][c][d]*p_L[c]
__global__ void qvec_all(const float* __restrict__ MHT, const float* __restrict__ p0,
    const float* __restrict__ p1, const float* __restrict__ p2, int lbase,
    float* __restrict__ q)
{
    const float* Pp[3] = {p0, p1, p2};
    int slot = blockIdx.z;
    int L = lbase + slot / 3, h = slot % 3;
    int d = blockIdx.x * 256 + threadIdx.x;
    int c0 = blockIdx.y * 128;
    const float* m = MHT + (size_t)slot * 1048576 + (size_t)c0 * CC + d;
    const float* p = Pp[L];
    float s = 0.f;
#pragma unroll 8
    for (int c = 0; c < 128; ++c) s += m[(size_t)c * CC] * p[c0 + c];
    atomicAdd(&q[(size_t)L * HC3 + h * CC + d], s);
}

// ---- attention helper vectors (batched over layers) ----
__global__ __launch_bounds__(256) void attvec_all(const float* __restrict__ w0,
    const float* __restrict__ w1, const float* __restrict__ w2,
    const float* __restrict__ as0, const float* __restrict__ as1, const float* __restrict__ as2,
    const float* __restrict__ ad0, const float* __restrict__ ad1, const float* __restrict__ ad2,
    int lbase, float* __restrict__ asv, float* __restrict__ adv)
{
    const float* Wp[3] = {w0, w1, w2};
    const float* Sp[3] = {as0, as1, as2};
    const float* Dp[3] = {ad0, ad1, ad2};
    int L = lbase + blockIdx.y;
    int wid = blockIdx.x * 4 + (threadIdx.x >> 6);
    int lane = threadIdx.x & 63;
    int h = wid >> 10, kk = wid & 1023;
    const float* wr = Wp[L] + (long long)kk * HC3 + h * CC;
    const float* sa = Sp[L] + h * CC;
    const float* da = Dp[L] + h * CC;
    float ss = 0.f, dd = 0.f;
    for (int c = lane; c < CC; c += 64) { float w = wr[c]; ss += w * sa[c]; dd += w * da[c]; }
    for (int off = 32; off; off >>= 1) { ss += __shfl_xor(ss, off, 64); dd += __shfl_xor(dd, off, 64); }
    if (lane == 0) { asv[(size_t)L * HC3 + h * CC + kk] = ss; adv[(size_t)L * HC3 + h * CC + kk] = dd; }
}

// ---- per-node: a_s, a_d (att) and t (score dots), 9 reductions in one pass ----
__global__ __launch_bounds__(256) void attn_dots_t(const float* __restrict__ xin,
    const float* __restrict__ asv, const float* __restrict__ adv, const float* __restrict__ q,
    float* __restrict__ AS, float* __restrict__ AD, float* __restrict__ T3, int n)
{
    int node = blockIdx.x * 4 + (threadIdx.x >> 6);
    int lane = threadIdx.x & 63;
    if (node >= n) return;
    const float* xr = xin + (long long)node * CC;
    float s0 = 0, s1 = 0, s2 = 0, d0 = 0, d1 = 0, d2 = 0, t0 = 0, t1 = 0, t2 = 0;
    for (int j = lane; j < CC; j += 64) {
        float v = xr[j];
        s0 += v * asv[j]; s1 += v * asv[CC + j]; s2 += v * asv[2 * CC + j];
        d0 += v * adv[j]; d1 += v * adv[CC + j]; d2 += v * adv[2 * CC + j];
        t0 += v * q[j];   t1 += v * q[CC + j];   t2 += v * q[2 * CC + j];
    }
    for (int off = 32; off; off >>= 1) {
        s0 += __shfl_xor(s0, off, 64); s1 += __shfl_xor(s1, off, 64); s2 += __shfl_xor(s2, off, 64);
        d0 += __shfl_xor(d0, off, 64); d1 += __shfl_xor(d1, off, 64); d2 += __shfl_xor(d2, off, 64);
        t0 += __shfl_xor(t0, off, 64); t1 += __shfl_xor(t1, off, 64); t2 += __shfl_xor(t2, off, 64);
    }
    if (lane == 0) {
        AS[node * 3 + 0] = s0; AS[node * 3 + 1] = s1; AS[node * 3 + 2] = s2;
        AD[node * 3 + 0] = d0; AD[node * 3 + 1] = d1; AD[node * 3 + 2] = d2;
        T3[node * 3 + 0] = t0; T3[node * 3 + 1] = t1; T3[node * 3 + 2] = t2;
    }
}

// ---- BV init + pnorm: blocks x<4: BV[L][c]=bt_L[c]; x==4: PN[L]=||p_L|| ----
__global__ void bvinit_pnorm(const float* __restrict__ bt0, const float* __restrict__ bt1,
    const float* __restrict__ bt2, const float* __restrict__ p0, const float* __restrict__ p1,
    const float* __restrict__ p2, int lbase, float* __restrict__ BV, float* __restrict__ PN)
{
    const float* Bp[3] = {bt0, bt1, bt2};
    const float* Pp[3] = {p0, p1, p2};
    int L = lbase + blockIdx.y;
    if (blockIdx.x < 4) {
        int c = blockIdx.x * 256 + threadIdx.x;
        BV[(size_t)L * CC + c] = Bp[L][c];
    } else {
        __shared__ float red[256];
        int t = threadIdx.x;
        const float* p = Pp[L];
        float s = 0.f;
        for (int j = t; j < CC; j += 256) { float v = p[j]; s += v * v; }
        red[t] = s; __syncthreads();
        for (int off = 128; off; off >>= 1) { if (t < off) red[t] += red[t + off]; __syncthreads(); }
        if (t == 0) PN[L] = sqrtf(red[0]);
    }
}

// BV[L][c] += sum_{k in chunk} b_L[k]*Wt_L[k*CC+c]
__global__ void bvec_part(const float* __restrict__ b0, const float* __restrict__ b1,
    const float* __restrict__ b2, const float* __restrict__ wt0, const float* __restrict__ wt1,
    const float* __restrict__ wt2, int lbase, float* __restrict__ BV)
{
    const float* bp[3] = {b0, b1, b2};
    const float* wp[3] = {wt0, wt1, wt2};
    int L = lbase + blockIdx.z;
    int c = blockIdx.x * 256 + threadIdx.x;
    int k0 = blockIdx.y * 256;
    const float* b = bp[L];
    const float* Wt = wp[L];
    float acc = 0.f;
#pragma unroll 8
    for (int k = k0; k < k0 + 256; ++k) acc += b[k] * Wt[(size_t)k * CC + c];
    atomicAdd(&BV[(size_t)L * CC + c], acc);
}

// BVP[L] = BV[L] . p_L
__global__ void bvp_all(const float* __restrict__ BV, const float* __restrict__ p0,
    const float* __restrict__ p1, const float* __restrict__ p2, int lbase,
    float* __restrict__ BVP)
{
    const float* Pp[3] = {p0, p1, p2};
    int L = lbase + blockIdx.x;
    __shared__ float red[256];
    int t = threadIdx.x;
    const float* p = Pp[L];
    float s = 0.f;
    for (int j = t; j < CC; j += 256) s += BV[(size_t)L * CC + j] * p[j];
    red[t] = s; __syncthreads();
    for (int off = 128; off; off >>= 1) { if (t < off) red[t] += red[t + off]; __syncthreads(); }
    if (t == 0) BVP[L] = red[0];
}

// ---- per-node init ----
__global__ void node_init_zero(const float* __restrict__ AS, const float* __restrict__ AD,
    float* __restrict__ sl, unsigned* __restrict__ mxe, float* __restrict__ sexp,
    int* __restrict__ cnt, int* __restrict__ cur, int n)
{
    int i = blockIdx.x * 256 + threadIdx.x;
    if (i >= n) return;
#pragma unroll
    for (int h = 0; h < 3; ++h) {
        float l = lrelu(AS[i * 3 + h] + AD[i * 3 + h]);
        sl[i * 3 + h] = l;
        mxe[i * 3 + h] = fenc(l);
        sexp[i * 3 + h] = 0.f;
    }
    cnt[i] = 0; cur[i] = 0;
}

// ---- fused edge pass: count + segment max + unnormalized exp-sum ----
__global__ void edge_pass1(const int* __restrict__ src, const int* __restrict__ dst,
    const int* __restrict__ msk, const float* __restrict__ AS, const float* __restrict__ AD,
    unsigned* __restrict__ mxe, float* __restrict__ sexp, int* __restrict__ cnt)
{
    int e = blockIdx.x * 256 + threadIdx.x;
    if (e >= EE || !msk[e]) return;
    int s = src[e], d = dst[e];
    atomicAdd(&cnt[d], 1);
#pragma unroll
    for (int h = 0; h < 3; ++h) {
        float l = lrelu(AS[s * 3 + h] + AD[d * 3 + h]);
        atomicMax(&mxe[d * 3 + h], fenc(l));
        atomicAdd(&sexp[d * 3 + h], expf(l));
    }
}

__global__ void scan_graph(const int* __restrict__ cnt, int* __restrict__ offs,
    int* __restrict__ gt, int npg)
{
    if (threadIdx.x != 0) return;
    int g = blockIdx.x, base = g * npg, run = 0;
    for (int i = 0; i < npg; ++i) { offs[base + i] = run; run += cnt[base + i]; }
    gt[g] = run;
}

__global__ void scan_base(const int* __restrict__ gt, int* __restrict__ gb)
{
    if (threadIdx.x != 0 || blockIdx.x != 0) return;
    int run = 0;
    for (int g = 0; g < NG; ++g) { gb[g] = run; run += gt[g]; }
}

__global__ void add_base(int* __restrict__ offs, const int* __restrict__ gb, int n, int npg)
{
    int i = blockIdx.x * 256 + threadIdx.x;
    if (i < n) offs[i] += gb[i / npg];
}

// den = exp(sl-mx) + exp(-mx)*sum_exp
__global__ void decode_selfden(const unsigned* __restrict__ mxe, const float* __restrict__ sl,
    const float* __restrict__ sexp, float* __restrict__ mxf, float* __restrict__ den, int n)
{
    int i = blockIdx.x * 256 + threadIdx.x;
    if (i >= n) return;
#pragma unroll
    for (int h = 0; h < 3; ++h) {
        float m = fdec(mxe[i * 3 + h]);
        mxf[i * 3 + h] = m;
        den[i * 3 + h] = expf(sl[i * 3 + h] - m) + expf(-m) * sexp[i * 3 + h];
    }
}

__global__ void fill_alpha(const int* __restrict__ src, const int* __restrict__ dst,
    const int* __restrict__ msk, const int* __restrict__ offs, int* __restrict__ cur,
    const float* __restrict__ AS, const float* __restrict__ AD,
    const float* __restrict__ mxf, const float* __restrict__ den,
    int* __restrict__ csrs, float* __restrict__ csra)
{
    int e = blockIdx.x * 256 + threadIdx.x;
    if (e >= EE || !msk[e]) return;
    int s = src[e], d = dst[e];
    int pos = offs[d] + atomicAdd(&cur[d], 1);
    csrs[pos] = s;
#pragma unroll
    for (int h = 0; h < 3; ++h) {
        float l = lrelu(AS[s * 3 + h] + AD[d * 3 + h]);
        float ex = expf(l - mxf[d * 3 + h]);
        csra[pos * 3 + h] = ex / (den[d * 3 + h] + 1e-16f);
    }
}

// ---- score via scalar CSR pass ----
__global__ void score_csr(const float* __restrict__ T3,
    const float* __restrict__ sl, const float* __restrict__ mxf, const float* __restrict__ den,
    const int* __restrict__ offs, const int* __restrict__ cnt, const int* __restrict__ csrs,
    const float* __restrict__ csra, const float* __restrict__ bvp, const float* __restrict__ pn,
    float* __restrict__ score, int n)
{
    int i = blockIdx.x * 256 + threadIdx.x;
    if (i >= n) return;
    float s = 0.f;
#pragma unroll
    for (int h = 0; h < 3; ++h) {
        float aself = expf(sl[i * 3 + h] - mxf[i * 3 + h]) / (den[i * 3 + h] + 1e-16f);
        s += aself * T3[i * 3 + h];
    }
    int beg = offs[i], num = cnt[i];
    for (int e = 0; e < num; ++e) {
        int sn = csrs[beg + e];
#pragma unroll
        for (int h = 0; h < 3; ++h) s += csra[(beg + e) * 3 + h] * T3[sn * 3 + h];
    }
    score[i] = tanhf((s + bvp[0]) / pn[0]);
}

// one wave per graph; stable argmax matches lax.top_k
__global__ __launch_bounds__(64) void topk_kernel(const float* __restrict__ score,
    int npg, int k, int* __restrict__ perm, float* __restrict__ vals, int* __restrict__ newid)
{
    int g = blockIdx.x, lane = threadIdx.x;
    for (int idx = lane; idx < npg; idx += 64) newid[g * npg + idx] = -1;
    const float* sc = score + g * npg;
    float v[4];
    int nsl = (npg + 63) >> 6;
#pragma unroll
    for (int s2 = 0; s2 < 4; ++s2) {
        int idx = lane + (s2 << 6);
        v[s2] = (s2 < nsl && idx < npg) ? sc[idx] : -1e30f;
    }
    for (int j = 0; j < k; ++j) {
        float bv = -2e30f; int bi = 0x7fffffff;
#pragma unroll
        for (int s2 = 0; s2 < 4; ++s2) {
            int idx = lane + (s2 << 6);
            if (v[s2] > bv) { bv = v[s2]; bi = idx; }
        }
        for (int off = 32; off; off >>= 1) {
            float ov = __shfl_xor(bv, off, 64);
            int   oi = __shfl_xor(bi, off, 64);
            if (ov > bv || (ov == bv && oi < bi)) { bv = ov; bi = oi; }
        }
        if (lane == 0) {
            perm[g * k + j] = g * npg + bi;
            vals[g * k + j] = bv;
            newid[g * npg + bi] = g * k + j;
        }
        if ((bi & 63) == lane) v[bi >> 6] = -1e30f;
    }
}

// ---- aggregation of SELECTED rows only, all 3 heads, concat split-bf16 [Gk][3072] ----
__global__ __launch_bounds__(256) void aggregate_sel(const float* __restrict__ xin,
    const float* __restrict__ sl, const float* __restrict__ mxf, const float* __restrict__ den,
    const int* __restrict__ offs, const int* __restrict__ cnt,
    const int* __restrict__ csrs, const float* __restrict__ csra,
    const int* __restrict__ perm,
    unsigned short* __restrict__ ahi, unsigned short* __restrict__ alo)
{
    int r = blockIdx.x, t = threadIdx.x;
    int i = perm[r];
    float aself[3];
#pragma unroll
    for (int h = 0; h < 3; ++h)
        aself[h] = expf(sl[i * 3 + h] - mxf[i * 3 + h]) / (den[i * 3 + h] + 1e-16f);
    const float* xr = xin + (long long)i * CC;
    float acc[3][4];
#pragma unroll
    for (int j = 0; j < 4; ++j) {
        float v = xr[t + (j << 8)];
#pragma unroll
        for (int h = 0; h < 3; ++h) acc[h][j] = aself[h] * v;
    }
    int beg = offs[i], num = cnt[i];
    for (int e = 0; e < num; ++e) {
        int s = csrs[beg + e];
        float a0 = csra[(beg + e) * 3 + 0];
        float a1 = csra[(beg + e) * 3 + 1];
        float a2 = csra[(beg + e) * 3 + 2];
        const float* sr = xin + (long long)s * CC;
#pragma unroll
        for (int j = 0; j < 4; ++j) {
            float v = sr[t + (j << 8)];
            acc[0][j] += a0 * v; acc[1][j] += a1 * v; acc[2][j] += a2 * v;
        }
    }
#pragma unroll
    for (int h = 0; h < 3; ++h)
#pragma unroll
        for (int j = 0; j < 4; ++j) {
            int c = t + (j << 8);
            float v = acc[h][j];
            unsigned short hh = f2bf(v);
            size_t idx = (size_t)r * HC3 + h * CC + c;
            ahi[idx] = hh;
            alo[idx] = f2bf(v - bf2f(hh));
        }
}

__global__ void remap_edges(int* __restrict__ s, int* __restrict__ d,
    int* __restrict__ m, const int* __restrict__ newid)
{
    int e = blockIdx.x * 256 + threadIdx.x;
    if (e >= EE) return;
    if (!m[e]) { s[e] = 0; d[e] = 0; return; }
    int ns = newid[s[e]], nd = newid[d[e]];
    int nm = (ns >= 0 && nd >= 0) ? 1 : 0;
    m[e] = nm; s[e] = nm ? ns : 0; d[e] = nm ? nd : 0;
}

// ---- two-pass readout ----
__global__ __launch_bounds__(256) void readout_part(const float* __restrict__ xn,
    int k, float* __restrict__ PM, float* __restrict__ PS)
{
    int g = blockIdx.x, ch = blockIdx.y, t = threadIdx.x;
    int rpc = k >> 3, r0 = ch * rpc;
#pragma unroll
    for (int j = 0; j < 4; ++j) {
        int c = t + (j << 8);
        float mx = -1e30f, sm = 0.f;
        for (int r = r0; r < r0 + rpc; ++r) {
            float vv = xn[((size_t)(g * k + r)) * CC + c];
            mx = fmaxf(mx, vv); sm += vv;
        }
        PM[(size_t)(g * 8 + ch) * CC + c] = mx;
        PS[(size_t)(g * 8 + ch) * CC + c] = sm;
    }
}

__global__ __launch_bounds__(256) void readout_fin(const float* __restrict__ PM,
    const float* __restrict__ PS, int k, float* __restrict__ R)
{
    int g = blockIdx.x, t = threadIdx.x;
#pragma unroll
    for (int j = 0; j < 4; ++j) {
        int c = t + (j << 8);
        float mx = -1e30f, sm = 0.f;
#pragma unroll
        for (int ch = 0; ch < 8; ++ch) {
            mx = fmaxf(mx, PM[(size_t)(g * 8 + ch) * CC + c]);
            sm += PS[(size_t)(g * 8 + ch) * CC + c];
        }
        R[g * 2048 + c] = mx;
        R[g * 2048 + 1024 + c] = sm / (float)k;
    }
}

__global__ void copy_edges(const int* __restrict__ ei, int* __restrict__ s,
    int* __restrict__ d, int* __restrict__ m)
{
    int e = blockIdx.x * 256 + threadIdx.x;
    if (e >= EE) return;
    s[e] = ei[e]; d[e] = ei[EE + e]; m[e] = 1;
}

// ---------------- final MLP ----------------
__global__ void zsum(const float* __restrict__ a, const float* __restrict__ b,
    const float* __restrict__ c, float* __restrict__ z)
{
    int i = blockIdx.x * 256 + threadIdx.x;
    if (i < NG * 2048) z[i] = a[i] + b[i] + c[i];
}

__global__ __launch_bounds__(256) void mlp1_kernel(const float* __restrict__ Z,
    const float* __restrict__ Wl1, const float* __restrict__ bl1, float* __restrict__ Z1)
{
    int c = blockIdx.x * 256 + threadIdx.x;
    int g = blockIdx.y;
    float acc = bl1[c];
    const float* zr = Z + g * 2048;
    for (int kk = 0; kk < 2048; ++kk) acc += zr[kk] * Wl1[kk * 1024 + c];
    Z1[g * 1024 + c] = acc > 0.f ? acc : 0.f;
}

__global__ __launch_bounds__(64) void mlp2_kernel(const float* __restrict__ Z1,
    const float* __restrict__ Wl2, const float* __restrict__ bl2, float* __restrict__ out)
{
    int b = blockIdx.x; int g = b >> 1, o = b & 1;
    int lane = threadIdx.x;
    const float* zr = Z1 + g * 1024;
    float s = 0.f;
    for (int j = lane; j < 1024; j += 64) s += zr[j] * Wl2[j * 2 + o];
    for (int off = 32; off; off >>= 1) s += __shfl_xor(s, off, 64);
    if (lane == 0) out[g * 2 + o] = s + bl2[o];
}

// ---------------- host ----------------
extern "C" void kernel_launch(void* const* d_in, const int* in_sizes, int n_in,
                              void* d_out, int out_size, void* d_ws, size_t ws_size,
                              hipStream_t stream)
{
    const float* x   = (const float*)d_in[0];
    const int*   ei  = (const int*)d_in[2];
    const float* W[3]    = {(const float*)d_in[4],  (const float*)d_in[11], (const float*)d_in[18]};
    const float* atts[3] = {(const float*)d_in[5],  (const float*)d_in[12], (const float*)d_in[19]};
    const float* attd[3] = {(const float*)d_in[6],  (const float*)d_in[13], (const float*)d_in[20]};
    const float* bb[3]   = {(const float*)d_in[7],  (const float*)d_in[14], (const float*)d_in[21]};
    const float* Wt[3]   = {(const float*)d_in[8],  (const float*)d_in[15], (const float*)d_in[22]};
    const float* bt[3]   = {(const float*)d_in[9],  (const float*)d_in[16], (const float*)d_in[23]};
    const float* pv[3]   = {(const float*)d_in[10], (const float*)d_in[17], (const float*)d_in[24]};
    const float* Wl1 = (const float*)d_in[25];
    const float* bl1 = (const float*)d_in[26];
    const float* Wl2 = (const float*)d_in[27];
    const float* bl2 = (const float*)d_in[28];
    float* out = (float*)d_out;

    // batched weight prep for all 3 layers needs +25 MB of persistent B2
    const bool batched = ws_size >= (size_t)225 * 1024 * 1024;

    char* wp = (char*)d_ws;
    auto carve = [&](size_t bytes) -> void* {
        void* p = (void*)wp;
        wp += (bytes + 255) & ~(size_t)255;
        return p;
    };
    const int NMAX = 12800;
    const int GKMAX = 10240;
    const size_t MSZ = (size_t)CC * CC;
    const int NSLOT = batched ? 9 : 3;
    // A2: selected-row concat split-bf16 [GKMAX][3072] (31.46M shorts each)
    unsigned short* A2H = (unsigned short*)carve((size_t)GKMAX * HC3 * 2);  // 62.9 MB
    unsigned short* A2L = (unsigned short*)carve((size_t)GKMAX * HC3 * 2);  // 62.9 MB
    // weight temps alias into A2 (prep completes before aggregate_sel writes A2)
    unsigned short* WTH = (unsigned short*)A2H;          // NSLOT*MSZ shorts
    unsigned short* WTL = WTH + (size_t)NSLOT * MSZ;
    unsigned short* WSH = WTL + (size_t)NSLOT * MSZ;     // 3*9*MSZ*2 = 56.6 MB <= 62.9
    unsigned short* WSL = (unsigned short*)A2L;
    float* MHT = (float*)(WSL + (size_t)NSLOT * MSZ);    // 9*MSZ*2 + 9*MSZ*4 = 56.6 <= 62.9
    float* XN   = (float*)carve((size_t)GKMAX * CC * 4); // 41.9 MB
    unsigned short* B2H = (unsigned short*)carve((size_t)NSLOT * MSZ * 2);
    unsigned short* B2L = (unsigned short*)carve((size_t)NSLOT * MSZ * 2);
    float* PM   = (float*)carve((size_t)NG * 8 * CC * 4);
    float* PS   = (float*)carve((size_t)NG * 8 * CC * 4);
    float* ASV  = (float*)carve((size_t)3 * HC3 * 4);
    float* ADV  = (float*)carve((size_t)3 * HC3 * 4);
    float* QV   = (float*)carve((size_t)3 * HC3 * 4);
    float* BV   = (float*)carve((size_t)3 * CC * 4);
    float* AS   = (float*)carve((size_t)NMAX * 3 * 4);
    float* AD   = (float*)carve((size_t)NMAX * 3 * 4);
    float* T3   = (float*)carve((size_t)NMAX * 3 * 4);
    float* SL   = (float*)carve((size_t)NMAX * 3 * 4);
    unsigned* MXE = (unsigned*)carve((size_t)NMAX * 3 * 4);
    float* MXF  = (float*)carve((size_t)NMAX * 3 * 4);
    float* DEN  = (float*)carve((size_t)NMAX * 3 * 4);
    float* SEXP = (float*)carve((size_t)NMAX * 3 * 4);
    int* CNT    = (int*)carve((size_t)NMAX * 4);
    int* OFFS   = (int*)carve((size_t)NMAX * 4);
    int* CUR    = (int*)carve((size_t)NMAX * 4);
    int* NEWID  = (int*)carve((size_t)NMAX * 4);
    int* GT     = (int*)carve((size_t)NG * 4);
    int* GB     = (int*)carve((size_t)NG * 4);
    int* CSRS   = (int*)carve((size_t)EE * 4);
    float* CSRA = (float*)carve((size_t)EE * 3 * 4);
    int* SRC = (int*)carve((size_t)EE * 4);
    int* DST = (int*)carve((size_t)EE * 4);
    int* MK  = (int*)carve((size_t)EE * 4);
    int* PERM  = (int*)carve((size_t)GKMAX * 4);
    float* VALS = (float*)carve((size_t)GKMAX * 4);
    float* SCORE = (float*)carve((size_t)NMAX * 4);
    float* PN  = (float*)carve(256);
    float* BVP = (float*)carve(256);
    float* R0 = (float*)carve((size_t)NG * 2048 * 4);
    float* R1 = (float*)carve((size_t)NG * 2048 * 4);
    float* R2 = (float*)carve((size_t)NG * 2048 * 4);
    float* Z  = (float*)carve((size_t)NG * 2048 * 4);
    float* Z1 = (float*)carve((size_t)NG * 1024 * 4);
    float* Rarr[3] = {R0, R1, R2};
    (void)in_sizes; (void)n_in; (void)out_size;

    copy_edges<<<cdiv(EE, 256), 256, 0, stream>>>(ei, SRC, DST, MK);

    // ---- weight prep (lbase, nl layers -> 3*nl slots) ----
    auto prep = [&](int lbase, int nl) {
        int nslots = 3 * nl;
        split_w_all<<<dim3(4096, nslots), 256, 0, stream>>>(W[0], W[1], W[2], lbase, WSH, WSL);
        transpose_split_wt_all<<<dim3(32, 32, nslots), 256, 0, stream>>>(Wt[0], Wt[1], Wt[2],
                                                                          lbase, WTH, WTL);
        gemm_split<<<dim3(8, 8, nslots), 256, 0, stream>>>(WTH, WTL, CC, WSH, WSL, CC,
            nullptr, nullptr, MHT, CC, CC, MSZ, MSZ, MSZ);
        split_interleave_all<<<dim3(4096, nslots), 256, 0, stream>>>(MHT, B2H, B2L);
        qzero<<<cdiv(nl * HC3, 256), 256, 0, stream>>>(QV + (size_t)lbase * HC3, nl * HC3);
        qvec_all<<<dim3(4, 8, nslots), 256, 0, stream>>>(MHT, pv[0], pv[1], pv[2], lbase, QV);
        attvec_all<<<dim3(768, nl), 256, 0, stream>>>(W[0], W[1], W[2],
            atts[0], atts[1], atts[2], attd[0], attd[1], attd[2], lbase, ASV, ADV);
        bvinit_pnorm<<<dim3(5, nl), 256, 0, stream>>>(bt[0], bt[1], bt[2],
            pv[0], pv[1], pv[2], lbase, BV, PN);
        bvec_part<<<dim3(4, 12, nl), 256, 0, stream>>>(bb[0], bb[1], bb[2],
            Wt[0], Wt[1], Wt[2], lbase, BV);
        bvp_all<<<nl, 256, 0, stream>>>(BV, pv[0], pv[1], pv[2], lbase, BVP);
    };

    if (batched) prep(0, 3);

    const int ns_[3]  = {12800, 10240, 5120};
    const int npg_[3] = {200, 160, 80};
    const int kk_[3]  = {160, 80, 16};
    const float* xin = x;

    for (int L = 0; L < 3; ++L) {
        int n = ns_[L], npg = npg_[L], k = kk_[L];
        int gk = NG * k;
        if (!batched) prep(L, 1);
        size_t b2off = batched ? (size_t)L * 3 * MSZ : 0;
        // attention coefficients + score dots
        attn_dots_t<<<n / 4, 256, 0, stream>>>(xin, ASV + (size_t)L * HC3,
            ADV + (size_t)L * HC3, QV + (size_t)L * HC3, AS, AD, T3, n);
        // CSR + segment softmax (single edge pass for max+sumexp+count)
        node_init_zero<<<cdiv(n, 256), 256, 0, stream>>>(AS, AD, SL, MXE, SEXP, CNT, CUR, n);
        edge_pass1<<<cdiv(EE, 256), 256, 0, stream>>>(SRC, DST, MK, AS, AD, MXE, SEXP, CNT);
        scan_graph<<<NG, 64, 0, stream>>>(CNT, OFFS, GT, npg);
        scan_base<<<1, 64, 0, stream>>>(GT, GB);
        add_base<<<cdiv(n, 256), 256, 0, stream>>>(OFFS, GB, n, npg);
        decode_selfden<<<cdiv(n, 256), 256, 0, stream>>>(MXE, SL, SEXP, MXF, DEN, n);
        fill_alpha<<<cdiv(EE, 256), 256, 0, stream>>>(SRC, DST, MK, OFFS, CUR,
                                                      AS, AD, MXF, DEN, CSRS, CSRA);
        // scores -> topk BEFORE any big GEMM
        score_csr<<<cdiv(n, 256), 256, 0, stream>>>(T3, SL, MXF, DEN, OFFS, CNT, CSRS, CSRA,
                                                    BVP + L, PN + L, SCORE, n);
        topk_kernel<<<NG, 64, 0, stream>>>(SCORE, npg, k, PERM, VALS, NEWID);
        // aggregate only selected rows; GEMM with bias+rowscale writes XN directly
        aggregate_sel<<<gk, 256, 0, stream>>>(xin, SL, MXF, DEN, OFFS, CNT, CSRS, CSRA,
                                              PERM, A2H, A2L);
        gemm_split<<<dim3(8, gk / 128, 1), 256, 0, stream>>>(A2H, A2L, HC3,
            B2H + b2off, B2L + b2off, HC3, BV + (size_t)L * CC, VALS, XN, CC, HC3, 0, 0, 0);
        // readout + edge remap
        readout_part<<<dim3(NG, 8), 256, 0, stream>>>(XN, k, PM, PS);
        readout_fin<<<NG, 256, 0, stream>>>(PM, PS, k, Rarr[L]);
        if (L < 2) remap_edges<<<cdiv(EE, 256), 256, 0, stream>>>(SRC, DST, MK, NEWID);
        xin = XN;
    }

    // final MLP
    zsum<<<cdiv(NG * 2048, 256), 256, 0, stream>>>(R0, R1, R2, Z);
    mlp1_kernel<<<dim3(4, NG), 256, 0, stream>>>(Z, Wl1, bl1, Z1);
    mlp2_kernel<<<NG * 2, 64, 0, stream>>>(Z1, Wl2, bl2, out);
}

// Round 7
// 1386.141 us; speedup vs baseline: 3.6362x; 1.1503x over previous
//
#include <hip/hip_runtime.h>
#include <math.h>

// Static problem dims
#define NG 64          // graphs
#define EE 64000       // edges
#define HC3 3072       // H*C
#define CC 1024        // C (and input feature dim)

static inline int cdiv(int a, int b) { return (a + b - 1) / b; }

typedef float f4_t __attribute__((ext_vector_type(4)));
typedef short s8_t __attribute__((ext_vector_type(8)));

__device__ __forceinline__ float lrelu(float x) { return x > 0.f ? x : 0.2f * x; }
__device__ __forceinline__ unsigned fenc(float f) {
    unsigned u = __float_as_uint(f);
    return (u & 0x80000000u) ? ~u : (u | 0x80000000u);
}
__device__ __forceinline__ float fdec(unsigned e) {
    return (e & 0x80000000u) ? __uint_as_float(e ^ 0x80000000u) : __uint_as_float(~e);
}
__device__ __forceinline__ unsigned short f2bf(float f) {
    unsigned u = __float_as_uint(f);
    u += 0x7fffu + ((u >> 16) & 1u);
    return (unsigned short)(u >> 16);
}
__device__ __forceinline__ float bf2f(unsigned short h) {
    return __uint_as_float(((unsigned)h) << 16);
}
__device__ __forceinline__ void gll16(const unsigned short* g, unsigned short* l) {
    __builtin_amdgcn_global_load_lds(
        (const __attribute__((address_space(1))) void*)g,
        (__attribute__((address_space(3))) void*)l, 16, 0, 0);
}

// ======== MFMA split-bf16 GEMM (prep, batched over z slots, fp32 store) ========
__global__ __launch_bounds__(256) void gemm_split(
    const unsigned short* __restrict__ Ahi, const unsigned short* __restrict__ Alo, int lda,
    const unsigned short* __restrict__ Bhi, const unsigned short* __restrict__ Blo, int ldb,
    float* __restrict__ C, int ldc, int K,
    size_t zsA, size_t zsB, size_t zsC)
{
    __shared__ unsigned short sAH[128 * 32];
    __shared__ unsigned short sAL[128 * 32];
    __shared__ unsigned short sBH[128 * 32];
    __shared__ unsigned short sBL[128 * 32];

    Ahi += blockIdx.z * zsA; Alo += blockIdx.z * zsA;
    Bhi += blockIdx.z * zsB; Blo += blockIdx.z * zsB;
    C   += blockIdx.z * zsC;

    const int t = threadIdx.x;
    const int w = t >> 6, lane = t & 63;
    const int wr = w >> 1, wc = w & 1;
    const int row0 = blockIdx.y * 128, col0 = blockIdx.x * 128;

    const int srow = w * 16 + (lane >> 2);
    const int skg = (((lane & 3) ^ ((lane >> 3) & 3)) << 3);
    const size_t aoff0 = (size_t)(row0 + srow) * lda + skg;
    const size_t aoff1 = (size_t)(row0 + 64 + srow) * lda + skg;
    const size_t boff0 = (size_t)(col0 + srow) * ldb + skg;
    const size_t boff1 = (size_t)(col0 + 64 + srow) * ldb + skg;
    const int l0 = (w * 16) * 32;
    const int l1 = (64 + w * 16) * 32;

    f4_t acc[4][4];
    const f4_t z4 = {0.f, 0.f, 0.f, 0.f};
#pragma unroll
    for (int i = 0; i < 4; ++i)
#pragma unroll
        for (int j = 0; j < 4; ++j) acc[i][j] = z4;

    const int mrow0 = wr * 64 + (lane & 15);
    const int nrow0 = wc * 64 + (lane & 15);
    const int kslot = (((lane >> 4) ^ ((lane >> 1) & 3)) << 3);

    for (int k0 = 0; k0 < K; k0 += 32) {
        gll16(Ahi + aoff0 + k0, &sAH[l0]);
        gll16(Ahi + aoff1 + k0, &sAH[l1]);
        gll16(Alo + aoff0 + k0, &sAL[l0]);
        gll16(Alo + aoff1 + k0, &sAL[l1]);
        gll16(Bhi + boff0 + k0, &sBH[l0]);
        gll16(Bhi + boff1 + k0, &sBH[l1]);
        gll16(Blo + boff0 + k0, &sBL[l0]);
        gll16(Blo + boff1 + k0, &sBL[l1]);
        __syncthreads();

        s8_t ah[4], al[4], bh[4], bl[4];
#pragma unroll
        for (int mt = 0; mt < 4; ++mt) {
            ah[mt] = *(const s8_t*)&sAH[(mrow0 + mt * 16) * 32 + kslot];
            al[mt] = *(const s8_t*)&sAL[(mrow0 + mt * 16) * 32 + kslot];
        }
#pragma unroll
        for (int nt = 0; nt < 4; ++nt) {
            bh[nt] = *(const s8_t*)&sBH[(nrow0 + nt * 16) * 32 + kslot];
            bl[nt] = *(const s8_t*)&sBL[(nrow0 + nt * 16) * 32 + kslot];
        }
#pragma unroll
        for (int mt = 0; mt < 4; ++mt)
#pragma unroll
            for (int nt = 0; nt < 4; ++nt) {
                acc[mt][nt] = __builtin_amdgcn_mfma_f32_16x16x32_bf16(ah[mt], bh[nt], acc[mt][nt], 0, 0, 0);
                acc[mt][nt] = __builtin_amdgcn_mfma_f32_16x16x32_bf16(ah[mt], bl[nt], acc[mt][nt], 0, 0, 0);
                acc[mt][nt] = __builtin_amdgcn_mfma_f32_16x16x32_bf16(al[mt], bh[nt], acc[mt][nt], 0, 0, 0);
            }
        __syncthreads();
    }

#pragma unroll
    for (int mt = 0; mt < 4; ++mt) {
        int row = row0 + wr * 64 + mt * 16 + (lane >> 4) * 4;
#pragma unroll
        for (int nt = 0; nt < 4; ++nt) {
            int col = col0 + wc * 64 + nt * 16 + (lane & 15);
#pragma unroll
            for (int r = 0; r < 4; ++r)
                C[(size_t)(row + r) * ldc + col] = acc[mt][nt][r];
        }
    }
}

// ======== main GEMM: split-K + L2-friendly grid (x=row tile fastest, y=col tile, z=k slab),
// fp32 atomicAdd epilogue into zero-initialized C ========
__global__ __launch_bounds__(256) void gemm_splitk(
    const unsigned short* __restrict__ Ahi, const unsigned short* __restrict__ Alo, int lda,
    const unsigned short* __restrict__ Bhi, const unsigned short* __restrict__ Blo, int ldb,
    float* __restrict__ C, int ldc, int ksub)
{
    __shared__ unsigned short sAH[128 * 32];
    __shared__ unsigned short sAL[128 * 32];
    __shared__ unsigned short sBH[128 * 32];
    __shared__ unsigned short sBL[128 * 32];

    const int t = threadIdx.x;
    const int w = t >> 6, lane = t & 63;
    const int wr = w >> 1, wc = w & 1;
    const int row0 = blockIdx.x * 128, col0 = blockIdx.y * 128;
    const int kbase = blockIdx.z * ksub;

    const int srow = w * 16 + (lane >> 2);
    const int skg = (((lane & 3) ^ ((lane >> 3) & 3)) << 3);
    const size_t aoff0 = (size_t)(row0 + srow) * lda + skg;
    const size_t aoff1 = (size_t)(row0 + 64 + srow) * lda + skg;
    const size_t boff0 = (size_t)(col0 + srow) * ldb + skg;
    const size_t boff1 = (size_t)(col0 + 64 + srow) * ldb + skg;
    const int l0 = (w * 16) * 32;
    const int l1 = (64 + w * 16) * 32;

    f4_t acc[4][4];
    const f4_t z4 = {0.f, 0.f, 0.f, 0.f};
#pragma unroll
    for (int i = 0; i < 4; ++i)
#pragma unroll
        for (int j = 0; j < 4; ++j) acc[i][j] = z4;

    const int mrow0 = wr * 64 + (lane & 15);
    const int nrow0 = wc * 64 + (lane & 15);
    const int kslot = (((lane >> 4) ^ ((lane >> 1) & 3)) << 3);

    for (int k0 = kbase; k0 < kbase + ksub; k0 += 32) {
        gll16(Ahi + aoff0 + k0, &sAH[l0]);
        gll16(Ahi + aoff1 + k0, &sAH[l1]);
        gll16(Alo + aoff0 + k0, &sAL[l0]);
        gll16(Alo + aoff1 + k0, &sAL[l1]);
        gll16(Bhi + boff0 + k0, &sBH[l0]);
        gll16(Bhi + boff1 + k0, &sBH[l1]);
        gll16(Blo + boff0 + k0, &sBL[l0]);
        gll16(Blo + boff1 + k0, &sBL[l1]);
        __syncthreads();

        s8_t ah[4], al[4], bh[4], bl[4];
#pragma unroll
        for (int mt = 0; mt < 4; ++mt) {
            ah[mt] = *(const s8_t*)&sAH[(mrow0 + mt * 16) * 32 + kslot];
            al[mt] = *(const s8_t*)&sAL[(mrow0 + mt * 16) * 32 + kslot];
        }
#pragma unroll
        for (int nt = 0; nt < 4; ++nt) {
            bh[nt] = *(const s8_t*)&sBH[(nrow0 + nt * 16) * 32 + kslot];
            bl[nt] = *(const s8_t*)&sBL[(nrow0 + nt * 16) * 32 + kslot];
        }
#pragma unroll
        for (int mt = 0; mt < 4; ++mt)
#pragma unroll
            for (int nt = 0; nt < 4; ++nt) {
                acc[mt][nt] = __builtin_amdgcn_mfma_f32_16x16x32_bf16(ah[mt], bh[nt], acc[mt][nt], 0, 0, 0);
                acc[mt][nt] = __builtin_amdgcn_mfma_f32_16x16x32_bf16(ah[mt], bl[nt], acc[mt][nt], 0, 0, 0);
                acc[mt][nt] = __builtin_amdgcn_mfma_f32_16x16x32_bf16(al[mt], bh[nt], acc[mt][nt], 0, 0, 0);
            }
        __syncthreads();
    }

#pragma unroll
    for (int mt = 0; mt < 4; ++mt) {
        int row = row0 + wr * 64 + mt * 16 + (lane >> 4) * 4;
#pragma unroll
        for (int nt = 0; nt < 4; ++nt) {
            int col = col0 + wc * 64 + nt * 16 + (lane & 15);
#pragma unroll
            for (int r = 0; r < 4; ++r)
                atomicAdd(&C[(size_t)(row + r) * ldc + col], acc[mt][nt][r]);
        }
    }
}

// ---- XN finalize: (XN + BV) * vals[row] ----
__global__ __launch_bounds__(256) void finalize_xn(float* __restrict__ XN,
    const float* __restrict__ BV, const float* __restrict__ vals)
{
    int r = blockIdx.x, t = threadIdx.x;
    float v = vals[r];
    float4* p = (float4*)(XN + (size_t)r * CC);
    const float4* b = (const float4*)BV;
    float4 x = p[t], bb = b[t];
    x.x = (x.x + bb.x) * v; x.y = (x.y + bb.y) * v;
    x.z = (x.z + bb.z) * v; x.w = (x.w + bb.w) * v;
    p[t] = x;
}

// ---- weight prep (slot = blockIdx-based; L = lbase + slot/3, h = slot%3) ----
__global__ void split_w_all(const float* __restrict__ w0, const float* __restrict__ w1,
    const float* __restrict__ w2, int lbase,
    unsigned short* __restrict__ ohi, unsigned short* __restrict__ olo)
{
    const float* Wp[3] = {w0, w1, w2};
    int slot = blockIdx.y;
    int L = lbase + slot / 3, h = slot % 3;
    int idx = blockIdx.x * 256 + threadIdx.x;
    int r = idx >> 10, c = idx & 1023;
    float v = Wp[L][(size_t)r * HC3 + h * CC + c];
    unsigned short hh = f2bf(v);
    ohi[(size_t)slot * 1048576 + idx] = hh;
    olo[(size_t)slot * 1048576 + idx] = f2bf(v - bf2f(hh));
}

__global__ void transpose_split_wt_all(const float* __restrict__ w0,
    const float* __restrict__ w1, const float* __restrict__ w2, int lbase,
    unsigned short* __restrict__ ohi, unsigned short* __restrict__ olo)
{
    const float* Wp[3] = {w0, w1, w2};
    int slot = blockIdx.z;
    int L = lbase + slot / 3, h = slot % 3;
    __shared__ float tile[32][33];
    int t = threadIdx.x, tr = t >> 5, tc = t & 31;
    int r0 = blockIdx.y * 32, c0 = blockIdx.x * 32;
    const float* in = Wp[L] + (size_t)h * 1048576;
#pragma unroll
    for (int i = 0; i < 4; ++i)
        tile[tr + i * 8][tc] = in[(size_t)(r0 + tr + i * 8) * CC + c0 + tc];
    __syncthreads();
    unsigned short* oh = ohi + (size_t)slot * 1048576;
    unsigned short* ol = olo + (size_t)slot * 1048576;
#pragma unroll
    for (int i = 0; i < 4; ++i) {
        int oc = c0 + tr + i * 8;
        int orr = r0 + tc;
        float v = tile[tc][tr + i * 8];
        unsigned short hh = f2bf(v);
        oh[(size_t)oc * CC + orr] = hh;
        ol[(size_t)oc * CC + orr] = f2bf(v - bf2f(hh));
    }
}

// MHT[slot][c][d] -> B2[(slot/3)*3MSZ + c*HC3 + (slot%3)*CC + d]
__global__ void split_interleave_all(const float* __restrict__ in,
    unsigned short* __restrict__ ohi, unsigned short* __restrict__ olo)
{
    int slot = blockIdx.y;
    int lrel = slot / 3, h = slot % 3;
    int idx = blockIdx.x * 256 + threadIdx.x;
    int c = idx >> 10, d = idx & 1023;
    float v = in[(size_t)slot * 1048576 + idx];
    unsigned short hh = f2bf(v);
    size_t dst = (size_t)lrel * 3145728 + (size_t)c * HC3 + h * CC + d;
    ohi[dst] = hh;
    olo[dst] = f2bf(v - bf2f(hh));
}

__global__ void qzero(float* __restrict__ q, int n) {
    int i = blockIdx.x * 256 + threadIdx.x;
    if (i < n) q[i] = 0.f;
}

// q[L][h*CC+d] += sum_c MHT[slot][c][d]*p_L[c]
__global__ void qvec_all(const float* __restrict__ MHT, const float* __restrict__ p0,
    const float* __restrict__ p1, const float* __restrict__ p2, int lbase,
    float* __restrict__ q)
{
    const float* Pp[3] = {p0, p1, p2};
    int slot = blockIdx.z;
    int L = lbase + slot / 3, h = slot % 3;
    int d = blockIdx.x * 256 + threadIdx.x;
    int c0 = blockIdx.y * 128;
    const float* m = MHT + (size_t)slot * 1048576 + (size_t)c0 * CC + d;
    const float* p = Pp[L];
    float s = 0.f;
#pragma unroll 8
    for (int c = 0; c < 128; ++c) s += m[(size_t)c * CC] * p[c0 + c];
    atomicAdd(&q[(size_t)L * HC3 + h * CC + d], s);
}

// ---- attention helper vectors (batched over layers) ----
__global__ __launch_bounds__(256) void attvec_all(const float* __restrict__ w0,
    const float* __restrict__ w1, const float* __restrict__ w2,
    const float* __restrict__ as0, const float* __restrict__ as1, const float* __restrict__ as2,
    const float* __restrict__ ad0, const float* __restrict__ ad1, const float* __restrict__ ad2,
    int lbase, float* __restrict__ asv, float* __restrict__ adv)
{
    const float* Wp[3] = {w0, w1, w2};
    const float* Sp[3] = {as0, as1, as2};
    const float* Dp[3] = {ad0, ad1, ad2};
    int L = lbase + blockIdx.y;
    int wid = blockIdx.x * 4 + (threadIdx.x >> 6);
    int lane = threadIdx.x & 63;
    int h = wid >> 10, kk = wid & 1023;
    const float* wr = Wp[L] + (long long)kk * HC3 + h * CC;
    const float* sa = Sp[L] + h * CC;
    const float* da = Dp[L] + h * CC;
    float ss = 0.f, dd = 0.f;
    for (int c = lane; c < CC; c += 64) { float w = wr[c]; ss += w * sa[c]; dd += w * da[c]; }
    for (int off = 32; off; off >>= 1) { ss += __shfl_xor(ss, off, 64); dd += __shfl_xor(dd, off, 64); }
    if (lane == 0) { asv[(size_t)L * HC3 + h * CC + kk] = ss; adv[(size_t)L * HC3 + h * CC + kk] = dd; }
}

// ---- per-node: a_s, a_d, t dots + node init (self-loop logit, max seed, counters) ----
__global__ __launch_bounds__(256) void attn_node(const float* __restrict__ xin,
    const float* __restrict__ asv, const float* __restrict__ adv, const float* __restrict__ q,
    float* __restrict__ AS, float* __restrict__ AD, float* __restrict__ T3,
    float* __restrict__ sl, unsigned* __restrict__ mxe, float* __restrict__ sexp,
    int* __restrict__ cnt, int* __restrict__ cur, int n)
{
    int node = blockIdx.x * 4 + (threadIdx.x >> 6);
    int lane = threadIdx.x & 63;
    if (node >= n) return;
    const float* xr = xin + (long long)node * CC;
    float s0 = 0, s1 = 0, s2 = 0, d0 = 0, d1 = 0, d2 = 0, t0 = 0, t1 = 0, t2 = 0;
    for (int j = lane; j < CC; j += 64) {
        float v = xr[j];
        s0 += v * asv[j]; s1 += v * asv[CC + j]; s2 += v * asv[2 * CC + j];
        d0 += v * adv[j]; d1 += v * adv[CC + j]; d2 += v * adv[2 * CC + j];
        t0 += v * q[j];   t1 += v * q[CC + j];   t2 += v * q[2 * CC + j];
    }
    for (int off = 32; off; off >>= 1) {
        s0 += __shfl_xor(s0, off, 64); s1 += __shfl_xor(s1, off, 64); s2 += __shfl_xor(s2, off, 64);
        d0 += __shfl_xor(d0, off, 64); d1 += __shfl_xor(d1, off, 64); d2 += __shfl_xor(d2, off, 64);
        t0 += __shfl_xor(t0, off, 64); t1 += __shfl_xor(t1, off, 64); t2 += __shfl_xor(t2, off, 64);
    }
    if (lane == 0) {
        AS[node * 3 + 0] = s0; AS[node * 3 + 1] = s1; AS[node * 3 + 2] = s2;
        AD[node * 3 + 0] = d0; AD[node * 3 + 1] = d1; AD[node * 3 + 2] = d2;
        T3[node * 3 + 0] = t0; T3[node * 3 + 1] = t1; T3[node * 3 + 2] = t2;
        float l0v = lrelu(s0 + d0), l1v = lrelu(s1 + d1), l2v = lrelu(s2 + d2);
        sl[node * 3 + 0] = l0v; sl[node * 3 + 1] = l1v; sl[node * 3 + 2] = l2v;
        mxe[node * 3 + 0] = fenc(l0v); mxe[node * 3 + 1] = fenc(l1v); mxe[node * 3 + 2] = fenc(l2v);
        sexp[node * 3 + 0] = 0.f; sexp[node * 3 + 1] = 0.f; sexp[node * 3 + 2] = 0.f;
        cnt[node] = 0; cur[node] = 0;
    }
}

// ---- BV init + pnorm ----
__global__ void bvinit_pnorm(const float* __restrict__ bt0, const float* __restrict__ bt1,
    const float* __restrict__ bt2, const float* __restrict__ p0, const float* __restrict__ p1,
    const float* __restrict__ p2, int lbase, float* __restrict__ BV, float* __restrict__ PN)
{
    const float* Bp[3] = {bt0, bt1, bt2};
    const float* Pp[3] = {p0, p1, p2};
    int L = lbase + blockIdx.y;
    if (blockIdx.x < 4) {
        int c = blockIdx.x * 256 + threadIdx.x;
        BV[(size_t)L * CC + c] = Bp[L][c];
    } else {
        __shared__ float red[256];
        int t = threadIdx.x;
        const float* p = Pp[L];
        float s = 0.f;
        for (int j = t; j < CC; j += 256) { float v = p[j]; s += v * v; }
        red[t] = s; __syncthreads();
        for (int off = 128; off; off >>= 1) { if (t < off) red[t] += red[t + off]; __syncthreads(); }
        if (t == 0) PN[L] = sqrtf(red[0]);
    }
}

__global__ void bvec_part(const float* __restrict__ b0, const float* __restrict__ b1,
    const float* __restrict__ b2, const float* __restrict__ wt0, const float* __restrict__ wt1,
    const float* __restrict__ wt2, int lbase, float* __restrict__ BV)
{
    const float* bp[3] = {b0, b1, b2};
    const float* wp[3] = {wt0, wt1, wt2};
    int L = lbase + blockIdx.z;
    int c = blockIdx.x * 256 + threadIdx.x;
    int k0 = blockIdx.y * 256;
    const float* b = bp[L];
    const float* Wt = wp[L];
    float acc = 0.f;
#pragma unroll 8
    for (int k = k0; k < k0 + 256; ++k) acc += b[k] * Wt[(size_t)k * CC + c];
    atomicAdd(&BV[(size_t)L * CC + c], acc);
}

__global__ void bvp_all(const float* __restrict__ BV, const float* __restrict__ p0,
    const float* __restrict__ p1, const float* __restrict__ p2, int lbase,
    float* __restrict__ BVP)
{
    const float* Pp[3] = {p0, p1, p2};
    int L = lbase + blockIdx.x;
    __shared__ float red[256];
    int t = threadIdx.x;
    const float* p = Pp[L];
    float s = 0.f;
    for (int j = t; j < CC; j += 256) s += BV[(size_t)L * CC + j] * p[j];
    red[t] = s; __syncthreads();
    for (int off = 128; off; off >>= 1) { if (t < off) red[t] += red[t + off]; __syncthreads(); }
    if (t == 0) BVP[L] = red[0];
}

// ---- fused edge pass: count + segment max + unnormalized exp-sum ----
__global__ void edge_pass1(const int* __restrict__ src, const int* __restrict__ dst,
    const int* __restrict__ msk, const float* __restrict__ AS, const float* __restrict__ AD,
    unsigned* __restrict__ mxe, float* __restrict__ sexp, int* __restrict__ cnt)
{
    int e = blockIdx.x * 256 + threadIdx.x;
    if (e >= EE || !msk[e]) return;
    int s = src[e], d = dst[e];
    atomicAdd(&cnt[d], 1);
#pragma unroll
    for (int h = 0; h < 3; ++h) {
        float l = lrelu(AS[s * 3 + h] + AD[d * 3 + h]);
        atomicMax(&mxe[d * 3 + h], fenc(l));
        atomicAdd(&sexp[d * 3 + h], expf(l));
    }
}

__global__ void scan_graph(const int* __restrict__ cnt, int* __restrict__ offs,
    int* __restrict__ gt, int npg)
{
    if (threadIdx.x != 0) return;
    int g = blockIdx.x, base = g * npg, run = 0;
    for (int i = 0; i < npg; ++i) { offs[base + i] = run; run += cnt[base + i]; }
    gt[g] = run;
}

// offs[i] += sum of gt over preceding graphs (merged scan_base+add_base)
__global__ void scan_finish(int* __restrict__ offs, const int* __restrict__ gt, int n, int npg)
{
    int i = blockIdx.x * 256 + threadIdx.x;
    if (i >= n) return;
    int g = i / npg;
    int base = 0;
    for (int gg = 0; gg < g; ++gg) base += gt[gg];
    offs[i] += base;
}

// den = exp(sl-mx) + exp(-mx)*sum_exp
__global__ void decode_selfden(const unsigned* __restrict__ mxe, const float* __restrict__ sl,
    const float* __restrict__ sexp, float* __restrict__ mxf, float* __restrict__ den, int n)
{
    int i = blockIdx.x * 256 + threadIdx.x;
    if (i >= n) return;
#pragma unroll
    for (int h = 0; h < 3; ++h) {
        float m = fdec(mxe[i * 3 + h]);
        mxf[i * 3 + h] = m;
        den[i * 3 + h] = expf(sl[i * 3 + h] - m) + expf(-m) * sexp[i * 3 + h];
    }
}

__global__ void fill_alpha(const int* __restrict__ src, const int* __restrict__ dst,
    const int* __restrict__ msk, const int* __restrict__ offs, int* __restrict__ cur,
    const float* __restrict__ AS, const float* __restrict__ AD,
    const float* __restrict__ mxf, const float* __restrict__ den,
    int* __restrict__ csrs, float* __restrict__ csra)
{
    int e = blockIdx.x * 256 + threadIdx.x;
    if (e >= EE || !msk[e]) return;
    int s = src[e], d = dst[e];
    int pos = offs[d] + atomicAdd(&cur[d], 1);
    csrs[pos] = s;
#pragma unroll
    for (int h = 0; h < 3; ++h) {
        float l = lrelu(AS[s * 3 + h] + AD[d * 3 + h]);
        float ex = expf(l - mxf[d * 3 + h]);
        csra[pos * 3 + h] = ex / (den[d * 3 + h] + 1e-16f);
    }
}

// ---- fused score (scalar CSR) + topk per graph: one wave per graph ----
__global__ __launch_bounds__(64) void score_topk(const float* __restrict__ T3,
    const float* __restrict__ sl, const float* __restrict__ mxf, const float* __restrict__ den,
    const int* __restrict__ offs, const int* __restrict__ cnt, const int* __restrict__ csrs,
    const float* __restrict__ csra, const float* __restrict__ bvp, const float* __restrict__ pn,
    int npg, int k, int* __restrict__ perm, float* __restrict__ vals, int* __restrict__ newid)
{
    __shared__ float sc[256];
    int g = blockIdx.x, lane = threadIdx.x;
    float bv0 = bvp[0], pn0 = pn[0];
    for (int ii = lane; ii < npg; ii += 64) {
        int i = g * npg + ii;
        float s = 0.f;
#pragma unroll
        for (int h = 0; h < 3; ++h) {
            float aself = expf(sl[i * 3 + h] - mxf[i * 3 + h]) / (den[i * 3 + h] + 1e-16f);
            s += aself * T3[i * 3 + h];
        }
        int beg = offs[i], num = cnt[i];
        for (int e = 0; e < num; ++e) {
            int sn = csrs[beg + e];
#pragma unroll
            for (int h = 0; h < 3; ++h) s += csra[(beg + e) * 3 + h] * T3[sn * 3 + h];
        }
        sc[ii] = tanhf((s + bv0) / pn0);
        newid[i] = -1;
    }
    __syncthreads();
    float v[4];
    int nsl = (npg + 63) >> 6;
#pragma unroll
    for (int s2 = 0; s2 < 4; ++s2) {
        int idx = lane + (s2 << 6);
        v[s2] = (s2 < nsl && idx < npg) ? sc[idx] : -1e30f;
    }
    for (int j = 0; j < k; ++j) {
        float bv = -2e30f; int bi = 0x7fffffff;
#pragma unroll
        for (int s2 = 0; s2 < 4; ++s2) {
            int idx = lane + (s2 << 6);
            if (v[s2] > bv) { bv = v[s2]; bi = idx; }
        }
        for (int off = 32; off; off >>= 1) {
            float ov = __shfl_xor(bv, off, 64);
            int   oi = __shfl_xor(bi, off, 64);
            if (ov > bv || (ov == bv && oi < bi)) { bv = ov; bi = oi; }
        }
        if (lane == 0) {
            perm[g * k + j] = g * npg + bi;
            vals[g * k + j] = bv;
            newid[g * npg + bi] = g * k + j;
        }
        if ((bi & 63) == lane) v[bi >> 6] = -1e30f;
    }
}

// ---- aggregation of SELECTED rows only, all 3 heads, concat split-bf16 [Gk][3072] ----
__global__ __launch_bounds__(256) void aggregate_sel(const float* __restrict__ xin,
    const float* __restrict__ sl, const float* __restrict__ mxf, const float* __restrict__ den,
    const int* __restrict__ offs, const int* __restrict__ cnt,
    const int* __restrict__ csrs, const float* __restrict__ csra,
    const int* __restrict__ perm,
    unsigned short* __restrict__ ahi, unsigned short* __restrict__ alo)
{
    int r = blockIdx.x, t = threadIdx.x;
    int i = perm[r];
    float aself[3];
#pragma unroll
    for (int h = 0; h < 3; ++h)
        aself[h] = expf(sl[i * 3 + h] - mxf[i * 3 + h]) / (den[i * 3 + h] + 1e-16f);
    const float* xr = xin + (long long)i * CC;
    float acc[3][4];
#pragma unroll
    for (int j = 0; j < 4; ++j) {
        float v = xr[t + (j << 8)];
#pragma unroll
        for (int h = 0; h < 3; ++h) acc[h][j] = aself[h] * v;
    }
    int beg = offs[i], num = cnt[i];
    for (int e = 0; e < num; ++e) {
        int s = csrs[beg + e];
        float a0 = csra[(beg + e) * 3 + 0];
        float a1 = csra[(beg + e) * 3 + 1];
        float a2 = csra[(beg + e) * 3 + 2];
        const float* sr = xin + (long long)s * CC;
#pragma unroll
        for (int j = 0; j < 4; ++j) {
            float v = sr[t + (j << 8)];
            acc[0][j] += a0 * v; acc[1][j] += a1 * v; acc[2][j] += a2 * v;
        }
    }
#pragma unroll
    for (int h = 0; h < 3; ++h)
#pragma unroll
        for (int j = 0; j < 4; ++j) {
            int c = t + (j << 8);
            float v = acc[h][j];
            unsigned short hh = f2bf(v);
            size_t idx = (size_t)r * HC3 + h * CC + c;
            ahi[idx] = hh;
            alo[idx] = f2bf(v - bf2f(hh));
        }
}

__global__ void remap_edges(int* __restrict__ s, int* __restrict__ d,
    int* __restrict__ m, const int* __restrict__ newid)
{
    int e = blockIdx.x * 256 + threadIdx.x;
    if (e >= EE) return;
    if (!m[e]) { s[e] = 0; d[e] = 0; return; }
    int ns = newid[s[e]], nd = newid[d[e]];
    int nm = (ns >= 0 && nd >= 0) ? 1 : 0;
    m[e] = nm; s[e] = nm ? ns : 0; d[e] = nm ? nd : 0;
}

// ---- two-pass readout ----
__global__ __launch_bounds__(256) void readout_part(const float* __restrict__ xn,
    int k, float* __restrict__ PM, float* __restrict__ PS)
{
    int g = blockIdx.x, ch = blockIdx.y, t = threadIdx.x;
    int rpc = k >> 3, r0 = ch * rpc;
#pragma unroll
    for (int j = 0; j < 4; ++j) {
        int c = t + (j << 8);
        float mx = -1e30f, sm = 0.f;
        for (int r = r0; r < r0 + rpc; ++r) {
            float vv = xn[((size_t)(g * k + r)) * CC + c];
            mx = fmaxf(mx, vv); sm += vv;
        }
        PM[(size_t)(g * 8 + ch) * CC + c] = mx;
        PS[(size_t)(g * 8 + ch) * CC + c] = sm;
    }
}

__global__ __launch_bounds__(256) void readout_fin(const float* __restrict__ PM,
    const float* __restrict__ PS, int k, float* __restrict__ R)
{
    int g = blockIdx.x, t = threadIdx.x;
#pragma unroll
    for (int j = 0; j < 4; ++j) {
        int c = t + (j << 8);
        float mx = -1e30f, sm = 0.f;
#pragma unroll
        for (int ch = 0; ch < 8; ++ch) {
            mx = fmaxf(mx, PM[(size_t)(g * 8 + ch) * CC + c]);
            sm += PS[(size_t)(g * 8 + ch) * CC + c];
        }
        R[g * 2048 + c] = mx;
        R[g * 2048 + 1024 + c] = sm / (float)k;
    }
}

__global__ void copy_edges(const int* __restrict__ ei, int* __restrict__ s,
    int* __restrict__ d, int* __restrict__ m)
{
    int e = blockIdx.x * 256 + threadIdx.x;
    if (e >= EE) return;
    s[e] = ei[e]; d[e] = ei[EE + e]; m[e] = 1;
}

// ---------------- final MLP ----------------
__global__ void zsum(const float* __restrict__ a, const float* __restrict__ b,
    const float* __restrict__ c, float* __restrict__ z)
{
    int i = blockIdx.x * 256 + threadIdx.x;
    if (i < NG * 2048) z[i] = a[i] + b[i] + c[i];
}

__global__ __launch_bounds__(256) void mlp1_kernel(const float* __restrict__ Z,
    const float* __restrict__ Wl1, const float* __restrict__ bl1, float* __restrict__ Z1)
{
    int c = blockIdx.x * 256 + threadIdx.x;
    int g = blockIdx.y;
    float acc = bl1[c];
    const float* zr = Z + g * 2048;
    for (int kk = 0; kk < 2048; ++kk) acc += zr[kk] * Wl1[kk * 1024 + c];
    Z1[g * 1024 + c] = acc > 0.f ? acc : 0.f;
}

__global__ __launch_bounds__(64) void mlp2_kernel(const float* __restrict__ Z1,
    const float* __restrict__ Wl2, const float* __restrict__ bl2, float* __restrict__ out)
{
    int b = blockIdx.x; int g = b >> 1, o = b & 1;
    int lane = threadIdx.x;
    const float* zr = Z1 + g * 1024;
    float s = 0.f;
    for (int j = lane; j < 1024; j += 64) s += zr[j] * Wl2[j * 2 + o];
    for (int off = 32; off; off >>= 1) s += __shfl_xor(s, off, 64);
    if (lane == 0) out[g * 2 + o] = s + bl2[o];
}

// ---------------- host ----------------
extern "C" void kernel_launch(void* const* d_in, const int* in_sizes, int n_in,
                              void* d_out, int out_size, void* d_ws, size_t ws_size,
                              hipStream_t stream)
{
    const float* x   = (const float*)d_in[0];
    const int*   ei  = (const int*)d_in[2];
    const float* W[3]    = {(const float*)d_in[4],  (const float*)d_in[11], (const float*)d_in[18]};
    const float* atts[3] = {(const float*)d_in[5],  (const float*)d_in[12], (const float*)d_in[19]};
    const float* attd[3] = {(const float*)d_in[6],  (const float*)d_in[13], (const float*)d_in[20]};
    const float* bb[3]   = {(const float*)d_in[7],  (const float*)d_in[14], (const float*)d_in[21]};
    const float* Wt[3]   = {(const float*)d_in[8],  (const float*)d_in[15], (const float*)d_in[22]};
    const float* bt[3]   = {(const float*)d_in[9],  (const float*)d_in[16], (const float*)d_in[23]};
    const float* pv[3]   = {(const float*)d_in[10], (const float*)d_in[17], (const float*)d_in[24]};
    const float* Wl1 = (const float*)d_in[25];
    const float* bl1 = (const float*)d_in[26];
    const float* Wl2 = (const float*)d_in[27];
    const float* bl2 = (const float*)d_in[28];
    float* out = (float*)d_out;

    const bool batched = ws_size >= (size_t)225 * 1024 * 1024;

    char* wp = (char*)d_ws;
    auto carve = [&](size_t bytes) -> void* {
        void* p = (void*)wp;
        wp += (bytes + 255) & ~(size_t)255;
        return p;
    };
    const int NMAX = 12800;
    const int GKMAX = 10240;
    const size_t MSZ = (size_t)CC * CC;
    const int NSLOT = batched ? 9 : 3;
    unsigned short* A2H = (unsigned short*)carve((size_t)GKMAX * HC3 * 2);  // 62.9 MB
    unsigned short* A2L = (unsigned short*)carve((size_t)GKMAX * HC3 * 2);  // 62.9 MB
    // weight temps alias into A2 (prep completes before aggregate_sel writes A2)
    unsigned short* WTH = (unsigned short*)A2H;
    unsigned short* WTL = WTH + (size_t)NSLOT * MSZ;
    unsigned short* WSH = WTL + (size_t)NSLOT * MSZ;
    unsigned short* WSL = (unsigned short*)A2L;
    float* MHT = (float*)(WSL + (size_t)NSLOT * MSZ);
    float* XN   = (float*)carve((size_t)GKMAX * CC * 4); // 41.9 MB
    unsigned short* B2H = (unsigned short*)carve((size_t)NSLOT * MSZ * 2);
    unsigned short* B2L = (unsigned short*)carve((size_t)NSLOT * MSZ * 2);
    float* PM   = (float*)carve((size_t)NG * 8 * CC * 4);
    float* PS   = (float*)carve((size_t)NG * 8 * CC * 4);
    float* ASV  = (float*)carve((size_t)3 * HC3 * 4);
    float* ADV  = (float*)carve((size_t)3 * HC3 * 4);
    float* QV   = (float*)carve((size_t)3 * HC3 * 4);
    float* BV   = (float*)carve((size_t)3 * CC * 4);
    float* AS   = (float*)carve((size_t)NMAX * 3 * 4);
    float* AD   = (float*)carve((size_t)NMAX * 3 * 4);
    float* T3   = (float*)carve((size_t)NMAX * 3 * 4);
    float* SL   = (float*)carve((size_t)NMAX * 3 * 4);
    unsigned* MXE = (unsigned*)carve((size_t)NMAX * 3 * 4);
    float* MXF  = (float*)carve((size_t)NMAX * 3 * 4);
    float* DEN  = (float*)carve((size_t)NMAX * 3 * 4);
    float* SEXP = (float*)carve((size_t)NMAX * 3 * 4);
    int* CNT    = (int*)carve((size_t)NMAX * 4);
    int* OFFS   = (int*)carve((size_t)NMAX * 4);
    int* CUR    = (int*)carve((size_t)NMAX * 4);
    int* NEWID  = (int*)carve((size_t)NMAX * 4);
    int* GT     = (int*)carve((size_t)NG * 4);
    int* CSRS   = (int*)carve((size_t)EE * 4);
    float* CSRA = (float*)carve((size_t)EE * 3 * 4);
    int* SRC = (int*)carve((size_t)EE * 4);
    int* DST = (int*)carve((size_t)EE * 4);
    int* MK  = (int*)carve((size_t)EE * 4);
    int* PERM  = (int*)carve((size_t)GKMAX * 4);
    float* VALS = (float*)carve((size_t)GKMAX * 4);
    float* PN  = (float*)carve(256);
    float* BVP = (float*)carve(256);
    float* R0 = (float*)carve((size_t)NG * 2048 * 4);
    float* R1 = (float*)carve((size_t)NG * 2048 * 4);
    float* R2 = (float*)carve((size_t)NG * 2048 * 4);
    float* Z  = (float*)carve((size_t)NG * 2048 * 4);
    float* Z1 = (float*)carve((size_t)NG * 1024 * 4);
    float* Rarr[3] = {R0, R1, R2};
    (void)in_sizes; (void)n_in; (void)out_size;

    copy_edges<<<cdiv(EE, 256), 256, 0, stream>>>(ei, SRC, DST, MK);

    auto prep = [&](int lbase, int nl) {
        int nslots = 3 * nl;
        split_w_all<<<dim3(4096, nslots), 256, 0, stream>>>(W[0], W[1], W[2], lbase, WSH, WSL);
        transpose_split_wt_all<<<dim3(32, 32, nslots), 256, 0, stream>>>(Wt[0], Wt[1], Wt[2],
                                                                          lbase, WTH, WTL);
        gemm_split<<<dim3(8, 8, nslots), 256, 0, stream>>>(WTH, WTL, CC, WSH, WSL, CC,
            MHT, CC, CC, MSZ, MSZ, MSZ);
        split_interleave_all<<<dim3(4096, nslots), 256, 0, stream>>>(MHT, B2H, B2L);
        qzero<<<cdiv(nl * HC3, 256), 256, 0, stream>>>(QV + (size_t)lbase * HC3, nl * HC3);
        qvec_all<<<dim3(4, 8, nslots), 256, 0, stream>>>(MHT, pv[0], pv[1], pv[2], lbase, QV);
        attvec_all<<<dim3(768, nl), 256, 0, stream>>>(W[0], W[1], W[2],
            atts[0], atts[1], atts[2], attd[0], attd[1], attd[2], lbase, ASV, ADV);
        bvinit_pnorm<<<dim3(5, nl), 256, 0, stream>>>(bt[0], bt[1], bt[2],
            pv[0], pv[1], pv[2], lbase, BV, PN);
        bvec_part<<<dim3(4, 12, nl), 256, 0, stream>>>(bb[0], bb[1], bb[2],
            Wt[0], Wt[1], Wt[2], lbase, BV);
        bvp_all<<<nl, 256, 0, stream>>>(BV, pv[0], pv[1], pv[2], lbase, BVP);
    };

    if (batched) prep(0, 3);

    const int ns_[3]  = {12800, 10240, 5120};
    const int npg_[3] = {200, 160, 80};
    const int kk_[3]  = {160, 80, 16};
    const int sk_[3]  = {2, 2, 4};     // split-K factors
    const float* xin = x;

    for (int L = 0; L < 3; ++L) {
        int n = ns_[L], npg = npg_[L], k = kk_[L];
        int gk = NG * k;
        if (!batched) prep(L, 1);
        size_t b2off = batched ? (size_t)L * 3 * MSZ : 0;
        attn_node<<<n / 4, 256, 0, stream>>>(xin, ASV + (size_t)L * HC3,
            ADV + (size_t)L * HC3, QV + (size_t)L * HC3, AS, AD, T3,
            SL, MXE, SEXP, CNT, CUR, n);
        edge_pass1<<<cdiv(EE, 256), 256, 0, stream>>>(SRC, DST, MK, AS, AD, MXE, SEXP, CNT);
        scan_graph<<<NG, 64, 0, stream>>>(CNT, OFFS, GT, npg);
        scan_finish<<<cdiv(n, 256), 256, 0, stream>>>(OFFS, GT, n, npg);
        decode_selfden<<<cdiv(n, 256), 256, 0, stream>>>(MXE, SL, SEXP, MXF, DEN, n);
        fill_alpha<<<cdiv(EE, 256), 256, 0, stream>>>(SRC, DST, MK, OFFS, CUR,
                                                      AS, AD, MXF, DEN, CSRS, CSRA);
        // fused score + topk (before any big GEMM)
        score_topk<<<NG, 64, 0, stream>>>(T3, SL, MXF, DEN, OFFS, CNT, CSRS, CSRA,
                                          BVP + L, PN + L, npg, k, PERM, VALS, NEWID);
        // aggregate selected rows -> split-K GEMM (atomic accum) -> finalize
        aggregate_sel<<<gk, 256, 0, stream>>>(xin, SL, MXF, DEN, OFFS, CNT, CSRS, CSRA,
                                              PERM, A2H, A2L);
        hipMemsetAsync(XN, 0, (size_t)gk * CC * 4, stream);
        gemm_splitk<<<dim3(gk / 128, 8, sk_[L]), 256, 0, stream>>>(A2H, A2L, HC3,
            B2H + b2off, B2L + b2off, HC3, XN, CC, HC3 / sk_[L]);
        finalize_xn<<<gk, 256, 0, stream>>>(XN, BV + (size_t)L * CC, VALS);
        readout_part<<<dim3(NG, 8), 256, 0, stream>>>(XN, k, PM, PS);
        readout_fin<<<NG, 256, 0, stream>>>(PM, PS, k, Rarr[L]);
        if (L < 2) remap_edges<<<cdiv(EE, 256), 256, 0, stream>>>(SRC, DST, MK, NEWID);
        xin = XN;
    }

    // final MLP
    zsum<<<cdiv(NG * 2048, 256), 256, 0, stream>>>(R0, R1, R2, Z);
    mlp1_kernel<<<dim3(4, NG), 256, 0, stream>>>(Z, Wl1, bl1, Z1);
    mlp2_kernel<<<NG * 2, 64, 0, stream>>>(Z1, Wl2, bl2, out);
}

// Round 8
// 1334.589 us; speedup vs baseline: 3.7767x; 1.0386x over previous
//
#include <hip/hip_runtime.h>
#include <math.h>

// Static problem dims
#define NG 64          // graphs
#define EE 64000       // edges
#define HC3 3072       // H*C
#define CC 1024        // C (and input feature dim)

static inline int cdiv(int a, int b) { return (a + b - 1) / b; }

typedef float f4_t __attribute__((ext_vector_type(4)));
typedef short s8_t __attribute__((ext_vector_type(8)));

__device__ __forceinline__ float lrelu(float x) { return x > 0.f ? x : 0.2f * x; }
__device__ __forceinline__ unsigned fenc(float f) {
    unsigned u = __float_as_uint(f);
    return (u & 0x80000000u) ? ~u : (u | 0x80000000u);
}
__device__ __forceinline__ float fdec(unsigned e) {
    return (e & 0x80000000u) ? __uint_as_float(e ^ 0x80000000u) : __uint_as_float(~e);
}
__device__ __forceinline__ unsigned short f2bf(float f) {
    unsigned u = __float_as_uint(f);
    u += 0x7fffu + ((u >> 16) & 1u);
    return (unsigned short)(u >> 16);
}
__device__ __forceinline__ float bf2f(unsigned short h) {
    return __uint_as_float(((unsigned)h) << 16);
}
__device__ __forceinline__ void gll16(const unsigned short* g, unsigned short* l) {
    __builtin_amdgcn_global_load_lds(
        (const __attribute__((address_space(1))) void*)g,
        (__attribute__((address_space(3))) void*)l, 16, 0, 0);
}

// ======== prep GEMM: C = A @ B^T per slot; epilogue writes split-bf16 B2 interleaved ========
// slot -> (lrel = slot/3, h = slot%3); B2[lrel*3MSZ + row*HC3 + h*CC + col]
__global__ __launch_bounds__(256) void gemm_prep(
    const unsigned short* __restrict__ Ahi, const unsigned short* __restrict__ Alo,
    const unsigned short* __restrict__ Bhi, const unsigned short* __restrict__ Blo,
    unsigned short* __restrict__ ohi, unsigned short* __restrict__ olo, int K)
{
    __shared__ unsigned short sAH[128 * 32];
    __shared__ unsigned short sAL[128 * 32];
    __shared__ unsigned short sBH[128 * 32];
    __shared__ unsigned short sBL[128 * 32];

    const size_t MSZ = (size_t)CC * CC;
    const int slot = blockIdx.z;
    const int lrel = slot / 3, hh = slot % 3;
    Ahi += slot * MSZ; Alo += slot * MSZ;
    Bhi += slot * MSZ; Blo += slot * MSZ;

    const int t = threadIdx.x;
    const int w = t >> 6, lane = t & 63;
    const int wr = w >> 1, wc = w & 1;
    const int row0 = blockIdx.y * 128, col0 = blockIdx.x * 128;

    const int srow = w * 16 + (lane >> 2);
    const int skg = (((lane & 3) ^ ((lane >> 3) & 3)) << 3);
    const size_t aoff0 = (size_t)(row0 + srow) * CC + skg;
    const size_t aoff1 = (size_t)(row0 + 64 + srow) * CC + skg;
    const size_t boff0 = (size_t)(col0 + srow) * CC + skg;
    const size_t boff1 = (size_t)(col0 + 64 + srow) * CC + skg;
    const int l0 = (w * 16) * 32;
    const int l1 = (64 + w * 16) * 32;

    f4_t acc[4][4];
    const f4_t z4 = {0.f, 0.f, 0.f, 0.f};
#pragma unroll
    for (int i = 0; i < 4; ++i)
#pragma unroll
        for (int j = 0; j < 4; ++j) acc[i][j] = z4;

    const int mrow0 = wr * 64 + (lane & 15);
    const int nrow0 = wc * 64 + (lane & 15);
    const int kslot = (((lane >> 4) ^ ((lane >> 1) & 3)) << 3);

    for (int k0 = 0; k0 < K; k0 += 32) {
        gll16(Ahi + aoff0 + k0, &sAH[l0]);
        gll16(Ahi + aoff1 + k0, &sAH[l1]);
        gll16(Alo + aoff0 + k0, &sAL[l0]);
        gll16(Alo + aoff1 + k0, &sAL[l1]);
        gll16(Bhi + boff0 + k0, &sBH[l0]);
        gll16(Bhi + boff1 + k0, &sBH[l1]);
        gll16(Blo + boff0 + k0, &sBL[l0]);
        gll16(Blo + boff1 + k0, &sBL[l1]);
        __syncthreads();

        s8_t ah[4], al[4], bh[4], bl[4];
#pragma unroll
        for (int mt = 0; mt < 4; ++mt) {
            ah[mt] = *(const s8_t*)&sAH[(mrow0 + mt * 16) * 32 + kslot];
            al[mt] = *(const s8_t*)&sAL[(mrow0 + mt * 16) * 32 + kslot];
        }
#pragma unroll
        for (int nt = 0; nt < 4; ++nt) {
            bh[nt] = *(const s8_t*)&sBH[(nrow0 + nt * 16) * 32 + kslot];
            bl[nt] = *(const s8_t*)&sBL[(nrow0 + nt * 16) * 32 + kslot];
        }
#pragma unroll
        for (int mt = 0; mt < 4; ++mt)
#pragma unroll
            for (int nt = 0; nt < 4; ++nt) {
                acc[mt][nt] = __builtin_amdgcn_mfma_f32_16x16x32_bf16(ah[mt], bh[nt], acc[mt][nt], 0, 0, 0);
                acc[mt][nt] = __builtin_amdgcn_mfma_f32_16x16x32_bf16(ah[mt], bl[nt], acc[mt][nt], 0, 0, 0);
                acc[mt][nt] = __builtin_amdgcn_mfma_f32_16x16x32_bf16(al[mt], bh[nt], acc[mt][nt], 0, 0, 0);
            }
        __syncthreads();
    }

#pragma unroll
    for (int mt = 0; mt < 4; ++mt) {
        int row = row0 + wr * 64 + mt * 16 + (lane >> 4) * 4;
#pragma unroll
        for (int nt = 0; nt < 4; ++nt) {
            int col = col0 + wc * 64 + nt * 16 + (lane & 15);
#pragma unroll
            for (int r = 0; r < 4; ++r) {
                float v = acc[mt][nt][r];
                unsigned short hv = f2bf(v);
                size_t dst = (size_t)lrel * 3 * MSZ + (size_t)(row + r) * HC3 + hh * CC + col;
                ohi[dst] = hv;
                olo[dst] = f2bf(v - bf2f(hv));
            }
        }
    }
}

// ======== main GEMM: split-K + L2-friendly grid, fp32 atomicAdd into zeroed C ========
__global__ __launch_bounds__(256) void gemm_splitk(
    const unsigned short* __restrict__ Ahi, const unsigned short* __restrict__ Alo, int lda,
    const unsigned short* __restrict__ Bhi, const unsigned short* __restrict__ Blo, int ldb,
    float* __restrict__ C, int ldc, int ksub)
{
    __shared__ unsigned short sAH[128 * 32];
    __shared__ unsigned short sAL[128 * 32];
    __shared__ unsigned short sBH[128 * 32];
    __shared__ unsigned short sBL[128 * 32];

    const int t = threadIdx.x;
    const int w = t >> 6, lane = t & 63;
    const int wr = w >> 1, wc = w & 1;
    const int row0 = blockIdx.x * 128, col0 = blockIdx.y * 128;
    const int kbase = blockIdx.z * ksub;

    const int srow = w * 16 + (lane >> 2);
    const int skg = (((lane & 3) ^ ((lane >> 3) & 3)) << 3);
    const size_t aoff0 = (size_t)(row0 + srow) * lda + skg;
    const size_t aoff1 = (size_t)(row0 + 64 + srow) * lda + skg;
    const size_t boff0 = (size_t)(col0 + srow) * ldb + skg;
    const size_t boff1 = (size_t)(col0 + 64 + srow) * ldb + skg;
    const int l0 = (w * 16) * 32;
    const int l1 = (64 + w * 16) * 32;

    f4_t acc[4][4];
    const f4_t z4 = {0.f, 0.f, 0.f, 0.f};
#pragma unroll
    for (int i = 0; i < 4; ++i)
#pragma unroll
        for (int j = 0; j < 4; ++j) acc[i][j] = z4;

    const int mrow0 = wr * 64 + (lane & 15);
    const int nrow0 = wc * 64 + (lane & 15);
    const int kslot = (((lane >> 4) ^ ((lane >> 1) & 3)) << 3);

    for (int k0 = kbase; k0 < kbase + ksub; k0 += 32) {
        gll16(Ahi + aoff0 + k0, &sAH[l0]);
        gll16(Ahi + aoff1 + k0, &sAH[l1]);
        gll16(Alo + aoff0 + k0, &sAL[l0]);
        gll16(Alo + aoff1 + k0, &sAL[l1]);
        gll16(Bhi + boff0 + k0, &sBH[l0]);
        gll16(Bhi + boff1 + k0, &sBH[l1]);
        gll16(Blo + boff0 + k0, &sBL[l0]);
        gll16(Blo + boff1 + k0, &sBL[l1]);
        __syncthreads();

        s8_t ah[4], al[4], bh[4], bl[4];
#pragma unroll
        for (int mt = 0; mt < 4; ++mt) {
            ah[mt] = *(const s8_t*)&sAH[(mrow0 + mt * 16) * 32 + kslot];
            al[mt] = *(const s8_t*)&sAL[(mrow0 + mt * 16) * 32 + kslot];
        }
#pragma unroll
        for (int nt = 0; nt < 4; ++nt) {
            bh[nt] = *(const s8_t*)&sBH[(nrow0 + nt * 16) * 32 + kslot];
            bl[nt] = *(const s8_t*)&sBL[(nrow0 + nt * 16) * 32 + kslot];
        }
#pragma unroll
        for (int mt = 0; mt < 4; ++mt)
#pragma unroll
            for (int nt = 0; nt < 4; ++nt) {
                acc[mt][nt] = __builtin_amdgcn_mfma_f32_16x16x32_bf16(ah[mt], bh[nt], acc[mt][nt], 0, 0, 0);
                acc[mt][nt] = __builtin_amdgcn_mfma_f32_16x16x32_bf16(ah[mt], bl[nt], acc[mt][nt], 0, 0, 0);
                acc[mt][nt] = __builtin_amdgcn_mfma_f32_16x16x32_bf16(al[mt], bh[nt], acc[mt][nt], 0, 0, 0);
            }
        __syncthreads();
    }

#pragma unroll
    for (int mt = 0; mt < 4; ++mt) {
        int row = row0 + wr * 64 + mt * 16 + (lane >> 4) * 4;
#pragma unroll
        for (int nt = 0; nt < 4; ++nt) {
            int col = col0 + wc * 64 + nt * 16 + (lane & 15);
#pragma unroll
            for (int r = 0; r < 4; ++r)
                atomicAdd(&C[(size_t)(row + r) * ldc + col], acc[mt][nt][r]);
        }
    }
}

// ---- weight prep ----
__global__ void split_w_all(const float* __restrict__ w0, const float* __restrict__ w1,
    const float* __restrict__ w2, int lbase,
    unsigned short* __restrict__ ohi, unsigned short* __restrict__ olo)
{
    const float* Wp[3] = {w0, w1, w2};
    int slot = blockIdx.y;
    int L = lbase + slot / 3, h = slot % 3;
    int idx = blockIdx.x * 256 + threadIdx.x;
    int r = idx >> 10, c = idx & 1023;
    float v = Wp[L][(size_t)r * HC3 + h * CC + c];
    unsigned short hh = f2bf(v);
    ohi[(size_t)slot * 1048576 + idx] = hh;
    olo[(size_t)slot * 1048576 + idx] = f2bf(v - bf2f(hh));
}

__global__ void transpose_split_wt_all(const float* __restrict__ w0,
    const float* __restrict__ w1, const float* __restrict__ w2, int lbase,
    unsigned short* __restrict__ ohi, unsigned short* __restrict__ olo)
{
    const float* Wp[3] = {w0, w1, w2};
    int slot = blockIdx.z;
    int L = lbase + slot / 3, h = slot % 3;
    __shared__ float tile[32][33];
    int t = threadIdx.x, tr = t >> 5, tc = t & 31;
    int r0 = blockIdx.y * 32, c0 = blockIdx.x * 32;
    const float* in = Wp[L] + (size_t)h * 1048576;
#pragma unroll
    for (int i = 0; i < 4; ++i)
        tile[tr + i * 8][tc] = in[(size_t)(r0 + tr + i * 8) * CC + c0 + tc];
    __syncthreads();
    unsigned short* oh = ohi + (size_t)slot * 1048576;
    unsigned short* ol = olo + (size_t)slot * 1048576;
#pragma unroll
    for (int i = 0; i < 4; ++i) {
        int oc = c0 + tr + i * 8;
        int orr = r0 + tc;
        float v = tile[tc][tr + i * 8];
        unsigned short hh = f2bf(v);
        oh[(size_t)oc * CC + orr] = hh;
        ol[(size_t)oc * CC + orr] = f2bf(v - bf2f(hh));
    }
}

// ---- u[L][h*CC+m] = Wt_L row (h*CC+m) . p_L  (one wave per row) ----
__global__ __launch_bounds__(256) void wtp_all(const float* __restrict__ wt0,
    const float* __restrict__ wt1, const float* __restrict__ wt2,
    const float* __restrict__ p0, const float* __restrict__ p1, const float* __restrict__ p2,
    int lbase, float* __restrict__ U)
{
    const float* Wp[3] = {wt0, wt1, wt2};
    const float* Pp[3] = {p0, p1, p2};
    int wid = blockIdx.x * 4 + (threadIdx.x >> 6);   // 0 .. nl*3072-1
    int lane = threadIdx.x & 63;
    int L = lbase + wid / HC3, rr = wid % HC3;
    const float* row = Wp[L] + (size_t)rr * CC;
    const float* p = Pp[L];
    float s = 0.f;
    for (int c = lane; c < CC; c += 64) s += row[c] * p[c];
    for (int off = 32; off; off >>= 1) s += __shfl_xor(s, off, 64);
    if (lane == 0) U[(size_t)L * HC3 + rr] = s;
}

// ---- attention helper vectors + q (q_h = W_h u_h), batched over layers ----
__global__ __launch_bounds__(256) void attvec_all(const float* __restrict__ w0,
    const float* __restrict__ w1, const float* __restrict__ w2,
    const float* __restrict__ as0, const float* __restrict__ as1, const float* __restrict__ as2,
    const float* __restrict__ ad0, const float* __restrict__ ad1, const float* __restrict__ ad2,
    const float* __restrict__ U, int lbase,
    float* __restrict__ asv, float* __restrict__ adv, float* __restrict__ qv)
{
    const float* Wp[3] = {w0, w1, w2};
    const float* Sp[3] = {as0, as1, as2};
    const float* Dp[3] = {ad0, ad1, ad2};
    int L = lbase + blockIdx.y;
    int wid = blockIdx.x * 4 + (threadIdx.x >> 6);
    int lane = threadIdx.x & 63;
    int h = wid >> 10, kk = wid & 1023;
    const float* wr = Wp[L] + (long long)kk * HC3 + h * CC;
    const float* sa = Sp[L] + h * CC;
    const float* da = Dp[L] + h * CC;
    const float* ua = U + (size_t)L * HC3 + h * CC;
    float ss = 0.f, dd = 0.f, qq = 0.f;
    for (int c = lane; c < CC; c += 64) {
        float w = wr[c];
        ss += w * sa[c]; dd += w * da[c]; qq += w * ua[c];
    }
    for (int off = 32; off; off >>= 1) {
        ss += __shfl_xor(ss, off, 64); dd += __shfl_xor(dd, off, 64); qq += __shfl_xor(qq, off, 64);
    }
    if (lane == 0) {
        asv[(size_t)L * HC3 + h * CC + kk] = ss;
        adv[(size_t)L * HC3 + h * CC + kk] = dd;
        qv[(size_t)L * HC3 + h * CC + kk] = qq;
    }
}

// ---- per-node: a_s, a_d, t dots + node init ----
__global__ __launch_bounds__(256) void attn_node(const float* __restrict__ xin,
    const float* __restrict__ asv, const float* __restrict__ adv, const float* __restrict__ q,
    float* __restrict__ AS, float* __restrict__ AD, float* __restrict__ T3,
    float* __restrict__ sl, unsigned* __restrict__ mxe, float* __restrict__ sexp,
    int* __restrict__ cnt, int* __restrict__ cur, int n)
{
    int node = blockIdx.x * 4 + (threadIdx.x >> 6);
    int lane = threadIdx.x & 63;
    if (node >= n) return;
    const float* xr = xin + (long long)node * CC;
    float s0 = 0, s1 = 0, s2 = 0, d0 = 0, d1 = 0, d2 = 0, t0 = 0, t1 = 0, t2 = 0;
    for (int j = lane; j < CC; j += 64) {
        float v = xr[j];
        s0 += v * asv[j]; s1 += v * asv[CC + j]; s2 += v * asv[2 * CC + j];
        d0 += v * adv[j]; d1 += v * adv[CC + j]; d2 += v * adv[2 * CC + j];
        t0 += v * q[j];   t1 += v * q[CC + j];   t2 += v * q[2 * CC + j];
    }
    for (int off = 32; off; off >>= 1) {
        s0 += __shfl_xor(s0, off, 64); s1 += __shfl_xor(s1, off, 64); s2 += __shfl_xor(s2, off, 64);
        d0 += __shfl_xor(d0, off, 64); d1 += __shfl_xor(d1, off, 64); d2 += __shfl_xor(d2, off, 64);
        t0 += __shfl_xor(t0, off, 64); t1 += __shfl_xor(t1, off, 64); t2 += __shfl_xor(t2, off, 64);
    }
    if (lane == 0) {
        AS[node * 3 + 0] = s0; AS[node * 3 + 1] = s1; AS[node * 3 + 2] = s2;
        AD[node * 3 + 0] = d0; AD[node * 3 + 1] = d1; AD[node * 3 + 2] = d2;
        T3[node * 3 + 0] = t0; T3[node * 3 + 1] = t1; T3[node * 3 + 2] = t2;
        float l0v = lrelu(s0 + d0), l1v = lrelu(s1 + d1), l2v = lrelu(s2 + d2);
        sl[node * 3 + 0] = l0v; sl[node * 3 + 1] = l1v; sl[node * 3 + 2] = l2v;
        mxe[node * 3 + 0] = fenc(l0v); mxe[node * 3 + 1] = fenc(l1v); mxe[node * 3 + 2] = fenc(l2v);
        sexp[node * 3 + 0] = 0.f; sexp[node * 3 + 1] = 0.f; sexp[node * 3 + 2] = 0.f;
        cnt[node] = 0; cur[node] = 0;
    }
}

// ---- BV init + pnorm ----
__global__ void bvinit_pnorm(const float* __restrict__ bt0, const float* __restrict__ bt1,
    const float* __restrict__ bt2, const float* __restrict__ p0, const float* __restrict__ p1,
    const float* __restrict__ p2, int lbase, float* __restrict__ BV, float* __restrict__ PN)
{
    const float* Bp[3] = {bt0, bt1, bt2};
    const float* Pp[3] = {p0, p1, p2};
    int L = lbase + blockIdx.y;
    if (blockIdx.x < 4) {
        int c = blockIdx.x * 256 + threadIdx.x;
        BV[(size_t)L * CC + c] = Bp[L][c];
    } else {
        __shared__ float red[256];
        int t = threadIdx.x;
        const float* p = Pp[L];
        float s = 0.f;
        for (int j = t; j < CC; j += 256) { float v = p[j]; s += v * v; }
        red[t] = s; __syncthreads();
        for (int off = 128; off; off >>= 1) { if (t < off) red[t] += red[t + off]; __syncthreads(); }
        if (t == 0) PN[L] = sqrtf(red[0]);
    }
}

__global__ void bvec_part(const float* __restrict__ b0, const float* __restrict__ b1,
    const float* __restrict__ b2, const float* __restrict__ wt0, const float* __restrict__ wt1,
    const float* __restrict__ wt2, int lbase, float* __restrict__ BV)
{
    const float* bp[3] = {b0, b1, b2};
    const float* wp[3] = {wt0, wt1, wt2};
    int L = lbase + blockIdx.z;
    int c = blockIdx.x * 256 + threadIdx.x;
    int k0 = blockIdx.y * 256;
    const float* b = bp[L];
    const float* Wt = wp[L];
    float acc = 0.f;
#pragma unroll 8
    for (int k = k0; k < k0 + 256; ++k) acc += b[k] * Wt[(size_t)k * CC + c];
    atomicAdd(&BV[(size_t)L * CC + c], acc);
}

__global__ void bvp_all(const float* __restrict__ BV, const float* __restrict__ p0,
    const float* __restrict__ p1, const float* __restrict__ p2, int lbase,
    float* __restrict__ BVP)
{
    const float* Pp[3] = {p0, p1, p2};
    int L = lbase + blockIdx.x;
    __shared__ float red[256];
    int t = threadIdx.x;
    const float* p = Pp[L];
    float s = 0.f;
    for (int j = t; j < CC; j += 256) s += BV[(size_t)L * CC + j] * p[j];
    red[t] = s; __syncthreads();
    for (int off = 128; off; off >>= 1) { if (t < off) red[t] += red[t + off]; __syncthreads(); }
    if (t == 0) BVP[L] = red[0];
}

// ---- fused edge pass: count + segment max + unnormalized exp-sum ----
__global__ void edge_pass1(const int* __restrict__ src, const int* __restrict__ dst,
    const int* __restrict__ msk, const float* __restrict__ AS, const float* __restrict__ AD,
    unsigned* __restrict__ mxe, float* __restrict__ sexp, int* __restrict__ cnt)
{
    int e = blockIdx.x * 256 + threadIdx.x;
    if (e >= EE || !msk[e]) return;
    int s = src[e], d = dst[e];
    atomicAdd(&cnt[d], 1);
#pragma unroll
    for (int h = 0; h < 3; ++h) {
        float l = lrelu(AS[s * 3 + h] + AD[d * 3 + h]);
        atomicMax(&mxe[d * 3 + h], fenc(l));
        atomicAdd(&sexp[d * 3 + h], expf(l));
    }
}

// ---- per-graph exclusive prefix via wave shuffle scan (1 wave per graph) ----
__global__ __launch_bounds__(64) void scan_graph(const int* __restrict__ cnt,
    int* __restrict__ offs, int* __restrict__ gt, int npg)
{
    int g = blockIdx.x, lane = threadIdx.x;
    int run = 0;
    for (int c0 = 0; c0 < npg; c0 += 64) {
        int i = c0 + lane;
        int v = (i < npg) ? cnt[g * npg + i] : 0;
        int s = v;
#pragma unroll
        for (int off = 1; off < 64; off <<= 1) {
            int o = __shfl_up(s, off, 64);
            if (lane >= off) s += o;
        }
        if (i < npg) offs[g * npg + i] = run + s - v;
        run += __shfl(s, 63, 64);
    }
    if (lane == 0) gt[g] = run;
}

// ---- merged: offs += base(graph), decode max, den (per node) ----
__global__ void post_edge(int* __restrict__ offs, const int* __restrict__ gt,
    const unsigned* __restrict__ mxe, const float* __restrict__ sl,
    const float* __restrict__ sexp, float* __restrict__ mxf, float* __restrict__ den,
    int n, int npg)
{
    int i = blockIdx.x * 256 + threadIdx.x;
    if (i >= n) return;
    int g = i / npg;
    int base = 0;
    for (int gg = 0; gg < g; ++gg) base += gt[gg];
    offs[i] += base;
#pragma unroll
    for (int h = 0; h < 3; ++h) {
        float m = fdec(mxe[i * 3 + h]);
        mxf[i * 3 + h] = m;
        den[i * 3 + h] = expf(sl[i * 3 + h] - m) + expf(-m) * sexp[i * 3 + h];
    }
}

__global__ void fill_alpha(const int* __restrict__ src, const int* __restrict__ dst,
    const int* __restrict__ msk, const int* __restrict__ offs, int* __restrict__ cur,
    const float* __restrict__ AS, const float* __restrict__ AD,
    const float* __restrict__ mxf, const float* __restrict__ den,
    int* __restrict__ csrs, float* __restrict__ csra)
{
    int e = blockIdx.x * 256 + threadIdx.x;
    if (e >= EE || !msk[e]) return;
    int s = src[e], d = dst[e];
    int pos = offs[d] + atomicAdd(&cur[d], 1);
    csrs[pos] = s;
#pragma unroll
    for (int h = 0; h < 3; ++h) {
        float l = lrelu(AS[s * 3 + h] + AD[d * 3 + h]);
        float ex = expf(l - mxf[d * 3 + h]);
        csra[pos * 3 + h] = ex / (den[d * 3 + h] + 1e-16f);
    }
}

// ---- fused score (scalar CSR) + topk per graph ----
__global__ __launch_bounds__(64) void score_topk(const float* __restrict__ T3,
    const float* __restrict__ sl, const float* __restrict__ mxf, const float* __restrict__ den,
    const int* __restrict__ offs, const int* __restrict__ cnt, const int* __restrict__ csrs,
    const float* __restrict__ csra, const float* __restrict__ bvp, const float* __restrict__ pn,
    int npg, int k, int* __restrict__ perm, float* __restrict__ vals, int* __restrict__ newid)
{
    __shared__ float sc[256];
    int g = blockIdx.x, lane = threadIdx.x;
    float bv0 = bvp[0], pn0 = pn[0];
    for (int ii = lane; ii < npg; ii += 64) {
        int i = g * npg + ii;
        float s = 0.f;
#pragma unroll
        for (int h = 0; h < 3; ++h) {
            float aself = expf(sl[i * 3 + h] - mxf[i * 3 + h]) / (den[i * 3 + h] + 1e-16f);
            s += aself * T3[i * 3 + h];
        }
        int beg = offs[i], num = cnt[i];
        for (int e = 0; e < num; ++e) {
            int sn = csrs[beg + e];
#pragma unroll
            for (int h = 0; h < 3; ++h) s += csra[(beg + e) * 3 + h] * T3[sn * 3 + h];
        }
        sc[ii] = tanhf((s + bv0) / pn0);
        newid[i] = -1;
    }
    __syncthreads();
    float v[4];
    int nsl = (npg + 63) >> 6;
#pragma unroll
    for (int s2 = 0; s2 < 4; ++s2) {
        int idx = lane + (s2 << 6);
        v[s2] = (s2 < nsl && idx < npg) ? sc[idx] : -1e30f;
    }
    for (int j = 0; j < k; ++j) {
        float bv = -2e30f; int bi = 0x7fffffff;
#pragma unroll
        for (int s2 = 0; s2 < 4; ++s2) {
            int idx = lane + (s2 << 6);
            if (v[s2] > bv) { bv = v[s2]; bi = idx; }
        }
        for (int off = 32; off; off >>= 1) {
            float ov = __shfl_xor(bv, off, 64);
            int   oi = __shfl_xor(bi, off, 64);
            if (ov > bv || (ov == bv && oi < bi)) { bv = ov; bi = oi; }
        }
        if (lane == 0) {
            perm[g * k + j] = g * npg + bi;
            vals[g * k + j] = bv;
            newid[g * npg + bi] = g * k + j;
        }
        if ((bi & 63) == lane) v[bi >> 6] = -1e30f;
    }
}

// ---- aggregation of SELECTED rows only, all 3 heads, concat split-bf16 [Gk][3072] ----
__global__ __launch_bounds__(256) void aggregate_sel(const float* __restrict__ xin,
    const float* __restrict__ sl, const float* __restrict__ mxf, const float* __restrict__ den,
    const int* __restrict__ offs, const int* __restrict__ cnt,
    const int* __restrict__ csrs, const float* __restrict__ csra,
    const int* __restrict__ perm,
    unsigned short* __restrict__ ahi, unsigned short* __restrict__ alo)
{
    int r = blockIdx.x, t = threadIdx.x;
    int i = perm[r];
    float aself[3];
#pragma unroll
    for (int h = 0; h < 3; ++h)
        aself[h] = expf(sl[i * 3 + h] - mxf[i * 3 + h]) / (den[i * 3 + h] + 1e-16f);
    const float* xr = xin + (long long)i * CC;
    float acc[3][4];
#pragma unroll
    for (int j = 0; j < 4; ++j) {
        float v = xr[t + (j << 8)];
#pragma unroll
        for (int h = 0; h < 3; ++h) acc[h][j] = aself[h] * v;
    }
    int beg = offs[i], num = cnt[i];
    for (int e = 0; e < num; ++e) {
        int s = csrs[beg + e];
        float a0 = csra[(beg + e) * 3 + 0];
        float a1 = csra[(beg + e) * 3 + 1];
        float a2 = csra[(beg + e) * 3 + 2];
        const float* sr = xin + (long long)s * CC;
#pragma unroll
        for (int j = 0; j < 4; ++j) {
            float v = sr[t + (j << 8)];
            acc[0][j] += a0 * v; acc[1][j] += a1 * v; acc[2][j] += a2 * v;
        }
    }
#pragma unroll
    for (int h = 0; h < 3; ++h)
#pragma unroll
        for (int j = 0; j < 4; ++j) {
            int c = t + (j << 8);
            float v = acc[h][j];
            unsigned short hh = f2bf(v);
            size_t idx = (size_t)r * HC3 + h * CC + c;
            ahi[idx] = hh;
            alo[idx] = f2bf(v - bf2f(hh));
        }
}

__global__ void remap_edges(int* __restrict__ s, int* __restrict__ d,
    int* __restrict__ m, const int* __restrict__ newid)
{
    int e = blockIdx.x * 256 + threadIdx.x;
    if (e >= EE) return;
    if (!m[e]) { s[e] = 0; d[e] = 0; return; }
    int ns = newid[s[e]], nd = newid[d[e]];
    int nm = (ns >= 0 && nd >= 0) ? 1 : 0;
    m[e] = nm; s[e] = nm ? ns : 0; d[e] = nm ? nd : 0;
}

// ---- readout pass 1 with fused finalize: xn_fin = (xn + BV) * vals[row], written back ----
__global__ __launch_bounds__(256) void readout_part(float* __restrict__ xn,
    const float* __restrict__ BV, const float* __restrict__ vals,
    int k, float* __restrict__ PM, float* __restrict__ PS)
{
    int g = blockIdx.x, ch = blockIdx.y, t = threadIdx.x;
    int rpc = k >> 3, r0 = ch * rpc;
#pragma unroll
    for (int j = 0; j < 4; ++j) {
        int c = t + (j << 8);
        float bvc = BV[c];
        float mx = -1e30f, sm = 0.f;
        for (int r = r0; r < r0 + rpc; ++r) {
            size_t idx = ((size_t)(g * k + r)) * CC + c;
            float vv = (xn[idx] + bvc) * vals[g * k + r];
            xn[idx] = vv;
            mx = fmaxf(mx, vv); sm += vv;
        }
        PM[(size_t)(g * 8 + ch) * CC + c] = mx;
        PS[(size_t)(g * 8 + ch) * CC + c] = sm;
    }
}

__global__ __launch_bounds__(256) void readout_fin(const float* __restrict__ PM,
    const float* __restrict__ PS, int k, float* __restrict__ R)
{
    int g = blockIdx.x, t = threadIdx.x;
#pragma unroll
    for (int j = 0; j < 4; ++j) {
        int c = t + (j << 8);
        float mx = -1e30f, sm = 0.f;
#pragma unroll
        for (int ch = 0; ch < 8; ++ch) {
            mx = fmaxf(mx, PM[(size_t)(g * 8 + ch) * CC + c]);
            sm += PS[(size_t)(g * 8 + ch) * CC + c];
        }
        R[g * 2048 + c] = mx;
        R[g * 2048 + 1024 + c] = sm / (float)k;
    }
}

__global__ void copy_edges(const int* __restrict__ ei, int* __restrict__ s,
    int* __restrict__ d, int* __restrict__ m)
{
    int e = blockIdx.x * 256 + threadIdx.x;
    if (e >= EE) return;
    s[e] = ei[e]; d[e] = ei[EE + e]; m[e] = 1;
}

// ---------------- final MLP (zsum fused into mlp1) ----------------
__global__ __launch_bounds__(256) void mlp1_kernel(const float* __restrict__ R0,
    const float* __restrict__ R1, const float* __restrict__ R2,
    const float* __restrict__ Wl1, const float* __restrict__ bl1, float* __restrict__ Z1)
{
    int c = blockIdx.x * 256 + threadIdx.x;
    int g = blockIdx.y;
    float acc = bl1[c];
    const float* r0 = R0 + g * 2048;
    const float* r1 = R1 + g * 2048;
    const float* r2 = R2 + g * 2048;
    for (int kk = 0; kk < 2048; ++kk)
        acc += (r0[kk] + r1[kk] + r2[kk]) * Wl1[kk * 1024 + c];
    Z1[g * 1024 + c] = acc > 0.f ? acc : 0.f;
}

__global__ __launch_bounds__(64) void mlp2_kernel(const float* __restrict__ Z1,
    const float* __restrict__ Wl2, const float* __restrict__ bl2, float* __restrict__ out)
{
    int b = blockIdx.x; int g = b >> 1, o = b & 1;
    int lane = threadIdx.x;
    const float* zr = Z1 + g * 1024;
    float s = 0.f;
    for (int j = lane; j < 1024; j += 64) s += zr[j] * Wl2[j * 2 + o];
    for (int off = 32; off; off >>= 1) s += __shfl_xor(s, off, 64);
    if (lane == 0) out[g * 2 + o] = s + bl2[o];
}

// ---------------- host ----------------
extern "C" void kernel_launch(void* const* d_in, const int* in_sizes, int n_in,
                              void* d_out, int out_size, void* d_ws, size_t ws_size,
                              hipStream_t stream)
{
    const float* x   = (const float*)d_in[0];
    const int*   ei  = (const int*)d_in[2];
    const float* W[3]    = {(const float*)d_in[4],  (const float*)d_in[11], (const float*)d_in[18]};
    const float* atts[3] = {(const float*)d_in[5],  (const float*)d_in[12], (const float*)d_in[19]};
    const float* attd[3] = {(const float*)d_in[6],  (const float*)d_in[13], (const float*)d_in[20]};
    const float* bb[3]   = {(const float*)d_in[7],  (const float*)d_in[14], (const float*)d_in[21]};
    const float* Wt[3]   = {(const float*)d_in[8],  (const float*)d_in[15], (const float*)d_in[22]};
    const float* bt[3]   = {(const float*)d_in[9],  (const float*)d_in[16], (const float*)d_in[23]};
    const float* pv[3]   = {(const float*)d_in[10], (const float*)d_in[17], (const float*)d_in[24]};
    const float* Wl1 = (const float*)d_in[25];
    const float* bl1 = (const float*)d_in[26];
    const float* Wl2 = (const float*)d_in[27];
    const float* bl2 = (const float*)d_in[28];
    float* out = (float*)d_out;

    const bool batched = ws_size >= (size_t)225 * 1024 * 1024;

    char* wp = (char*)d_ws;
    auto carve = [&](size_t bytes) -> void* {
        void* p = (void*)wp;
        wp += (bytes + 255) & ~(size_t)255;
        return p;
    };
    const int NMAX = 12800;
    const int GKMAX = 10240;
    const size_t MSZ = (size_t)CC * CC;
    const int NSLOT = batched ? 9 : 3;
    unsigned short* A2H = (unsigned short*)carve((size_t)GKMAX * HC3 * 2);  // 62.9 MB
    unsigned short* A2L = (unsigned short*)carve((size_t)GKMAX * HC3 * 2);  // 62.9 MB
    // weight temps alias into A2 (prep completes before aggregate_sel writes A2)
    unsigned short* WTH = (unsigned short*)A2H;
    unsigned short* WTL = WTH + (size_t)NSLOT * MSZ;
    unsigned short* WSH = WTL + (size_t)NSLOT * MSZ;
    unsigned short* WSL = (unsigned short*)A2L;
    float* XN   = (float*)carve((size_t)GKMAX * CC * 4); // 41.9 MB
    unsigned short* B2H = (unsigned short*)carve((size_t)NSLOT * MSZ * 2);
    unsigned short* B2L = (unsigned short*)carve((size_t)NSLOT * MSZ * 2);
    float* PM   = (float*)carve((size_t)NG * 8 * CC * 4);
    float* PS   = (float*)carve((size_t)NG * 8 * CC * 4);
    float* ASV  = (float*)carve((size_t)3 * HC3 * 4);
    float* ADV  = (float*)carve((size_t)3 * HC3 * 4);
    float* QV   = (float*)carve((size_t)3 * HC3 * 4);
    float* UU   = (float*)carve((size_t)3 * HC3 * 4);
    float* BV   = (float*)carve((size_t)3 * CC * 4);
    float* AS   = (float*)carve((size_t)NMAX * 3 * 4);
    float* AD   = (float*)carve((size_t)NMAX * 3 * 4);
    float* T3   = (float*)carve((size_t)NMAX * 3 * 4);
    float* SL   = (float*)carve((size_t)NMAX * 3 * 4);
    unsigned* MXE = (unsigned*)carve((size_t)NMAX * 3 * 4);
    float* MXF  = (float*)carve((size_t)NMAX * 3 * 4);
    float* DEN  = (float*)carve((size_t)NMAX * 3 * 4);
    float* SEXP = (float*)carve((size_t)NMAX * 3 * 4);
    int* CNT    = (int*)carve((size_t)NMAX * 4);
    int* OFFS   = (int*)carve((size_t)NMAX * 4);
    int* CUR    = (int*)carve((size_t)NMAX * 4);
    int* NEWID  = (int*)carve((size_t)NMAX * 4);
    int* GT     = (int*)carve((size_t)NG * 4);
    int* CSRS   = (int*)carve((size_t)EE * 4);
    float* CSRA = (float*)carve((size_t)EE * 3 * 4);
    int* SRC = (int*)carve((size_t)EE * 4);
    int* DST = (int*)carve((size_t)EE * 4);
    int* MK  = (int*)carve((size_t)EE * 4);
    int* PERM  = (int*)carve((size_t)GKMAX * 4);
    float* VALS = (float*)carve((size_t)GKMAX * 4);
    float* PN  = (float*)carve(256);
    float* BVP = (float*)carve(256);
    float* R0 = (float*)carve((size_t)NG * 2048 * 4);
    float* R1 = (float*)carve((size_t)NG * 2048 * 4);
    float* R2 = (float*)carve((size_t)NG * 2048 * 4);
    float* Z1 = (float*)carve((size_t)NG * 1024 * 4);
    float* Rarr[3] = {R0, R1, R2};
    (void)in_sizes; (void)n_in; (void)out_size;

    copy_edges<<<cdiv(EE, 256), 256, 0, stream>>>(ei, SRC, DST, MK);

    auto prep = [&](int lbase, int nl) {
        int nslots = 3 * nl;
        split_w_all<<<dim3(4096, nslots), 256, 0, stream>>>(W[0], W[1], W[2], lbase, WSH, WSL);
        transpose_split_wt_all<<<dim3(32, 32, nslots), 256, 0, stream>>>(Wt[0], Wt[1], Wt[2],
                                                                          lbase, WTH, WTL);
        wtp_all<<<nl * 768, 256, 0, stream>>>(Wt[0], Wt[1], Wt[2], pv[0], pv[1], pv[2],
                                              lbase, UU);
        gemm_prep<<<dim3(8, 8, nslots), 256, 0, stream>>>(WTH, WTL, WSH, WSL, B2H, B2L, CC);
        attvec_all<<<dim3(768, nl), 256, 0, stream>>>(W[0], W[1], W[2],
            atts[0], atts[1], atts[2], attd[0], attd[1], attd[2], UU, lbase, ASV, ADV, QV);
        bvinit_pnorm<<<dim3(5, nl), 256, 0, stream>>>(bt[0], bt[1], bt[2],
            pv[0], pv[1], pv[2], lbase, BV, PN);
        bvec_part<<<dim3(4, 12, nl), 256, 0, stream>>>(bb[0], bb[1], bb[2],
            Wt[0], Wt[1], Wt[2], lbase, BV);
        bvp_all<<<nl, 256, 0, stream>>>(BV, pv[0], pv[1], pv[2], lbase, BVP);
    };

    if (batched) prep(0, 3);

    const int ns_[3]  = {12800, 10240, 5120};
    const int npg_[3] = {200, 160, 80};
    const int kk_[3]  = {160, 80, 16};
    const int sk_[3]  = {2, 2, 4};     // split-K factors
    const float* xin = x;

    for (int L = 0; L < 3; ++L) {
        int n = ns_[L], npg = npg_[L], k = kk_[L];
        int gk = NG * k;
        if (!batched) prep(L, 1);
        size_t b2off = batched ? (size_t)L * 3 * MSZ : 0;
        attn_node<<<n / 4, 256, 0, stream>>>(xin, ASV + (size_t)L * HC3,
            ADV + (size_t)L * HC3, QV + (size_t)L * HC3, AS, AD, T3,
            SL, MXE, SEXP, CNT, CUR, n);
        edge_pass1<<<cdiv(EE, 256), 256, 0, stream>>>(SRC, DST, MK, AS, AD, MXE, SEXP, CNT);
        scan_graph<<<NG, 64, 0, stream>>>(CNT, OFFS, GT, npg);
        post_edge<<<cdiv(n, 256), 256, 0, stream>>>(OFFS, GT, MXE, SL, SEXP, MXF, DEN, n, npg);
        fill_alpha<<<cdiv(EE, 256), 256, 0, stream>>>(SRC, DST, MK, OFFS, CUR,
                                                      AS, AD, MXF, DEN, CSRS, CSRA);
        score_topk<<<NG, 64, 0, stream>>>(T3, SL, MXF, DEN, OFFS, CNT, CSRS, CSRA,
                                          BVP + L, PN + L, npg, k, PERM, VALS, NEWID);
        aggregate_sel<<<gk, 256, 0, stream>>>(xin, SL, MXF, DEN, OFFS, CNT, CSRS, CSRA,
                                              PERM, A2H, A2L);
        hipMemsetAsync(XN, 0, (size_t)gk * CC * 4, stream);
        gemm_splitk<<<dim3(gk / 128, 8, sk_[L]), 256, 0, stream>>>(A2H, A2L, HC3,
            B2H + b2off, B2L + b2off, HC3, XN, CC, HC3 / sk_[L]);
        readout_part<<<dim3(NG, 8), 256, 0, stream>>>(XN, BV + (size_t)L * CC, VALS,
                                                      k, PM, PS);
        readout_fin<<<NG, 256, 0, stream>>>(PM, PS, k, Rarr[L]);
        if (L < 2) remap_edges<<<cdiv(EE, 256), 256, 0, stream>>>(SRC, DST, MK, NEWID);
        xin = XN;
    }

    // final MLP
    mlp1_kernel<<<dim3(4, NG), 256, 0, stream>>>(R0, R1, R2, Wl1, bl1, Z1);
    mlp2_kernel<<<NG * 2, 64, 0, stream>>>(Z1, Wl2, bl2, out);
}